// Round 1
// baseline (3425.070 us; speedup 1.0000x reference)
//
#include <hip/hip_runtime.h>

// ---------------------------------------------------------------------------
// GemNet InteractionBlock forward, MI355X (gfx950).
// Round 1: pure-f32 correctness baseline. All heavy ops are tiled-LDS f32
// GEMMs (no MFMA yet). Sizes are fixed by the reference.
// ---------------------------------------------------------------------------

#define EE   120000   // edges
#define NA   10000    // atoms
#define DEE  128      // edge emb
#define DTT  64       // triplet emb
#define KK   8        // triplets per edge
#define SS   7        // spherical basis

constexpr float C_INV = 0.70710678118654752440f;  // 1/sqrt(2)

__device__ __forceinline__ float act_silu(float x) {
    return x / (1.0f + __expf(-x));
}

// ---------------------------------------------------------------------------
// Generic tiled f32 GEMM: out(M x N) = epilogue(act?(A(M x K) @ W(K x N)))
// Block tile: 128 rows x N cols, 256 threads, K staged in chunks of 16.
// EPI: 0 none; 1 out = v*extra; 2 out = (skip+v)*C;
//      3 out = ((skip+v)*C + extra)*C; 4 out[gs[row]] += 0.5*v (perm-add)
// ASI: A rows assembled from [hsrc[gs[r]] | hsrc[gt[r]] | A[r]]  (K=384)
// ---------------------------------------------------------------------------
template<int K, int N, bool ACT, int EPI, bool ASI>
__global__ __launch_bounds__(256) void gemm_k(
    const float* __restrict__ A, const float* __restrict__ W,
    float* out, int M,
    const float* skip, const float* extra,
    const float* __restrict__ hsrc,
    const int* __restrict__ gs, const int* __restrict__ gt)
{
    constexpr int CT  = N / 4;        // col-threads (32 for N=128, 16 for N=64)
    constexpr int RT  = 256 / CT;     // row-threads
    constexpr int RPT = 128 / RT;     // rows per thread

    __shared__ float As[128][20];     // pad 20: float4-aligned, conflict-free
    __shared__ float Ws[16][N];

    const int tid  = threadIdx.x;
    const int tx   = tid % CT;
    const int ty   = tid / CT;
    const int row0 = blockIdx.x * 128;

    float acc[RPT][4];
    #pragma unroll
    for (int i = 0; i < RPT; ++i)
        acc[i][0] = acc[i][1] = acc[i][2] = acc[i][3] = 0.f;

    for (int k0 = 0; k0 < K; k0 += 16) {
        // stage A: 128 rows x 16 k  (512 float4)
        #pragma unroll
        for (int t = tid; t < 512; t += 256) {
            int r  = t >> 2;
            int k4 = (t & 3) << 2;
            int row = row0 + r;
            float4 v = make_float4(0.f, 0.f, 0.f, 0.f);
            if (row < M) {
                const float* p;
                int off;
                if (ASI) {
                    int seg = k0 >> 7;
                    off = (k0 & 127) + k4;
                    p = (seg == 0) ? hsrc + (size_t)gs[row] * 128
                      : (seg == 1) ? hsrc + (size_t)gt[row] * 128
                                   : A + (size_t)row * 128;
                } else {
                    p   = A + (size_t)row * K;
                    off = k0 + k4;
                }
                v = *(const float4*)(p + off);
            }
            *(float4*)&As[r][k4] = v;
        }
        // stage W: 16 x N
        #pragma unroll
        for (int t = tid; t < 4 * N; t += 256) {
            int kk = t / (N / 4);
            int c4 = (t % (N / 4)) * 4;
            *(float4*)&Ws[kk][c4] = *(const float4*)(W + (size_t)(k0 + kk) * N + c4);
        }
        __syncthreads();
        #pragma unroll
        for (int kk = 0; kk < 16; kk += 2) {
            float4 w0 = *(const float4*)&Ws[kk + 0][tx * 4];
            float4 w1 = *(const float4*)&Ws[kk + 1][tx * 4];
            #pragma unroll
            for (int i = 0; i < RPT; ++i) {
                float2 a = *(const float2*)&As[ty + RT * i][kk];
                acc[i][0] += a.x * w0.x; acc[i][0] += a.y * w1.x;
                acc[i][1] += a.x * w0.y; acc[i][1] += a.y * w1.y;
                acc[i][2] += a.x * w0.z; acc[i][2] += a.y * w1.z;
                acc[i][3] += a.x * w0.w; acc[i][3] += a.y * w1.w;
            }
        }
        __syncthreads();
    }

    #pragma unroll
    for (int i = 0; i < RPT; ++i) {
        int row = row0 + ty + RT * i;
        if (row >= M) continue;
        float4 v;
        v.x = ACT ? act_silu(acc[i][0]) : acc[i][0];
        v.y = ACT ? act_silu(acc[i][1]) : acc[i][1];
        v.z = ACT ? act_silu(acc[i][2]) : acc[i][2];
        v.w = ACT ? act_silu(acc[i][3]) : acc[i][3];
        size_t o = (size_t)row * N + tx * 4;
        if (EPI == 0) {
            *(float4*)(out + o) = v;
        } else if (EPI == 1) {
            float4 ex = *(const float4*)(extra + o);
            v.x *= ex.x; v.y *= ex.y; v.z *= ex.z; v.w *= ex.w;
            *(float4*)(out + o) = v;
        } else if (EPI == 2) {
            float4 sk = *(const float4*)(skip + o);
            v.x = (sk.x + v.x) * C_INV;
            v.y = (sk.y + v.y) * C_INV;
            v.z = (sk.z + v.z) * C_INV;
            v.w = (sk.w + v.w) * C_INV;
            *(float4*)(out + o) = v;
        } else if (EPI == 3) {
            float4 sk = *(const float4*)(skip + o);
            float4 ex = *(const float4*)(extra + o);
            v.x = ((sk.x + v.x) * C_INV + ex.x) * C_INV;
            v.y = ((sk.y + v.y) * C_INV + ex.y) * C_INV;
            v.z = ((sk.z + v.z) * C_INV + ex.z) * C_INV;
            v.w = ((sk.w + v.w) * C_INV + ex.w) * C_INV;
            *(float4*)(out + o) = v;
        } else if (EPI == 4) {
            size_t oo = (size_t)gs[row] * N + tx * 4;  // gs = inverse perm
            float4 cur = *(float4*)(out + oo);
            cur.x += 0.5f * v.x;
            cur.y += 0.5f * v.y;
            cur.z += 0.5f * v.z;
            cur.w += 0.5f * v.w;
            *(float4*)(out + oo) = cur;
        }
    }
}

// ---------------------------------------------------------------------------
// inv[idx_swap[i]] = i  (idx_swap is a permutation -> no write conflicts)
// ---------------------------------------------------------------------------
__global__ void inv_perm_k(const int* __restrict__ sw, int* __restrict__ inv, int n)
{
    int i = blockIdx.x * 256 + threadIdx.x;
    if (i < n) inv[sw[i]] = i;
}

// ---------------------------------------------------------------------------
// x = C*x + 0.5*y   (merging x_skip with x_st before permuted x_ts add)
// ---------------------------------------------------------------------------
__global__ void merge1_k(float4* x, const float4* __restrict__ y)
{
    int i = blockIdx.x * 256 + threadIdx.x;   // exactly E*32 elements
    float4 a = x[i], b = y[i];
    a.x = C_INV * a.x + 0.5f * b.x;
    a.y = C_INV * a.y + 0.5f * b.y;
    a.z = C_INV * a.z + 0.5f * b.z;
    a.w = C_INV * a.w + 0.5f * b.w;
    x[i] = a;
}

// ---------------------------------------------------------------------------
// segment_sum(x * coef, idx_t) via global f32 atomics into h2 (N_A x 128)
// ---------------------------------------------------------------------------
__global__ void scatter_k(const float4* __restrict__ x, const float4* __restrict__ coef,
                          const int* __restrict__ idxt, float* h2)
{
    int i = blockIdx.x * 256 + threadIdx.x;   // exactly E*32
    int e = i >> 5, q = i & 31;
    float4 xv = x[i], cv = coef[i];
    float* dst = h2 + (size_t)idxt[e] * 128 + q * 4;
    atomicAdd(dst + 0, xv.x * cv.x);
    atomicAdd(dst + 1, xv.y * cv.y);
    atomicAdd(dst + 2, xv.z * cv.z);
    atomicAdd(dst + 3, xv.w * cv.w);
}

// ---------------------------------------------------------------------------
// EfficientInteractionBilinear, fused. 8 edges / block, 256 threads (4 waves).
//   m2[e][k][c]   = mkt[id3_kt[(e0+e)*8+k]][c]          (gather)
//   sumk[e][s][c] = sum_k sph[e][k][s] * m2[e][k][c]
//   a[e][j][c]    = sum_s rbfW1[e][j][s] * sumk[e][s][c]
//   xb[e][u]      = sum_{c,j} a[e][j][c] * Wbil[c][j][u]
// Final contraction: W_bil held in VGPRs (64 regs = 4 c-slices x 16 j per
// lane-u), each wave handles 4 of the 16 c-chunks for all 8 edges,
// per-wave partial xb in LDS, reduced at the end.
// a stored in LDS as [e][c][j] with an XOR bank swizzle (rows are 16 floats).
// ---------------------------------------------------------------------------
__device__ __forceinline__ int al_off(int e, int cc, int j)
{
    return (e * 64 + cc) * 16 + (j ^ (((cc >> 1) & 3) << 2));
}

__global__ __launch_bounds__(256) void bilinear_k(
    const float* __restrict__ mkt,     // E x 64
    const float* __restrict__ rbfW1,   // E x 16 x 7
    const float* __restrict__ sph,     // E x 8 x 7
    const int*   __restrict__ id3kt,   // E*8
    const float* __restrict__ Wbil,    // [64][16][64]  (c, j, u)
    float* __restrict__ xb)            // E x 64
{
    __shared__ float sm[15872];        // 63.5 KB
    float* m2   = sm;                  // [8][8][64]  = 4096   (dead after B)
    float* sumk = sm + 4096;           // [8][7][64]  = 3584   (dead after C)
    float* al   = sm + 7680;           // [8][64][16] = 8192   (swizzled)
    float* xbs  = sm;                  // [4][8][64]  = 2048   aliases m2 (phase D)

    const int tid  = threadIdx.x;
    const int lane = tid & 63;
    const int wid  = tid >> 6;
    const int e0   = blockIdx.x * 8;

    // phase A: gather m2
    for (int r = wid; r < 64; r += 4)
        m2[r * 64 + lane] = mkt[(size_t)id3kt[e0 * 8 + r] * 64 + lane];
    __syncthreads();

    // phase B: sumk
    for (int r = wid; r < 56; r += 4) {
        int e = r / 7, s = r - e * 7;
        const float* sp = sph + (size_t)(e0 + e) * (KK * SS) + s;
        float acc = 0.f;
        #pragma unroll
        for (int k = 0; k < 8; ++k)
            acc += sp[k * SS] * m2[(e * 8 + k) * 64 + lane];
        sumk[(e * 7 + s) * 64 + lane] = acc;
    }
    __syncthreads();

    // phase C: a  (store as [e][c][j], lane = c)
    for (int r = wid; r < 128; r += 4) {
        int e = r >> 4, j = r & 15;
        const float* rp = rbfW1 + ((size_t)(e0 + e) * 16 + j) * SS;
        float acc = 0.f;
        #pragma unroll
        for (int s = 0; s < 7; ++s)
            acc += rp[s] * sumk[(e * 7 + s) * 64 + lane];
        al[al_off(e, lane, j)] = acc;
    }
    __syncthreads();   // al ready; m2/sumk dead -> xbs may be written

    // phase D: xb partials, W_bil in registers (lane = u)
    float* xbw = xbs + wid * 512;
    for (int t = lane; t < 512; t += 64) xbw[t] = 0.f;  // own slice, no race

    for (int chunk = wid; chunk < 16; chunk += 4) {
        int cc0 = chunk * 4;
        float w[64];
        #pragma unroll
        for (int q = 0; q < 64; ++q)
            w[q] = Wbil[(size_t)(cc0 + (q >> 4)) * 1024 + (q & 15) * 64 + lane];
        #pragma unroll
        for (int e = 0; e < 8; ++e) {
            float p = 0.f;
            #pragma unroll
            for (int t4 = 0; t4 < 16; ++t4) {
                int cc = cc0 + (t4 >> 2);
                const float4 a4 = *(const float4*)&al[al_off(e, cc, (t4 & 3) * 4)];
                p += a4.x * w[t4 * 4 + 0];
                p += a4.y * w[t4 * 4 + 1];
                p += a4.z * w[t4 * 4 + 2];
                p += a4.w * w[t4 * 4 + 3];
            }
            xbw[e * 64 + lane] += p;
        }
    }
    __syncthreads();

    // reduce the 4 wave slices
    for (int t = tid; t < 512; t += 256) {
        float s = xbs[t] + xbs[512 + t] + xbs[1024 + t] + xbs[1536 + t];
        xb[(size_t)(e0 + (t >> 6)) * 64 + (t & 63)] = s;
    }
}

// ---------------------------------------------------------------------------
// launch
// ---------------------------------------------------------------------------
extern "C" void kernel_launch(void* const* d_in, const int* in_sizes, int n_in,
                              void* d_out, int out_size, void* d_ws, size_t ws_size,
                              hipStream_t stream)
{
    const float* m_st      = (const float*)d_in[1];
    const float* rbf_h     = (const float*)d_in[2];
    const float* rbf3      = (const float*)d_in[3];
    const float* cbf_rbfW1 = (const float*)d_in[4];
    const float* cbf_sph   = (const float*)d_in[5];
    const float* W_mlp_st  = (const float*)d_in[6];
    const float* W_m_kt    = (const float*)d_in[7];
    const float* W_t_rbf   = (const float*)d_in[8];
    const float* W_down    = (const float*)d_in[9];
    const float* W_bil     = (const float*)d_in[10];
    const float* W_st3     = (const float*)d_in[11];
    const float* W_ts3     = (const float*)d_in[12];
    const float* resb      = (const float*)d_in[13];
    const float* resa      = (const float*)d_in[14];
    const float* W_ae_rbf  = (const float*)d_in[15];
    const float* W_ae_in   = (const float*)d_in[16];
    const float* resat     = (const float*)d_in[17];
    const float* W_asi     = (const float*)d_in[18];
    const float* resm      = (const float*)d_in[19];
    const int*   idx_s     = (const int*)d_in[20];
    const int*   idx_t     = (const int*)d_in[21];
    const int*   idx_swap  = (const int*)d_in[22];
    const int*   id3_kt    = (const int*)d_in[23];

    // workspace layout (floats)
    float* B0  = (float*)d_ws;                      // E x 128 : x_skip -> x
    float* B1  = B0 + (size_t)EE * 128;             // E x 128 : temps / m
    float* BT  = B1 + (size_t)EE * 128;             // E x 128 : scale/mkt|xb/res tmp
    float* B5  = BT + (size_t)EE * 128;             // NA x 128: h2 / atom tmp
    float* B6  = B5 + (size_t)NA * 128;             // NA x 128: atom tmp
    int*   inv = (int*)(B6 + (size_t)NA * 128);     // E       : inverse of idx_swap

    float* out_h = (float*)d_out;                   // NA x 128
    float* out_m = out_h + (size_t)NA * 128;        // E x 128
    float* mkt   = BT;                              // E x 64
    float* xbuf  = BT + (size_t)EE * 64;            // E x 64

    const dim3 blk(256);
    const int gE = (EE + 127) / 128;   // 938
    const int gN = (NA + 127) / 128;   // 79
    constexpr size_t SQ = 128 * 128;   // res-layer weight stride

    inv_perm_k<<<(EE + 255) / 256, blk, 0, stream>>>(idx_swap, inv, EE);

    // scale = rbf3 @ W_t_rbf -> BT
    gemm_k<16, 128, false, 0, false><<<gE, blk, 0, stream>>>(
        rbf3, W_t_rbf, BT, EE, nullptr, nullptr, nullptr, nullptr, nullptr);
    // x_skip = m_st @ W_mlp_st -> B0
    gemm_k<128, 128, false, 0, false><<<gE, blk, 0, stream>>>(
        m_st, W_mlp_st, B0, EE, nullptr, nullptr, nullptr, nullptr, nullptr);
    // t_pre = act(m_st @ W_m_kt) * scale -> B1
    gemm_k<128, 128, true, 1, false><<<gE, blk, 0, stream>>>(
        m_st, W_m_kt, B1, EE, nullptr, BT, nullptr, nullptr, nullptr);
    // m_kt = act(t_pre @ W_down) -> BT[0 : E*64)
    gemm_k<128, 64, true, 0, false><<<gE, blk, 0, stream>>>(
        B1, W_down, mkt, EE, nullptr, nullptr, nullptr, nullptr, nullptr);
    // bilinear -> xbuf
    bilinear_k<<<EE / 8, blk, 0, stream>>>(mkt, cbf_rbfW1, cbf_sph, id3_kt, W_bil, xbuf);
    // y_st = act(xb @ W_st3) -> B1
    gemm_k<64, 128, true, 0, false><<<gE, blk, 0, stream>>>(
        xbuf, W_st3, B1, EE, nullptr, nullptr, nullptr, nullptr, nullptr);
    // x = C*x_skip + 0.5*y_st   (B0 in place)
    merge1_k<<<EE * 32 / 256, blk, 0, stream>>>((float4*)B0, (const float4*)B1);
    // x[inv[j]] += 0.5*act(xb @ W_ts3)[j]
    gemm_k<64, 128, true, 4, false><<<gE, blk, 0, stream>>>(
        xbuf, W_ts3, B0, EE, nullptr, nullptr, nullptr, inv, nullptr);

    // res_before (1 layer), then + m_st merge folded into EPI 3
    gemm_k<128, 128, true, 0, false><<<gE, blk, 0, stream>>>(
        B0, resb, B1, EE, nullptr, nullptr, nullptr, nullptr, nullptr);
    gemm_k<128, 128, true, 3, false><<<gE, blk, 0, stream>>>(
        B1, resb + SQ, B0, EE, B0, m_st, nullptr, nullptr, nullptr);

    // res_after (2 layers)
    gemm_k<128, 128, true, 0, false><<<gE, blk, 0, stream>>>(
        B0, resa, B1, EE, nullptr, nullptr, nullptr, nullptr, nullptr);
    gemm_k<128, 128, true, 2, false><<<gE, blk, 0, stream>>>(
        B1, resa + SQ, B0, EE, B0, nullptr, nullptr, nullptr, nullptr);
    gemm_k<128, 128, true, 0, false><<<gE, blk, 0, stream>>>(
        B0, resa + 2 * SQ, B1, EE, nullptr, nullptr, nullptr, nullptr, nullptr);
    gemm_k<128, 128, true, 2, false><<<gE, blk, 0, stream>>>(
        B1, resa + 3 * SQ, B0, EE, B0, nullptr, nullptr, nullptr, nullptr);

    // coef = rbf_h @ W_ae_rbf -> B1 ; h2 = segment_sum(x*coef, idx_t) -> B5
    gemm_k<16, 128, false, 0, false><<<gE, blk, 0, stream>>>(
        rbf_h, W_ae_rbf, B1, EE, nullptr, nullptr, nullptr, nullptr, nullptr);
    hipMemsetAsync(B5, 0, (size_t)NA * 128 * sizeof(float), stream);
    scatter_k<<<EE * 32 / 256, blk, 0, stream>>>((const float4*)B0, (const float4*)B1, idx_t, B5);

    // h3 = act(h2 @ W_ae_in) -> B6 ; res_atom (2 layers) -> out_h
    gemm_k<128, 128, true, 0, false><<<gN, blk, 0, stream>>>(
        B5, W_ae_in, B6, NA, nullptr, nullptr, nullptr, nullptr, nullptr);
    gemm_k<128, 128, true, 0, false><<<gN, blk, 0, stream>>>(
        B6, resat, B5, NA, nullptr, nullptr, nullptr, nullptr, nullptr);
    gemm_k<128, 128, true, 2, false><<<gN, blk, 0, stream>>>(
        B5, resat + SQ, B6, NA, B6, nullptr, nullptr, nullptr, nullptr);
    gemm_k<128, 128, true, 0, false><<<gN, blk, 0, stream>>>(
        B6, resat + 2 * SQ, B5, NA, nullptr, nullptr, nullptr, nullptr, nullptr);
    gemm_k<128, 128, true, 2, false><<<gN, blk, 0, stream>>>(
        B5, resat + 3 * SQ, out_h, NA, B6, nullptr, nullptr, nullptr, nullptr);

    // ASI: m = act([h[idx_s]|h[idx_t]|x] @ W_asi) -> B1
    gemm_k<384, 128, true, 0, true><<<gE, blk, 0, stream>>>(
        B0, W_asi, B1, EE, nullptr, nullptr, out_h, idx_s, idx_t);

    // res_m (2 layers), final + x merge folded into EPI 3 -> out_m
    gemm_k<128, 128, true, 0, false><<<gE, blk, 0, stream>>>(
        B1, resm, BT, EE, nullptr, nullptr, nullptr, nullptr, nullptr);
    gemm_k<128, 128, true, 2, false><<<gE, blk, 0, stream>>>(
        BT, resm + SQ, B1, EE, B1, nullptr, nullptr, nullptr, nullptr);
    gemm_k<128, 128, true, 0, false><<<gE, blk, 0, stream>>>(
        B1, resm + 2 * SQ, BT, EE, nullptr, nullptr, nullptr, nullptr, nullptr);
    gemm_k<128, 128, true, 3, false><<<gE, blk, 0, stream>>>(
        BT, resm + 3 * SQ, out_m, EE, B1, B0, nullptr, nullptr, nullptr);
}

// Round 2
// 2013.285 us; speedup vs baseline: 1.7012x; 1.7012x over previous
//
#include <hip/hip_runtime.h>

// ---------------------------------------------------------------------------
// GemNet InteractionBlock forward, MI355X (gfx950).
// Round 2: bilinear rebuilt as fused bf16-MFMA GEMM (register ABC phases,
// swizzled bf16 A-tile in LDS, K split across 8 waves, W_bil in VGPRs).
// GEMM chain still f32 (round-3 target).
// ---------------------------------------------------------------------------

#define EE   120000   // edges
#define NA   10000    // atoms

constexpr float C_INV = 0.70710678118654752440f;  // 1/sqrt(2)

using f32x4 = __attribute__((ext_vector_type(4))) float;
using s16x8 = __attribute__((ext_vector_type(8))) short;

__device__ __forceinline__ float act_silu(float x) {
    return x / (1.0f + __expf(-x));
}

__device__ __forceinline__ unsigned short f2bf(float f) {
    unsigned int u = __float_as_uint(f);
    u += 0x7fffu + ((u >> 16) & 1u);           // round-to-nearest-even
    return (unsigned short)(u >> 16);
}

// ---------------------------------------------------------------------------
// Generic tiled f32 GEMM: out(M x N) = epilogue(act?(A(M x K) @ W(K x N)))
// Block tile: 128 rows x N cols, 256 threads, K staged in chunks of 16.
// EPI: 0 none; 1 out = v*extra; 2 out = (skip+v)*C;
//      3 out = ((skip+v)*C + extra)*C; 4 out[gs[row]] += 0.5*v (perm-add)
// ASI: A rows assembled from [hsrc[gs[r]] | hsrc[gt[r]] | A[r]]  (K=384)
// ---------------------------------------------------------------------------
template<int K, int N, bool ACT, int EPI, bool ASI>
__global__ __launch_bounds__(256) void gemm_k(
    const float* __restrict__ A, const float* __restrict__ W,
    float* out, int M,
    const float* skip, const float* extra,
    const float* __restrict__ hsrc,
    const int* __restrict__ gs, const int* __restrict__ gt)
{
    constexpr int CT  = N / 4;
    constexpr int RT  = 256 / CT;
    constexpr int RPT = 128 / RT;

    __shared__ float As[128][20];
    __shared__ float Ws[16][N];

    const int tid  = threadIdx.x;
    const int tx   = tid % CT;
    const int ty   = tid / CT;
    const int row0 = blockIdx.x * 128;

    float acc[RPT][4];
    #pragma unroll
    for (int i = 0; i < RPT; ++i)
        acc[i][0] = acc[i][1] = acc[i][2] = acc[i][3] = 0.f;

    for (int k0 = 0; k0 < K; k0 += 16) {
        #pragma unroll
        for (int t = tid; t < 512; t += 256) {
            int r  = t >> 2;
            int k4 = (t & 3) << 2;
            int row = row0 + r;
            float4 v = make_float4(0.f, 0.f, 0.f, 0.f);
            if (row < M) {
                const float* p;
                int off;
                if (ASI) {
                    int seg = k0 >> 7;
                    off = (k0 & 127) + k4;
                    p = (seg == 0) ? hsrc + (size_t)gs[row] * 128
                      : (seg == 1) ? hsrc + (size_t)gt[row] * 128
                                   : A + (size_t)row * 128;
                } else {
                    p   = A + (size_t)row * K;
                    off = k0 + k4;
                }
                v = *(const float4*)(p + off);
            }
            *(float4*)&As[r][k4] = v;
        }
        #pragma unroll
        for (int t = tid; t < 4 * N; t += 256) {
            int kk = t / (N / 4);
            int c4 = (t % (N / 4)) * 4;
            *(float4*)&Ws[kk][c4] = *(const float4*)(W + (size_t)(k0 + kk) * N + c4);
        }
        __syncthreads();
        #pragma unroll
        for (int kk = 0; kk < 16; kk += 2) {
            float4 w0 = *(const float4*)&Ws[kk + 0][tx * 4];
            float4 w1 = *(const float4*)&Ws[kk + 1][tx * 4];
            #pragma unroll
            for (int i = 0; i < RPT; ++i) {
                float2 a = *(const float2*)&As[ty + RT * i][kk];
                acc[i][0] += a.x * w0.x; acc[i][0] += a.y * w1.x;
                acc[i][1] += a.x * w0.y; acc[i][1] += a.y * w1.y;
                acc[i][2] += a.x * w0.z; acc[i][2] += a.y * w1.z;
                acc[i][3] += a.x * w0.w; acc[i][3] += a.y * w1.w;
            }
        }
        __syncthreads();
    }

    #pragma unroll
    for (int i = 0; i < RPT; ++i) {
        int row = row0 + ty + RT * i;
        if (row >= M) continue;
        float4 v;
        v.x = ACT ? act_silu(acc[i][0]) : acc[i][0];
        v.y = ACT ? act_silu(acc[i][1]) : acc[i][1];
        v.z = ACT ? act_silu(acc[i][2]) : acc[i][2];
        v.w = ACT ? act_silu(acc[i][3]) : acc[i][3];
        size_t o = (size_t)row * N + tx * 4;
        if (EPI == 0) {
            *(float4*)(out + o) = v;
        } else if (EPI == 1) {
            float4 ex = *(const float4*)(extra + o);
            v.x *= ex.x; v.y *= ex.y; v.z *= ex.z; v.w *= ex.w;
            *(float4*)(out + o) = v;
        } else if (EPI == 2) {
            float4 sk = *(const float4*)(skip + o);
            v.x = (sk.x + v.x) * C_INV;
            v.y = (sk.y + v.y) * C_INV;
            v.z = (sk.z + v.z) * C_INV;
            v.w = (sk.w + v.w) * C_INV;
            *(float4*)(out + o) = v;
        } else if (EPI == 3) {
            float4 sk = *(const float4*)(skip + o);
            float4 ex = *(const float4*)(extra + o);
            v.x = ((sk.x + v.x) * C_INV + ex.x) * C_INV;
            v.y = ((sk.y + v.y) * C_INV + ex.y) * C_INV;
            v.z = ((sk.z + v.z) * C_INV + ex.z) * C_INV;
            v.w = ((sk.w + v.w) * C_INV + ex.w) * C_INV;
            *(float4*)(out + o) = v;
        } else if (EPI == 4) {
            size_t oo = (size_t)gs[row] * N + tx * 4;
            float4 cur = *(float4*)(out + oo);
            cur.x += 0.5f * v.x;
            cur.y += 0.5f * v.y;
            cur.z += 0.5f * v.z;
            cur.w += 0.5f * v.w;
            *(float4*)(out + oo) = cur;
        }
    }
}

__global__ void inv_perm_k(const int* __restrict__ sw, int* __restrict__ inv, int n)
{
    int i = blockIdx.x * 256 + threadIdx.x;
    if (i < n) inv[sw[i]] = i;
}

__global__ void merge1_k(float4* x, const float4* __restrict__ y)
{
    int i = blockIdx.x * 256 + threadIdx.x;
    float4 a = x[i], b = y[i];
    a.x = C_INV * a.x + 0.5f * b.x;
    a.y = C_INV * a.y + 0.5f * b.y;
    a.z = C_INV * a.z + 0.5f * b.z;
    a.w = C_INV * a.w + 0.5f * b.w;
    x[i] = a;
}

__global__ void scatter_k(const float4* __restrict__ x, const float4* __restrict__ coef,
                          const int* __restrict__ idxt, float* h2)
{
    int i = blockIdx.x * 256 + threadIdx.x;
    int e = i >> 5, q = i & 31;
    float4 xv = x[i], cv = coef[i];
    float* dst = h2 + (size_t)idxt[e] * 128 + q * 4;
    atomicAdd(dst + 0, xv.x * cv.x);
    atomicAdd(dst + 1, xv.y * cv.y);
    atomicAdd(dst + 2, xv.z * cv.z);
    atomicAdd(dst + 3, xv.w * cv.w);
}

// ---------------------------------------------------------------------------
// W_bil (f32 [c=64][j=16][u=64]) -> WT bf16 [u=64][k=1024], k = j*64 + c.
// B-fragments then load as 16B contiguous runs along k.
// ---------------------------------------------------------------------------
__global__ void wconv_k(const float* __restrict__ Wbil, unsigned short* __restrict__ WT)
{
    int t = blockIdx.x * 256 + threadIdx.x;    // 65536 total
    int u = t >> 10;
    int k = t & 1023;
    int j = k >> 6;
    int c = k & 63;
    WT[t] = f2bf(Wbil[(size_t)(c * 16 + j) * 64 + u]);
}

// ---------------------------------------------------------------------------
// Fused EfficientInteractionBilinear, v2 (bf16 MFMA).
// 512 threads (8 waves), 32 edges/block, 64 KB dynamic LDS.
//   per wave, per round (4 rounds = 1 edge each):
//     m2[k] regs <- gather mkt rows; sumk[7] regs; a[j] -> bf16 LDS (swizzled)
//   phase D: wave w owns K-slice [w*128, w*128+128):
//     B-frags (16 x dwordx4 from WT, preloaded), A-frags via ds_read_b128,
//     32 x mfma_f32_16x16x32_bf16; partials reduced through LDS (aliases a).
// ---------------------------------------------------------------------------
__global__ __launch_bounds__(512) void bilinear2_k(
    const float* __restrict__ mkt,          // E x 64
    const float* __restrict__ rbfW1,        // E x 16 x 7
    const float* __restrict__ sph,          // E x 8 x 7
    const int*   __restrict__ id3kt,        // E*8
    const unsigned short* __restrict__ WT,  // [64][1024] bf16
    float* __restrict__ xb)                 // E x 64
{
    extern __shared__ unsigned char smem[];
    unsigned short* aS = (unsigned short*)smem;   // [32][1024] bf16, swizzled
    float*          pS = (float*)smem;            // [8][32][64] f32 partials (aliases aS)

    const int tid = threadIdx.x;
    const int l   = tid & 63;
    const int w   = tid >> 6;
    const int e0  = blockIdx.x * 32;

    // ---- B-fragments: issue global loads first (L2-resident WT) ----
    s16x8 bfrag[4][4];
    {
        const int u  = l & 15;
        const int kh = w * 128 + ((l >> 4) << 3);
        #pragma unroll
        for (int nt = 0; nt < 4; ++nt)
            #pragma unroll
            for (int kq = 0; kq < 4; ++kq)
                bfrag[nt][kq] = *(const s16x8*)&WT[(size_t)(nt * 16 + u) * 1024 + kh + kq * 32];
    }

    // ---- phases A-C: build a-tile (bf16, swizzled) ----
    #pragma unroll
    for (int r = 0; r < 4; ++r) {
        const int eL = r * 8 + w;
        const int eG = e0 + eL;

        float m2r[8];
        #pragma unroll
        for (int k = 0; k < 8; ++k)
            m2r[k] = mkt[(size_t)id3kt[eG * 8 + k] * 64 + l];

        float sk[7];
        #pragma unroll
        for (int s = 0; s < 7; ++s) sk[s] = 0.f;
        const float* sp = sph + (size_t)eG * 56;
        #pragma unroll
        for (int k = 0; k < 8; ++k)
            #pragma unroll
            for (int s = 0; s < 7; ++s)
                sk[s] += sp[k * 7 + s] * m2r[k];

        const float* rp = rbfW1 + (size_t)eG * 112;
        unsigned short* arow = aS + eL * 1024;
        const int lsw = l ^ ((eL & 7) << 3);      // T2 XOR swizzle (byte<<4 == elem<<3)
        #pragma unroll
        for (int j = 0; j < 16; ++j) {
            float av = 0.f;
            #pragma unroll
            for (int s = 0; s < 7; ++s)
                av += rp[j * 7 + s] * sk[s];
            arow[j * 64 + lsw] = f2bf(av);
        }
    }
    __syncthreads();

    // ---- phase D: MFMA over this wave's K-slice ----
    f32x4 acc[2][4];
    #pragma unroll
    for (int mt = 0; mt < 2; ++mt)
        #pragma unroll
        for (int nt = 0; nt < 4; ++nt)
            acc[mt][nt] = (f32x4){0.f, 0.f, 0.f, 0.f};

    const int kbase = w * 128 + ((l >> 4) << 3);
    #pragma unroll
    for (int kq = 0; kq < 4; ++kq) {
        s16x8 afr[2];
        #pragma unroll
        for (int mt = 0; mt < 2; ++mt) {
            const int row = mt * 16 + (l & 15);
            const int kk  = (kbase + kq * 32) ^ ((row & 7) << 3);
            afr[mt] = *(const s16x8*)&aS[row * 1024 + kk];
        }
        #pragma unroll
        for (int mt = 0; mt < 2; ++mt)
            #pragma unroll
            for (int nt = 0; nt < 4; ++nt)
                acc[mt][nt] = __builtin_amdgcn_mfma_f32_16x16x32_bf16(
                    afr[mt], bfrag[nt][kq], acc[mt][nt], 0, 0, 0);
    }
    __syncthreads();   // all A-reads done before pS overwrites aS

    // ---- write per-wave partials (C/D layout: col=l&15, row=(l>>4)*4+q) ----
    #pragma unroll
    for (int mt = 0; mt < 2; ++mt)
        #pragma unroll
        for (int nt = 0; nt < 4; ++nt)
            #pragma unroll
            for (int q = 0; q < 4; ++q) {
                const int e = mt * 16 + ((l >> 4) << 2) + q;
                const int u = nt * 16 + (l & 15);
                pS[(w * 32 + e) * 64 + u] = acc[mt][nt][q];
            }
    __syncthreads();

    // ---- reduce 8 K-slices, coalesced store ----
    {
        const int e  = tid >> 4;
        const int u0 = (tid & 15) << 2;
        f32x4 s = (f32x4){0.f, 0.f, 0.f, 0.f};
        #pragma unroll
        for (int ww = 0; ww < 8; ++ww)
            s += *(const f32x4*)&pS[(ww * 32 + e) * 64 + u0];
        *(f32x4*)&xb[(size_t)(e0 + e) * 64 + u0] = s;
    }
}

// ---------------------------------------------------------------------------
// launch
// ---------------------------------------------------------------------------
extern "C" void kernel_launch(void* const* d_in, const int* in_sizes, int n_in,
                              void* d_out, int out_size, void* d_ws, size_t ws_size,
                              hipStream_t stream)
{
    const float* m_st      = (const float*)d_in[1];
    const float* rbf_h     = (const float*)d_in[2];
    const float* rbf3      = (const float*)d_in[3];
    const float* cbf_rbfW1 = (const float*)d_in[4];
    const float* cbf_sph   = (const float*)d_in[5];
    const float* W_mlp_st  = (const float*)d_in[6];
    const float* W_m_kt    = (const float*)d_in[7];
    const float* W_t_rbf   = (const float*)d_in[8];
    const float* W_down    = (const float*)d_in[9];
    const float* W_bil     = (const float*)d_in[10];
    const float* W_st3     = (const float*)d_in[11];
    const float* W_ts3     = (const float*)d_in[12];
    const float* resb      = (const float*)d_in[13];
    const float* resa      = (const float*)d_in[14];
    const float* W_ae_rbf  = (const float*)d_in[15];
    const float* W_ae_in   = (const float*)d_in[16];
    const float* resat     = (const float*)d_in[17];
    const float* W_asi     = (const float*)d_in[18];
    const float* resm      = (const float*)d_in[19];
    const int*   idx_s     = (const int*)d_in[20];
    const int*   idx_t     = (const int*)d_in[21];
    const int*   idx_swap  = (const int*)d_in[22];
    const int*   id3_kt    = (const int*)d_in[23];

    float* B0  = (float*)d_ws;
    float* B1  = B0 + (size_t)EE * 128;
    float* BT  = B1 + (size_t)EE * 128;
    float* B5  = BT + (size_t)EE * 128;
    float* B6  = B5 + (size_t)NA * 128;
    int*   inv = (int*)(B6 + (size_t)NA * 128);
    unsigned short* WT = (unsigned short*)(inv + EE);   // 64 x 1024 bf16

    float* out_h = (float*)d_out;
    float* out_m = out_h + (size_t)NA * 128;
    float* mkt   = BT;
    float* xbuf  = BT + (size_t)EE * 64;

    const dim3 blk(256);
    const int gE = (EE + 127) / 128;
    const int gN = (NA + 127) / 128;
    constexpr size_t SQ = 128 * 128;

    inv_perm_k<<<(EE + 255) / 256, blk, 0, stream>>>(idx_swap, inv, EE);
    wconv_k<<<65536 / 256, blk, 0, stream>>>(W_bil, WT);

    gemm_k<16, 128, false, 0, false><<<gE, blk, 0, stream>>>(
        rbf3, W_t_rbf, BT, EE, nullptr, nullptr, nullptr, nullptr, nullptr);
    gemm_k<128, 128, false, 0, false><<<gE, blk, 0, stream>>>(
        m_st, W_mlp_st, B0, EE, nullptr, nullptr, nullptr, nullptr, nullptr);
    gemm_k<128, 128, true, 1, false><<<gE, blk, 0, stream>>>(
        m_st, W_m_kt, B1, EE, nullptr, BT, nullptr, nullptr, nullptr);
    gemm_k<128, 64, true, 0, false><<<gE, blk, 0, stream>>>(
        B1, W_down, mkt, EE, nullptr, nullptr, nullptr, nullptr, nullptr);

    bilinear2_k<<<EE / 32, dim3(512), 65536, stream>>>(
        mkt, cbf_rbfW1, cbf_sph, id3_kt, WT, xbuf);

    gemm_k<64, 128, true, 0, false><<<gE, blk, 0, stream>>>(
        xbuf, W_st3, B1, EE, nullptr, nullptr, nullptr, nullptr, nullptr);
    merge1_k<<<EE * 32 / 256, blk, 0, stream>>>((float4*)B0, (const float4*)B1);
    gemm_k<64, 128, true, 4, false><<<gE, blk, 0, stream>>>(
        xbuf, W_ts3, B0, EE, nullptr, nullptr, nullptr, inv, nullptr);

    gemm_k<128, 128, true, 0, false><<<gE, blk, 0, stream>>>(
        B0, resb, B1, EE, nullptr, nullptr, nullptr, nullptr, nullptr);
    gemm_k<128, 128, true, 3, false><<<gE, blk, 0, stream>>>(
        B1, resb + SQ, B0, EE, B0, m_st, nullptr, nullptr, nullptr);

    gemm_k<128, 128, true, 0, false><<<gE, blk, 0, stream>>>(
        B0, resa, B1, EE, nullptr, nullptr, nullptr, nullptr, nullptr);
    gemm_k<128, 128, true, 2, false><<<gE, blk, 0, stream>>>(
        B1, resa + SQ, B0, EE, B0, nullptr, nullptr, nullptr, nullptr);
    gemm_k<128, 128, true, 0, false><<<gE, blk, 0, stream>>>(
        B0, resa + 2 * SQ, B1, EE, nullptr, nullptr, nullptr, nullptr, nullptr);
    gemm_k<128, 128, true, 2, false><<<gE, blk, 0, stream>>>(
        B1, resa + 3 * SQ, B0, EE, B0, nullptr, nullptr, nullptr, nullptr);

    gemm_k<16, 128, false, 0, false><<<gE, blk, 0, stream>>>(
        rbf_h, W_ae_rbf, B1, EE, nullptr, nullptr, nullptr, nullptr, nullptr);
    hipMemsetAsync(B5, 0, (size_t)NA * 128 * sizeof(float), stream);
    scatter_k<<<EE * 32 / 256, blk, 0, stream>>>((const float4*)B0, (const float4*)B1, idx_t, B5);

    gemm_k<128, 128, true, 0, false><<<gN, blk, 0, stream>>>(
        B5, W_ae_in, B6, NA, nullptr, nullptr, nullptr, nullptr, nullptr);
    gemm_k<128, 128, true, 0, false><<<gN, blk, 0, stream>>>(
        B6, resat, B5, NA, nullptr, nullptr, nullptr, nullptr, nullptr);
    gemm_k<128, 128, true, 2, false><<<gN, blk, 0, stream>>>(
        B5, resat + SQ, B6, NA, B6, nullptr, nullptr, nullptr, nullptr);
    gemm_k<128, 128, true, 0, false><<<gN, blk, 0, stream>>>(
        B6, resat + 2 * SQ, B5, NA, nullptr, nullptr, nullptr, nullptr, nullptr);
    gemm_k<128, 128, true, 2, false><<<gN, blk, 0, stream>>>(
        B5, resat + 3 * SQ, out_h, NA, B6, nullptr, nullptr, nullptr, nullptr);

    gemm_k<384, 128, true, 0, true><<<gE, blk, 0, stream>>>(
        B0, W_asi, B1, EE, nullptr, nullptr, out_h, idx_s, idx_t);

    gemm_k<128, 128, true, 0, false><<<gE, blk, 0, stream>>>(
        B1, resm, BT, EE, nullptr, nullptr, nullptr, nullptr, nullptr);
    gemm_k<128, 128, true, 2, false><<<gE, blk, 0, stream>>>(
        BT, resm + SQ, B1, EE, B1, nullptr, nullptr, nullptr, nullptr);
    gemm_k<128, 128, true, 0, false><<<gE, blk, 0, stream>>>(
        B1, resm + 2 * SQ, BT, EE, nullptr, nullptr, nullptr, nullptr, nullptr);
    gemm_k<128, 128, true, 3, false><<<gE, blk, 0, stream>>>(
        BT, resm + 3 * SQ, out_m, EE, B1, B0, nullptr, nullptr, nullptr);
}

// Round 3
// 1475.717 us; speedup vs baseline: 2.3210x; 1.3643x over previous
//
#include <hip/hip_runtime.h>

// ---------------------------------------------------------------------------
// GemNet InteractionBlock forward, MI355X (gfx950).
// Round 3: full bf16-MFMA GEMM chain (f32 accum, f32 residual state),
// bilinear with readlane-broadcast coefficients, bf16 intermediates.
// ---------------------------------------------------------------------------

#define EE 120000
#define NA 10000

constexpr float C_INV = 0.70710678118654752440f;

using f32x4 = __attribute__((ext_vector_type(4))) float;
using s16x8 = __attribute__((ext_vector_type(8))) short;
using s16x4 = __attribute__((ext_vector_type(4))) short;

__device__ __forceinline__ float act_silu(float x) { return x / (1.0f + __expf(-x)); }

__device__ __forceinline__ unsigned short f2bf(float f) {
    unsigned int u = __float_as_uint(f);
    u += 0x7fffu + ((u >> 16) & 1u);
    return (unsigned short)(u >> 16);
}
__device__ __forceinline__ float bf2f(unsigned short h) {
    return __uint_as_float(((unsigned int)h) << 16);
}

// ---------------------------------------------------------------------------
// bf16 MFMA GEMM: out(MxNT) = EPI(ACT?(A(MxKT) @ WT^T))   WT: [NT][KT] bf16
// 256 thr = 4 waves (2x2), block tile 128 x NT, wave tile 64 x NT/2.
// A reg-staged into XOR-swizzled LDS (f32 or bf16 source); B-frags from L2.
// EPI: 0 plain; 1 v*=extra; 2 (skip+v)*C; 3 ((skip+v)*C+extra)*C;
//      4 out[gs[row]]+=0.5v; 5 out=C*out+0.5v.
// ASRC: 0 = A rows; 1 = ASI concat [h2[gs]|h2[gt]|A] (KT=384, chunks of 128).
// ---------------------------------------------------------------------------
template<int KT, int NT, bool ACT, int EPI, int ASRC, bool AB16>
__global__ __launch_bounds__(256) void gemm2_k(
    const void* __restrict__ Ap, const unsigned short* __restrict__ WT,
    float* __restrict__ out, unsigned short* __restrict__ outb, int M,
    const float* __restrict__ skip, const float* __restrict__ extra,
    const float* __restrict__ h2,
    const int* __restrict__ gs, const int* __restrict__ gt)
{
    constexpr int BK = (KT >= 128) ? 128 : KT;   // k-chunk
    constexpr int NC = KT / BK;                  // chunks
    constexpr int KQ = BK / 32;                  // mfma k-steps per chunk
    constexpr int WN = NT / 2;                   // wave tile N
    constexpr int NF = WN / 16;                  // b-frags per k-step
    constexpr int UPT = 128 * BK / 8 / 256;      // 16B stage units per thread

    __shared__ unsigned short As[128 * BK];

    const int tid  = threadIdx.x;
    const int l    = tid & 63;
    const int w    = tid >> 6;
    const int wm   = w >> 1;
    const int wn   = w & 1;
    const int row0 = blockIdx.x * 128;

    const float*          Af = (const float*)Ap;
    const unsigned short* Ab = (const unsigned short*)Ap;

    f32x4 acc[4][NF];
    #pragma unroll
    for (int mt = 0; mt < 4; ++mt)
        #pragma unroll
        for (int nf = 0; nf < NF; ++nf)
            acc[mt][nf] = (f32x4){0.f, 0.f, 0.f, 0.f};

    for (int c = 0; c < NC; ++c) {
        // B-fragments for this chunk (global, L2-resident weights)
        s16x8 bfr[NF][KQ];
        #pragma unroll
        for (int nf = 0; nf < NF; ++nf)
            #pragma unroll
            for (int kq = 0; kq < KQ; ++kq) {
                const int n = wn * WN + nf * 16 + (l & 15);
                const int k = c * BK + kq * 32 + ((l >> 4) << 3);
                bfr[nf][kq] = *(const s16x8*)&WT[(size_t)n * KT + k];
            }

        if (c) __syncthreads();
        // stage A chunk into swizzled LDS
        #pragma unroll
        for (int u = 0; u < UPT; ++u) {
            const int flat = tid + u * 256;
            const int row  = flat / (BK / 8);
            const int k8   = (flat % (BK / 8)) << 3;
            const int grow = row0 + row;
            s16x8 val = {0, 0, 0, 0, 0, 0, 0, 0};
            if (grow < M) {
                if (AB16) {
                    val = *(const s16x8*)&Ab[(size_t)grow * KT + c * BK + k8];
                } else {
                    const float* src;
                    if (ASRC == 1) {
                        src = (c == 0) ? h2 + (size_t)gs[grow] * 128
                            : (c == 1) ? h2 + (size_t)gt[grow] * 128
                                       : Af + (size_t)grow * 128;
                        src += k8;
                    } else {
                        src = Af + (size_t)grow * KT + c * BK + k8;
                    }
                    f32x4 lo = *(const f32x4*)src;
                    f32x4 hi = *(const f32x4*)(src + 4);
                    #pragma unroll
                    for (int i = 0; i < 4; ++i) {
                        val[i]     = (short)f2bf(lo[i]);
                        val[i + 4] = (short)f2bf(hi[i]);
                    }
                }
            }
            const int byte = row * (BK * 2) + ((k8 * 2) ^ ((row & 7) << 4));
            *(s16x8*)((char*)As + byte) = val;
        }
        __syncthreads();

        #pragma unroll
        for (int kq = 0; kq < KQ; ++kq) {
            s16x8 afr[4];
            #pragma unroll
            for (int mt = 0; mt < 4; ++mt) {
                const int row = wm * 64 + mt * 16 + (l & 15);
                const int kb  = (kq * 64 + ((l >> 4) << 4)) ^ ((row & 7) << 4);
                afr[mt] = *(const s16x8*)((const char*)As + row * (BK * 2) + kb);
            }
            #pragma unroll
            for (int mt = 0; mt < 4; ++mt)
                #pragma unroll
                for (int nf = 0; nf < NF; ++nf)
                    acc[mt][nf] = __builtin_amdgcn_mfma_f32_16x16x32_bf16(
                        afr[mt], bfr[nf][kq], acc[mt][nf], 0, 0, 0);
        }
    }

    // epilogue (C/D: col=l&15, row=(l>>4)*4+q per 16x16 frag)
    #pragma unroll
    for (int mt = 0; mt < 4; ++mt)
        #pragma unroll
        for (int nf = 0; nf < NF; ++nf) {
            const int col = wn * WN + nf * 16 + (l & 15);
            #pragma unroll
            for (int q = 0; q < 4; ++q) {
                const int row = row0 + wm * 64 + mt * 16 + ((l >> 4) << 2) + q;
                if (row >= M) continue;
                float v = acc[mt][nf][q];
                if (ACT) v = act_silu(v);
                const size_t o = (size_t)row * NT + col;
                if (EPI == 1) v *= extra[o];
                if (EPI == 2) v = (skip[o] + v) * C_INV;
                if (EPI == 3) v = ((skip[o] + v) * C_INV + extra[o]) * C_INV;
                if (EPI == 4) {
                    out[(size_t)gs[row] * NT + col] += 0.5f * v;
                } else if (EPI == 5) {
                    out[o] = C_INV * out[o] + 0.5f * v;
                } else {
                    if (out)  out[o] = v;
                    if (outb) outb[o] = f2bf(v);
                }
            }
        }
}

// ---------------------------------------------------------------------------
// f32 GEMM for the two K=16 rbf projections (small, memory-bound)
// ---------------------------------------------------------------------------
__global__ __launch_bounds__(256) void rbf_gemm_k(
    const float* __restrict__ A, const float* __restrict__ W,
    float* __restrict__ out, int M)
{
    __shared__ float Ws[16][128];
    const int tid = threadIdx.x;
    #pragma unroll
    for (int t = tid; t < 512; t += 256) {
        int kk = t >> 5, c4 = (t & 31) << 2;
        *(float4*)&Ws[kk][c4] = *(const float4*)(W + kk * 128 + c4);
    }
    __syncthreads();
    const int tx = tid & 31, ty = tid >> 5;          // 8 rows x 32 col4
    const int row0 = blockIdx.x * 128;
    #pragma unroll
    for (int i = 0; i < 16; ++i) {
        const int row = row0 + ty + i * 8;
        if (row >= M) continue;
        float4 a0 = *(const float4*)(A + (size_t)row * 16);
        float4 a1 = *(const float4*)(A + (size_t)row * 16 + 4);
        float4 a2 = *(const float4*)(A + (size_t)row * 16 + 8);
        float4 a3 = *(const float4*)(A + (size_t)row * 16 + 12);
        float av[16] = {a0.x,a0.y,a0.z,a0.w, a1.x,a1.y,a1.z,a1.w,
                        a2.x,a2.y,a2.z,a2.w, a3.x,a3.y,a3.z,a3.w};
        float4 s = make_float4(0.f, 0.f, 0.f, 0.f);
        #pragma unroll
        for (int k = 0; k < 16; ++k) {
            float4 wv = *(const float4*)&Ws[k][tx * 4];
            s.x += av[k] * wv.x; s.y += av[k] * wv.y;
            s.z += av[k] * wv.z; s.w += av[k] * wv.w;
        }
        *(float4*)(out + (size_t)row * 128 + tx * 4) = s;
    }
}

__global__ void inv_perm_k(const int* __restrict__ sw, int* __restrict__ inv, int n)
{
    int i = blockIdx.x * 256 + threadIdx.x;
    if (i < n) inv[sw[i]] = i;
}

__global__ void scatter_k(const float4* __restrict__ x, const float4* __restrict__ coef,
                          const int* __restrict__ idxt, float* h2)
{
    int i = blockIdx.x * 256 + threadIdx.x;
    int e = i >> 5, q = i & 31;
    float4 xv = x[i], cv = coef[i];
    float* dst = h2 + (size_t)idxt[e] * 128 + q * 4;
    atomicAdd(dst + 0, xv.x * cv.x);
    atomicAdd(dst + 1, xv.y * cv.y);
    atomicAdd(dst + 2, xv.z * cv.z);
    atomicAdd(dst + 3, xv.w * cv.w);
}

// W_bil (f32 [c=64][j=16][u=64]) -> [u=64][k=1024] bf16, k = j*64+c
__global__ void wconv_k(const float* __restrict__ Wbil, unsigned short* __restrict__ WT)
{
    int t = blockIdx.x * 256 + threadIdx.x;
    int u = t >> 10, k = t & 1023, j = k >> 6, c = k & 63;
    WT[t] = f2bf(Wbil[(size_t)(c * 16 + j) * 64 + u]);
}

// batched weight transpose-convert: src f32 [K][N] -> dst bf16 [N][K]
struct WDesc { const float* src; int K; int N; int off; };
struct WTab  { WDesc d[21]; };

__global__ void wconvall_k(WTab tab, unsigned short* __restrict__ dst)
{
    WDesc d = tab.d[blockIdx.x];
    const int tot = d.K * d.N;
    for (int i = threadIdx.x; i < tot; i += 256) {
        int n = i / d.K, k = i - n * d.K;
        dst[d.off + i] = f2bf(d.src[(size_t)k * d.N + n]);
    }
}

// ---------------------------------------------------------------------------
// bilinear v3: readlane coefficient broadcast, bf16 mkt in / bf16 xb out.
// 512 thr (8 waves), 32 edges/block, 64 KB static LDS.
// ---------------------------------------------------------------------------
__device__ __forceinline__ float rlc(const f32x4& cv, int idx, int lbase)
{
    const int c = idx & 3;
    float comp = (c == 0) ? cv.x : (c == 1) ? cv.y : (c == 2) ? cv.z : cv.w;
    return __uint_as_float(__builtin_amdgcn_readlane(__float_as_uint(comp),
                                                     lbase + (idx >> 2)));
}

__global__ __launch_bounds__(512) void bilinear3_k(
    const unsigned short* __restrict__ mkt,   // E x 64 bf16
    const float* __restrict__ rbfW1,          // E x 16 x 7
    const float* __restrict__ sph,            // E x 8 x 7
    const int*   __restrict__ id3kt,          // E*8
    const unsigned short* __restrict__ WT,    // [64][1024] bf16
    unsigned short* __restrict__ xb)          // E x 64 bf16
{
    __shared__ unsigned short aS[32 * 1024];  // 64 KB, f32 partials alias
    float* pS = (float*)aS;

    const int tid = threadIdx.x;
    const int l   = tid & 63;
    const int w   = tid >> 6;
    const int e0  = blockIdx.x * 32;

    s16x8 bfrag[4][4];
    {
        const int u  = l & 15;
        const int kh = w * 128 + ((l >> 4) << 3);
        #pragma unroll
        for (int nt = 0; nt < 4; ++nt)
            #pragma unroll
            for (int kq = 0; kq < 4; ++kq)
                bfrag[nt][kq] = *(const s16x8*)&WT[(size_t)(nt * 16 + u) * 1024 + kh + kq * 32];
    }

    #pragma unroll
    for (int r = 0; r < 4; ++r) {
        const int eL = r * 8 + w;
        const int eG = e0 + eL;

        f32x4 cv = {0.f, 0.f, 0.f, 0.f};
        if (l < 14)       cv = *(const f32x4*)(sph   + (size_t)eG * 56  + l * 4);
        else if (l < 42)  cv = *(const f32x4*)(rbfW1 + (size_t)eG * 112 + (l - 14) * 4);

        float m2r[8];
        #pragma unroll
        for (int k = 0; k < 8; ++k)
            m2r[k] = bf2f(mkt[(size_t)id3kt[eG * 8 + k] * 64 + l]);

        float sk[7] = {0.f, 0.f, 0.f, 0.f, 0.f, 0.f, 0.f};
        #pragma unroll
        for (int k = 0; k < 8; ++k)
            #pragma unroll
            for (int s = 0; s < 7; ++s)
                sk[s] += rlc(cv, k * 7 + s, 0) * m2r[k];

        unsigned short* arow = aS + eL * 1024;
        const int lsw = l ^ ((eL & 7) << 3);
        #pragma unroll
        for (int j = 0; j < 16; ++j) {
            float av = 0.f;
            #pragma unroll
            for (int s = 0; s < 7; ++s)
                av += rlc(cv, j * 7 + s, 14) * sk[s];
            arow[j * 64 + lsw] = f2bf(av);
        }
    }
    __syncthreads();

    f32x4 acc[2][4];
    #pragma unroll
    for (int mt = 0; mt < 2; ++mt)
        #pragma unroll
        for (int nt = 0; nt < 4; ++nt)
            acc[mt][nt] = (f32x4){0.f, 0.f, 0.f, 0.f};

    const int kbase = w * 128 + ((l >> 4) << 3);
    #pragma unroll
    for (int kq = 0; kq < 4; ++kq) {
        s16x8 afr[2];
        #pragma unroll
        for (int mt = 0; mt < 2; ++mt) {
            const int row = mt * 16 + (l & 15);
            const int kk  = (kbase + kq * 32) ^ ((row & 7) << 3);
            afr[mt] = *(const s16x8*)&aS[row * 1024 + kk];
        }
        #pragma unroll
        for (int mt = 0; mt < 2; ++mt)
            #pragma unroll
            for (int nt = 0; nt < 4; ++nt)
                acc[mt][nt] = __builtin_amdgcn_mfma_f32_16x16x32_bf16(
                    afr[mt], bfrag[nt][kq], acc[mt][nt], 0, 0, 0);
    }
    __syncthreads();

    #pragma unroll
    for (int mt = 0; mt < 2; ++mt)
        #pragma unroll
        for (int nt = 0; nt < 4; ++nt)
            #pragma unroll
            for (int q = 0; q < 4; ++q) {
                const int e = mt * 16 + ((l >> 4) << 2) + q;
                const int u = nt * 16 + (l & 15);
                pS[(w * 32 + e) * 64 + u] = acc[mt][nt][q];
            }
    __syncthreads();

    {
        const int e  = tid >> 4;
        const int u0 = (tid & 15) << 2;
        f32x4 s = (f32x4){0.f, 0.f, 0.f, 0.f};
        #pragma unroll
        for (int ww = 0; ww < 8; ++ww)
            s += *(const f32x4*)&pS[(ww * 32 + e) * 64 + u0];
        s16x4 ov;
        #pragma unroll
        for (int i = 0; i < 4; ++i) ov[i] = (short)f2bf(s[i]);
        *(s16x4*)&xb[(size_t)(e0 + e) * 64 + u0] = ov;
    }
}

// ---------------------------------------------------------------------------
// launch
// ---------------------------------------------------------------------------
extern "C" void kernel_launch(void* const* d_in, const int* in_sizes, int n_in,
                              void* d_out, int out_size, void* d_ws, size_t ws_size,
                              hipStream_t stream)
{
    const float* m_st      = (const float*)d_in[1];
    const float* rbf_h     = (const float*)d_in[2];
    const float* rbf3      = (const float*)d_in[3];
    const float* cbf_rbfW1 = (const float*)d_in[4];
    const float* cbf_sph   = (const float*)d_in[5];
    const float* W_mlp_st  = (const float*)d_in[6];
    const float* W_m_kt    = (const float*)d_in[7];
    const float* W_t_rbf   = (const float*)d_in[8];
    const float* W_down    = (const float*)d_in[9];
    const float* W_bil     = (const float*)d_in[10];
    const float* W_st3     = (const float*)d_in[11];
    const float* W_ts3     = (const float*)d_in[12];
    const float* resb      = (const float*)d_in[13];
    const float* resa      = (const float*)d_in[14];
    const float* W_ae_rbf  = (const float*)d_in[15];
    const float* W_ae_in   = (const float*)d_in[16];
    const float* resat     = (const float*)d_in[17];
    const float* W_asi     = (const float*)d_in[18];
    const float* resm      = (const float*)d_in[19];
    const int*   idx_s     = (const int*)d_in[20];
    const int*   idx_t     = (const int*)d_in[21];
    const int*   idx_swap  = (const int*)d_in[22];
    const int*   id3_kt    = (const int*)d_in[23];

    float* B0 = (float*)d_ws;                       // E x 128 f32 : x
    float* B1 = B0 + (size_t)EE * 128;              // E x 128 f32 : scale/coef/m
    float* BT = B1 + (size_t)EE * 128;              // E x 128 f32 region, bf16 sub-use
    float* B5 = BT + (size_t)EE * 128;              // NA x 128 f32
    float* B6 = B5 + (size_t)NA * 128;              // NA x 128 f32
    int*   inv = (int*)(B6 + (size_t)NA * 128);
    unsigned short* WTbil = (unsigned short*)(inv + EE);    // 64x1024
    unsigned short* WTall = WTbil + 65536;                  // 352256 bf16

    unsigned short* mkt_b = (unsigned short*)BT;            // E x 64 bf16
    unsigned short* xb_b  = mkt_b + (size_t)EE * 64;        // E x 64 bf16
    unsigned short* T16   = xb_b + (size_t)EE * 64;         // E x 128 bf16

    float* out_h = (float*)d_out;
    float* out_m = out_h + (size_t)NA * 128;

    const dim3 blk(256);
    const int gE = (EE + 127) / 128;   // 938
    const int gN = (NA + 127) / 128;   // 79
    constexpr size_t SQ = 128 * 128;

    // --- weight conversion table ---
    WTab tab; int off = 0; int oi = 0;
    auto put = [&](const float* s, int K, int N) {
        int o = off; tab.d[oi].src = s; tab.d[oi].K = K; tab.d[oi].N = N;
        tab.d[oi].off = o; ++oi; off += K * N; return o;
    };
    const int o_mlp  = put(W_mlp_st, 128, 128);
    const int o_mktw = put(W_m_kt, 128, 128);
    const int o_down = put(W_down, 128, 64);
    const int o_st3  = put(W_st3, 64, 128);
    const int o_ts3  = put(W_ts3, 64, 128);
    const int o_rb0  = put(resb, 128, 128);
    const int o_rb1  = put(resb + SQ, 128, 128);
    const int o_ra0  = put(resa, 128, 128);
    const int o_ra1  = put(resa + SQ, 128, 128);
    const int o_ra2  = put(resa + 2 * SQ, 128, 128);
    const int o_ra3  = put(resa + 3 * SQ, 128, 128);
    const int o_aein = put(W_ae_in, 128, 128);
    const int o_rat0 = put(resat, 128, 128);
    const int o_rat1 = put(resat + SQ, 128, 128);
    const int o_rat2 = put(resat + 2 * SQ, 128, 128);
    const int o_rat3 = put(resat + 3 * SQ, 128, 128);
    const int o_asi  = put(W_asi, 384, 128);
    const int o_rm0  = put(resm, 128, 128);
    const int o_rm1  = put(resm + SQ, 128, 128);
    const int o_rm2  = put(resm + 2 * SQ, 128, 128);
    const int o_rm3  = put(resm + 3 * SQ, 128, 128);

    inv_perm_k<<<(EE + 255) / 256, blk, 0, stream>>>(idx_swap, inv, EE);
    wconv_k<<<65536 / 256, blk, 0, stream>>>(W_bil, WTbil);
    wconvall_k<<<21, blk, 0, stream>>>(tab, WTall);

    // scale = rbf3 @ W_t_rbf -> B1 (f32)
    rbf_gemm_k<<<gE, blk, 0, stream>>>(rbf3, W_t_rbf, B1, EE);
    // x_skip = m_st @ W_mlp_st -> B0
    gemm2_k<128, 128, false, 0, 0, false><<<gE, blk, 0, stream>>>(
        m_st, WTall + o_mlp, B0, nullptr, EE, nullptr, nullptr, nullptr, nullptr, nullptr);
    // tpre = act(m_st @ W_m_kt) * scale -> T16 (bf16)
    gemm2_k<128, 128, true, 1, 0, false><<<gE, blk, 0, stream>>>(
        m_st, WTall + o_mktw, nullptr, T16, EE, nullptr, B1, nullptr, nullptr, nullptr);
    // mkt = act(tpre @ W_down) -> mkt_b (bf16)
    gemm2_k<128, 64, true, 0, 0, true><<<gE, blk, 0, stream>>>(
        T16, WTall + o_down, nullptr, mkt_b, EE, nullptr, nullptr, nullptr, nullptr, nullptr);
    // bilinear -> xb_b (bf16)
    bilinear3_k<<<EE / 32, dim3(512), 0, stream>>>(
        mkt_b, cbf_rbfW1, cbf_sph, id3_kt, WTbil, xb_b);
    // x = C*x_skip + 0.5*act(xb @ W_st3)   (EPI5, in-place B0)
    gemm2_k<64, 128, true, 5, 0, true><<<gE, blk, 0, stream>>>(
        xb_b, WTall + o_st3, B0, nullptr, EE, nullptr, nullptr, nullptr, nullptr, nullptr);
    // x[inv[j]] += 0.5*act(xb @ W_ts3)[j]  (EPI4)
    gemm2_k<64, 128, true, 4, 0, true><<<gE, blk, 0, stream>>>(
        xb_b, WTall + o_ts3, B0, nullptr, EE, nullptr, nullptr, nullptr, inv, nullptr);

    // res_before + m_st merge
    gemm2_k<128, 128, true, 0, 0, false><<<gE, blk, 0, stream>>>(
        B0, WTall + o_rb0, nullptr, T16, EE, nullptr, nullptr, nullptr, nullptr, nullptr);
    gemm2_k<128, 128, true, 3, 0, true><<<gE, blk, 0, stream>>>(
        T16, WTall + o_rb1, B0, nullptr, EE, B0, m_st, nullptr, nullptr, nullptr);
    // res_after x2
    gemm2_k<128, 128, true, 0, 0, false><<<gE, blk, 0, stream>>>(
        B0, WTall + o_ra0, nullptr, T16, EE, nullptr, nullptr, nullptr, nullptr, nullptr);
    gemm2_k<128, 128, true, 2, 0, true><<<gE, blk, 0, stream>>>(
        T16, WTall + o_ra1, B0, nullptr, EE, B0, nullptr, nullptr, nullptr, nullptr);
    gemm2_k<128, 128, true, 0, 0, false><<<gE, blk, 0, stream>>>(
        B0, WTall + o_ra2, nullptr, T16, EE, nullptr, nullptr, nullptr, nullptr, nullptr);
    gemm2_k<128, 128, true, 2, 0, true><<<gE, blk, 0, stream>>>(
        T16, WTall + o_ra3, B0, nullptr, EE, B0, nullptr, nullptr, nullptr, nullptr);

    // coef = rbf_h @ W_ae_rbf -> B1 ; h2 = segment_sum(x*coef) -> B5
    rbf_gemm_k<<<gE, blk, 0, stream>>>(rbf_h, W_ae_rbf, B1, EE);
    hipMemsetAsync(B5, 0, (size_t)NA * 128 * sizeof(float), stream);
    scatter_k<<<EE * 32 / 256, blk, 0, stream>>>((const float4*)B0, (const float4*)B1, idx_t, B5);

    // atom chain
    gemm2_k<128, 128, true, 0, 0, false><<<gN, blk, 0, stream>>>(
        B5, WTall + o_aein, B6, nullptr, NA, nullptr, nullptr, nullptr, nullptr, nullptr);
    gemm2_k<128, 128, true, 0, 0, false><<<gN, blk, 0, stream>>>(
        B6, WTall + o_rat0, nullptr, T16, NA, nullptr, nullptr, nullptr, nullptr, nullptr);
    gemm2_k<128, 128, true, 2, 0, true><<<gN, blk, 0, stream>>>(
        T16, WTall + o_rat1, B6, nullptr, NA, B6, nullptr, nullptr, nullptr, nullptr);
    gemm2_k<128, 128, true, 0, 0, false><<<gN, blk, 0, stream>>>(
        B6, WTall + o_rat2, nullptr, T16, NA, nullptr, nullptr, nullptr, nullptr, nullptr);
    gemm2_k<128, 128, true, 2, 0, true><<<gN, blk, 0, stream>>>(
        T16, WTall + o_rat3, out_h, nullptr, NA, B6, nullptr, nullptr, nullptr, nullptr);

    // ASI: m = act([h[idx_s]|h[idx_t]|x] @ W_asi) -> B1 (f32)
    gemm2_k<384, 128, true, 0, 1, false><<<gE, blk, 0, stream>>>(
        B0, WTall + o_asi, B1, nullptr, EE, nullptr, nullptr, out_h, idx_s, idx_t);

    // res_m x2, final + x merge
    gemm2_k<128, 128, true, 0, 0, false><<<gE, blk, 0, stream>>>(
        B1, WTall + o_rm0, nullptr, T16, EE, nullptr, nullptr, nullptr, nullptr, nullptr);
    gemm2_k<128, 128, true, 2, 0, true><<<gE, blk, 0, stream>>>(
        T16, WTall + o_rm1, B1, nullptr, EE, B1, nullptr, nullptr, nullptr, nullptr);
    gemm2_k<128, 128, true, 0, 0, false><<<gE, blk, 0, stream>>>(
        B1, WTall + o_rm2, nullptr, T16, EE, nullptr, nullptr, nullptr, nullptr, nullptr);
    gemm2_k<128, 128, true, 3, 0, true><<<gE, blk, 0, stream>>>(
        T16, WTall + o_rm3, out_m, nullptr, EE, B1, B0, nullptr, nullptr, nullptr);
}

// Round 4
// 1138.106 us; speedup vs baseline: 3.0094x; 1.2966x over previous
//
#include <hip/hip_runtime.h>

// ---------------------------------------------------------------------------
// GemNet InteractionBlock forward, MI355X (gfx950).
// Round 4: fused transposed-MFMA MLP chains (intermediates stay in LDS),
// sort-based segment_sum (no atomics on the hot path), bilinear w/ readlane.
// ---------------------------------------------------------------------------

#define EE 120000
#define NA 10000

constexpr float C_INV = 0.70710678118654752440f;

using f32x4 = __attribute__((ext_vector_type(4))) float;
using f32x2 = __attribute__((ext_vector_type(2))) float;
using s16x8 = __attribute__((ext_vector_type(8))) short;
using s16x4 = __attribute__((ext_vector_type(4))) short;

__device__ __forceinline__ float act_silu(float x) { return x / (1.0f + __expf(-x)); }

__device__ __forceinline__ unsigned short f2bf(float f) {
    unsigned int u = __float_as_uint(f);
    u += 0x7fffu + ((u >> 16) & 1u);
    return (unsigned short)(u >> 16);
}
__device__ __forceinline__ float bf2f(unsigned short h) {
    return __uint_as_float(((unsigned int)h) << 16);
}

// ---------------------------------------------------------------------------
// Transposed GEMM tile: D[outF][row] += W[outF][k] * act[row][k]
// a-op = weights (global, [outF][KW] bf16, pre-offset to wave base+chunk),
// b-op = activations (LDS, row-major [row][*] bf16, XOR-swizzled, RS bytes).
// Output frag (mt,nf): outF = mt*16 + (l>>4)*4 + q, row = nf*16 + (l&15).
// ---------------------------------------------------------------------------
template<int MT, int KQ>
__device__ __forceinline__ void gemmT(
    const char* ldsB, int RS,
    const unsigned short* W, int KW,
    int rowBase, int l, f32x4 (&acc)[MT][4])
{
    const int fr = l & 15;
    const int k8 = (l >> 4) << 3;
    #pragma unroll
    for (int kq = 0; kq < KQ; ++kq) {
        s16x8 b[4];
        #pragma unroll
        for (int nf = 0; nf < 4; ++nf) {
            const int row = rowBase + nf * 16 + fr;
            const int kb  = ((kq * 32 + k8) * 2) ^ ((row & 7) << 4);
            b[nf] = *(const s16x8*)(ldsB + row * RS + kb);
        }
        s16x8 a[MT];
        #pragma unroll
        for (int mt = 0; mt < MT; ++mt)
            a[mt] = *(const s16x8*)&W[(size_t)(mt * 16 + fr) * KW + kq * 32 + k8];
        #pragma unroll
        for (int mt = 0; mt < MT; ++mt)
            #pragma unroll
            for (int nf = 0; nf < 4; ++nf)
                acc[mt][nf] = __builtin_amdgcn_mfma_f32_16x16x32_bf16(
                    a[mt], b[nf], acc[mt][nf], 0, 0, 0);
    }
}

template<int MT>
__device__ __forceinline__ void zacc(f32x4 (&acc)[MT][4])
{
    #pragma unroll
    for (int mt = 0; mt < MT; ++mt)
        #pragma unroll
        for (int nf = 0; nf < 4; ++nf)
            acc[mt][nf] = (f32x4){0.f, 0.f, 0.f, 0.f};
}

// pack 4 contiguous out-features (bf16) into swizzled LDS act buffer
__device__ __forceinline__ void packA(char* lds, int RS, int row, int outF0, f32x4 v)
{
    s16x4 p;
    p[0] = (short)f2bf(v[0]); p[1] = (short)f2bf(v[1]);
    p[2] = (short)f2bf(v[2]); p[3] = (short)f2bf(v[3]);
    *(s16x4*)(lds + row * RS + ((outF0 * 2) ^ ((row & 7) << 4))) = p;
}

// stage 128 rows x 128 f32 -> swizzled bf16 LDS (RS=256)
__device__ __forceinline__ void stage_f32(char* lds, const float* __restrict__ src,
                                          int row0, int M, int tid)
{
    #pragma unroll
    for (int u = 0; u < 8; ++u) {
        const int flat = tid + u * 256;
        const int row  = flat >> 4;
        const int k8   = (flat & 15) << 3;
        const int grow = row0 + row;
        s16x8 val = {0, 0, 0, 0, 0, 0, 0, 0};
        if (grow < M) {
            const float* p = src + (size_t)grow * 128 + k8;
            f32x4 lo = *(const f32x4*)p;
            f32x4 hi = *(const f32x4*)(p + 4);
            #pragma unroll
            for (int i = 0; i < 4; ++i) {
                val[i]     = (short)f2bf(lo[i]);
                val[i + 4] = (short)f2bf(hi[i]);
            }
        }
        *(s16x8*)(lds + row * 256 + ((k8 * 2) ^ ((row & 7) << 4))) = val;
    }
}

// ---------------------------------------------------------------------------
// one ResidualLayer: inter = act(x@W0); y = act(inter@W1); x = (x+y)*C
// entry: x packed in A (and in regs); exit: same. MSTM adds (x+m_st)*C after.
// ---------------------------------------------------------------------------
template<bool MSTM>
__device__ __forceinline__ void res_layer(
    char* A, char* B,
    const unsigned short* W0, const unsigned short* W1,
    int wm, int wn, int l, f32x4 (&x)[4][4],
    const float* __restrict__ mst, int row0, int M)
{
    const int fr = l & 15;
    const int fq = (l >> 4) << 2;
    f32x4 acc[4][4];
    zacc<4>(acc);
    gemmT<4, 4>(A, 256, W0 + (size_t)(wm * 64) * 128, 128, wn * 64, l, acc);
    #pragma unroll
    for (int mt = 0; mt < 4; ++mt)
        #pragma unroll
        for (int nf = 0; nf < 4; ++nf) {
            const int row = wn * 64 + nf * 16 + fr;
            const int of0 = wm * 64 + mt * 16 + fq;
            f32x4 v;
            #pragma unroll
            for (int q = 0; q < 4; ++q) v[q] = act_silu(acc[mt][nf][q]);
            packA(B, 256, row, of0, v);
        }
    __syncthreads();
    zacc<4>(acc);
    gemmT<4, 4>(B, 256, W1 + (size_t)(wm * 64) * 128, 128, wn * 64, l, acc);
    #pragma unroll
    for (int mt = 0; mt < 4; ++mt)
        #pragma unroll
        for (int nf = 0; nf < 4; ++nf) {
            const int row = wn * 64 + nf * 16 + fr;
            const int of0 = wm * 64 + mt * 16 + fq;
            #pragma unroll
            for (int q = 0; q < 4; ++q)
                x[mt][nf][q] = (x[mt][nf][q] + act_silu(acc[mt][nf][q])) * C_INV;
            if (MSTM) {
                const int grow = row0 + row;
                if (grow < M) {
                    f32x4 mv = *(const f32x4*)&mst[(size_t)grow * 128 + of0];
                    #pragma unroll
                    for (int q = 0; q < 4; ++q)
                        x[mt][nf][q] = (x[mt][nf][q] + mv[q]) * C_INV;
                }
            }
            packA(A, 256, row, of0, x[mt][nf]);
        }
    __syncthreads();
}

// ---------------------------------------------------------------------------
// front: tpre = act(m_st@W_m_kt)*scale ; mkt = act(tpre@W_down)  (bf16 out)
// ---------------------------------------------------------------------------
__global__ __launch_bounds__(256) void front_k(
    const float* __restrict__ m_st, const unsigned short* __restrict__ scale_b,
    const unsigned short* __restrict__ Wmkt, const unsigned short* __restrict__ Wdown,
    unsigned short* __restrict__ mkt_b)
{
    __shared__ char A[128 * 256];
    const int tid = threadIdx.x;
    const int l = tid & 63, w = tid >> 6, wm = w >> 1, wn = w & 1;
    const int fr = l & 15, fq = (l >> 4) << 2;
    const int row0 = blockIdx.x * 128;

    stage_f32(A, m_st, row0, EE, tid);
    __syncthreads();

    f32x4 acc[4][4];
    zacc<4>(acc);
    gemmT<4, 4>(A, 256, Wmkt + (size_t)(wm * 64) * 128, 128, wn * 64, l, acc);
    __syncthreads();
    #pragma unroll
    for (int mt = 0; mt < 4; ++mt)
        #pragma unroll
        for (int nf = 0; nf < 4; ++nf) {
            const int row = wn * 64 + nf * 16 + fr;
            const int grow = row0 + row;
            const int of0 = wm * 64 + mt * 16 + fq;
            f32x4 v = {0.f, 0.f, 0.f, 0.f};
            if (grow < EE) {
                s16x4 sc = *(const s16x4*)&scale_b[(size_t)grow * 128 + of0];
                #pragma unroll
                for (int q = 0; q < 4; ++q)
                    v[q] = act_silu(acc[mt][nf][q]) * bf2f((unsigned short)sc[q]);
            }
            packA(A, 256, row, of0, v);
        }
    __syncthreads();

    f32x4 acc2[2][4];
    zacc<2>(acc2);
    gemmT<2, 4>(A, 256, Wdown + (size_t)(wm * 32) * 128, 128, wn * 64, l, acc2);
    #pragma unroll
    for (int mt = 0; mt < 2; ++mt)
        #pragma unroll
        for (int nf = 0; nf < 4; ++nf) {
            const int row = wn * 64 + nf * 16 + fr;
            const int grow = row0 + row;
            if (grow >= EE) continue;
            const int of0 = wm * 32 + mt * 16 + fq;
            s16x4 p;
            #pragma unroll
            for (int q = 0; q < 4; ++q) p[q] = (short)f2bf(act_silu(acc2[mt][nf][q]));
            *(s16x4*)&mkt_b[(size_t)grow * 64 + of0] = p;
        }
}

// ---------------------------------------------------------------------------
// st3/ts3: y_st = act(xb@W_st3), y_ts = act(xb@W_ts3)  (both bf16)
// ---------------------------------------------------------------------------
__global__ __launch_bounds__(256) void st3ts3_k(
    const unsigned short* __restrict__ xb_b,
    const unsigned short* __restrict__ Wst3, const unsigned short* __restrict__ Wts3,
    unsigned short* __restrict__ yst, unsigned short* __restrict__ yts)
{
    __shared__ char A[128 * 128];
    const int tid = threadIdx.x;
    const int l = tid & 63, w = tid >> 6, wm = w >> 1, wn = w & 1;
    const int fr = l & 15, fq = (l >> 4) << 2;
    const int row0 = blockIdx.x * 128;

    #pragma unroll
    for (int u = 0; u < 4; ++u) {
        const int flat = tid + u * 256;
        const int row = flat >> 3;
        const int k8 = (flat & 7) << 3;
        const int grow = row0 + row;
        s16x8 v = {0, 0, 0, 0, 0, 0, 0, 0};
        if (grow < EE) v = *(const s16x8*)&xb_b[(size_t)grow * 64 + k8];
        *(s16x8*)(A + row * 128 + ((k8 * 2) ^ ((row & 7) << 4))) = v;
    }
    __syncthreads();

    f32x4 aS[4][4], aT[4][4];
    zacc<4>(aS); zacc<4>(aT);
    gemmT<4, 2>(A, 128, Wst3 + (size_t)(wm * 64) * 64, 64, wn * 64, l, aS);
    gemmT<4, 2>(A, 128, Wts3 + (size_t)(wm * 64) * 64, 64, wn * 64, l, aT);

    #pragma unroll
    for (int mt = 0; mt < 4; ++mt)
        #pragma unroll
        for (int nf = 0; nf < 4; ++nf) {
            const int row = wn * 64 + nf * 16 + fr;
            const int grow = row0 + row;
            if (grow >= EE) continue;
            const int of0 = wm * 64 + mt * 16 + fq;
            s16x4 p, q4;
            #pragma unroll
            for (int q = 0; q < 4; ++q) {
                p[q]  = (short)f2bf(act_silu(aS[mt][nf][q]));
                q4[q] = (short)f2bf(act_silu(aT[mt][nf][q]));
            }
            *(s16x4*)&yst[(size_t)grow * 128 + of0] = p;
            *(s16x4*)&yts[(size_t)grow * 128 + of0] = q4;
        }
}

// ---------------------------------------------------------------------------
// chain: x_skip GEMM + (y_st + y_ts[swap]) merge + resb + m_st merge + resa x2
// outputs x (f32) and x_b (bf16)
// ---------------------------------------------------------------------------
__global__ __launch_bounds__(256) void chain_k(
    const float* __restrict__ m_st,
    const unsigned short* __restrict__ yst, const unsigned short* __restrict__ yts,
    const int* __restrict__ idx_swap,
    const unsigned short* __restrict__ Wmlp,
    const unsigned short* __restrict__ Wrb0, const unsigned short* __restrict__ Wrb1,
    const unsigned short* __restrict__ Wra0, const unsigned short* __restrict__ Wra1,
    const unsigned short* __restrict__ Wra2, const unsigned short* __restrict__ Wra3,
    float* __restrict__ x_out, unsigned short* __restrict__ xb_out)
{
    __shared__ char A[128 * 256];
    __shared__ char B[128 * 256];
    const int tid = threadIdx.x;
    const int l = tid & 63, w = tid >> 6, wm = w >> 1, wn = w & 1;
    const int fr = l & 15, fq = (l >> 4) << 2;
    const int row0 = blockIdx.x * 128;

    stage_f32(A, m_st, row0, EE, tid);
    __syncthreads();

    f32x4 acc[4][4];
    zacc<4>(acc);
    gemmT<4, 4>(A, 256, Wmlp + (size_t)(wm * 64) * 128, 128, wn * 64, l, acc);

    f32x4 x[4][4];
    #pragma unroll
    for (int mt = 0; mt < 4; ++mt)
        #pragma unroll
        for (int nf = 0; nf < 4; ++nf) {
            const int row = wn * 64 + nf * 16 + fr;
            const int grow = row0 + row;
            const int of0 = wm * 64 + mt * 16 + fq;
            if (grow < EE) {
                s16x4 a = *(const s16x4*)&yst[(size_t)grow * 128 + of0];
                const int sw = idx_swap[grow];
                s16x4 b = *(const s16x4*)&yts[(size_t)sw * 128 + of0];
                #pragma unroll
                for (int q = 0; q < 4; ++q)
                    x[mt][nf][q] = (acc[mt][nf][q] +
                        (bf2f((unsigned short)a[q]) + bf2f((unsigned short)b[q])) * C_INV) * C_INV;
            } else {
                x[mt][nf] = (f32x4){0.f, 0.f, 0.f, 0.f};
            }
        }
    __syncthreads();
    #pragma unroll
    for (int mt = 0; mt < 4; ++mt)
        #pragma unroll
        for (int nf = 0; nf < 4; ++nf)
            packA(A, 256, wn * 64 + nf * 16 + fr, wm * 64 + mt * 16 + fq, x[mt][nf]);
    __syncthreads();

    res_layer<true >(A, B, Wrb0, Wrb1, wm, wn, l, x, m_st, row0, EE);
    res_layer<false>(A, B, Wra0, Wra1, wm, wn, l, x, m_st, row0, EE);
    res_layer<false>(A, B, Wra2, Wra3, wm, wn, l, x, m_st, row0, EE);

    #pragma unroll
    for (int mt = 0; mt < 4; ++mt)
        #pragma unroll
        for (int nf = 0; nf < 4; ++nf) {
            const int row = wn * 64 + nf * 16 + fr;
            const int grow = row0 + row;
            if (grow >= EE) continue;
            const int of0 = wm * 64 + mt * 16 + fq;
            *(f32x4*)&x_out[(size_t)grow * 128 + of0] = x[mt][nf];
            s16x4 p;
            #pragma unroll
            for (int q = 0; q < 4; ++q) p[q] = (short)f2bf(x[mt][nf][q]);
            *(s16x4*)&xb_out[(size_t)grow * 128 + of0] = p;
        }
}

// ---------------------------------------------------------------------------
// atom chain: h3 = act(h2@W_ae_in); res_atom x2 -> out_h (f32) + h_b (bf16)
// ---------------------------------------------------------------------------
__global__ __launch_bounds__(256) void atom_k(
    const float* __restrict__ h2,
    const unsigned short* __restrict__ Wae,
    const unsigned short* __restrict__ Wr0, const unsigned short* __restrict__ Wr1,
    const unsigned short* __restrict__ Wr2, const unsigned short* __restrict__ Wr3,
    float* __restrict__ out_h, unsigned short* __restrict__ h_b)
{
    __shared__ char A[128 * 256];
    __shared__ char B[128 * 256];
    const int tid = threadIdx.x;
    const int l = tid & 63, w = tid >> 6, wm = w >> 1, wn = w & 1;
    const int fr = l & 15, fq = (l >> 4) << 2;
    const int row0 = blockIdx.x * 128;

    stage_f32(A, h2, row0, NA, tid);
    __syncthreads();

    f32x4 acc[4][4];
    zacc<4>(acc);
    gemmT<4, 4>(A, 256, Wae + (size_t)(wm * 64) * 128, 128, wn * 64, l, acc);
    f32x4 x[4][4];
    #pragma unroll
    for (int mt = 0; mt < 4; ++mt)
        #pragma unroll
        for (int nf = 0; nf < 4; ++nf)
            #pragma unroll
            for (int q = 0; q < 4; ++q)
                x[mt][nf][q] = act_silu(acc[mt][nf][q]);
    __syncthreads();
    #pragma unroll
    for (int mt = 0; mt < 4; ++mt)
        #pragma unroll
        for (int nf = 0; nf < 4; ++nf)
            packA(A, 256, wn * 64 + nf * 16 + fr, wm * 64 + mt * 16 + fq, x[mt][nf]);
    __syncthreads();

    res_layer<false>(A, B, Wr0, Wr1, wm, wn, l, x, nullptr, row0, NA);
    res_layer<false>(A, B, Wr2, Wr3, wm, wn, l, x, nullptr, row0, NA);

    #pragma unroll
    for (int mt = 0; mt < 4; ++mt)
        #pragma unroll
        for (int nf = 0; nf < 4; ++nf) {
            const int row = wn * 64 + nf * 16 + fr;
            const int grow = row0 + row;
            if (grow >= NA) continue;
            const int of0 = wm * 64 + mt * 16 + fq;
            *(f32x4*)&out_h[(size_t)grow * 128 + of0] = x[mt][nf];
            s16x4 p;
            #pragma unroll
            for (int q = 0; q < 4; ++q) p[q] = (short)f2bf(x[mt][nf][q]);
            *(s16x4*)&h_b[(size_t)grow * 128 + of0] = p;
        }
}

// ---------------------------------------------------------------------------
// ASI + res_m: m = act([h[s]|h[t]|x]@W_asi); res_m x2; out_m = (m + x)*C
// ---------------------------------------------------------------------------
__global__ __launch_bounds__(256) void asi_k(
    const unsigned short* __restrict__ h_b, const unsigned short* __restrict__ x_b,
    const float* __restrict__ x_f32,
    const int* __restrict__ idx_s, const int* __restrict__ idx_t,
    const unsigned short* __restrict__ Wasi,
    const unsigned short* __restrict__ Wm0, const unsigned short* __restrict__ Wm1,
    const unsigned short* __restrict__ Wm2, const unsigned short* __restrict__ Wm3,
    float* __restrict__ out_m)
{
    __shared__ char A[128 * 256];
    __shared__ char B[128 * 256];
    const int tid = threadIdx.x;
    const int l = tid & 63, w = tid >> 6, wm = w >> 1, wn = w & 1;
    const int fr = l & 15, fq = (l >> 4) << 2;
    const int row0 = blockIdx.x * 128;

    f32x4 acc[4][4];
    zacc<4>(acc);

    for (int c = 0; c < 3; ++c) {
        #pragma unroll
        for (int u = 0; u < 8; ++u) {
            const int flat = tid + u * 256;
            const int row = flat >> 4;
            const int k8 = (flat & 15) << 3;
            const int grow = row0 + row;
            s16x8 v = {0, 0, 0, 0, 0, 0, 0, 0};
            if (grow < EE) {
                const unsigned short* src =
                    (c == 0) ? h_b + (size_t)idx_s[grow] * 128
                  : (c == 1) ? h_b + (size_t)idx_t[grow] * 128
                             : x_b + (size_t)grow * 128;
                v = *(const s16x8*)&src[k8];
            }
            *(s16x8*)(A + row * 256 + ((k8 * 2) ^ ((row & 7) << 4))) = v;
        }
        __syncthreads();
        gemmT<4, 4>(A, 256, Wasi + (size_t)(wm * 64) * 384 + c * 128, 384, wn * 64, l, acc);
        __syncthreads();
    }

    f32x4 x[4][4];
    #pragma unroll
    for (int mt = 0; mt < 4; ++mt)
        #pragma unroll
        for (int nf = 0; nf < 4; ++nf)
            #pragma unroll
            for (int q = 0; q < 4; ++q)
                x[mt][nf][q] = act_silu(acc[mt][nf][q]);
    #pragma unroll
    for (int mt = 0; mt < 4; ++mt)
        #pragma unroll
        for (int nf = 0; nf < 4; ++nf)
            packA(A, 256, wn * 64 + nf * 16 + fr, wm * 64 + mt * 16 + fq, x[mt][nf]);
    __syncthreads();

    res_layer<false>(A, B, Wm0, Wm1, wm, wn, l, x, nullptr, row0, EE);
    res_layer<false>(A, B, Wm2, Wm3, wm, wn, l, x, nullptr, row0, EE);

    #pragma unroll
    for (int mt = 0; mt < 4; ++mt)
        #pragma unroll
        for (int nf = 0; nf < 4; ++nf) {
            const int row = wn * 64 + nf * 16 + fr;
            const int grow = row0 + row;
            if (grow >= EE) continue;
            const int of0 = wm * 64 + mt * 16 + fq;
            f32x4 xv = *(const f32x4*)&x_f32[(size_t)grow * 128 + of0];
            f32x4 o;
            #pragma unroll
            for (int q = 0; q < 4; ++q) o[q] = (x[mt][nf][q] + xv[q]) * C_INV;
            *(f32x4*)&out_m[(size_t)grow * 128 + of0] = o;
        }
}

// ---------------------------------------------------------------------------
// rbf scale: scale = rbf3 @ W_t_rbf -> bf16
// ---------------------------------------------------------------------------
__global__ __launch_bounds__(256) void rbf_scale_k(
    const float* __restrict__ A, const float* __restrict__ W,
    unsigned short* __restrict__ out, int M)
{
    __shared__ float Ws[16][128];
    const int tid = threadIdx.x;
    #pragma unroll
    for (int t = tid; t < 512; t += 256) {
        int kk = t >> 5, c4 = (t & 31) << 2;
        *(float4*)&Ws[kk][c4] = *(const float4*)(W + kk * 128 + c4);
    }
    __syncthreads();
    const int tx = tid & 31, ty = tid >> 5;
    const int row0 = blockIdx.x * 128;
    #pragma unroll
    for (int i = 0; i < 16; ++i) {
        const int row = row0 + ty + i * 8;
        if (row >= M) continue;
        float av[16];
        #pragma unroll
        for (int j = 0; j < 4; ++j) {
            float4 a = *(const float4*)(A + (size_t)row * 16 + j * 4);
            av[j * 4] = a.x; av[j * 4 + 1] = a.y; av[j * 4 + 2] = a.z; av[j * 4 + 3] = a.w;
        }
        float4 s = make_float4(0.f, 0.f, 0.f, 0.f);
        #pragma unroll
        for (int k = 0; k < 16; ++k) {
            float4 wv = *(const float4*)&Ws[k][tx * 4];
            s.x += av[k] * wv.x; s.y += av[k] * wv.y;
            s.z += av[k] * wv.z; s.w += av[k] * wv.w;
        }
        s16x4 p;
        p[0] = (short)f2bf(s.x); p[1] = (short)f2bf(s.y);
        p[2] = (short)f2bf(s.z); p[3] = (short)f2bf(s.w);
        *(s16x4*)&out[(size_t)row * 128 + tx * 4] = p;
    }
}

// ---------------------------------------------------------------------------
// counting sort of idx_t + gather segment-sum with fused coef
// ---------------------------------------------------------------------------
__global__ void hist_k(const int* __restrict__ idxt, int* __restrict__ cnt)
{
    int i = blockIdx.x * 256 + threadIdx.x;
    if (i < EE) atomicAdd(&cnt[idxt[i]], 1);
}

__global__ __launch_bounds__(256) void scan_k(const int* __restrict__ cnt,
                                              int* __restrict__ start, int* __restrict__ wrk)
{
    __shared__ int ps[256];
    const int t = threadIdx.x;
    int s = 0;
    for (int j = 0; j < 40; ++j) {
        int idx = t * 40 + j;
        if (idx < NA) s += cnt[idx];
    }
    ps[t] = s;
    __syncthreads();
    for (int off = 1; off < 256; off <<= 1) {
        int v = (t >= off) ? ps[t - off] : 0;
        __syncthreads();
        ps[t] += v;
        __syncthreads();
    }
    int run = ps[t] - s;   // exclusive
    for (int j = 0; j < 40; ++j) {
        int idx = t * 40 + j;
        if (idx < NA) {
            start[idx] = run;
            wrk[idx] = run;
            run += cnt[idx];
        }
    }
    if (t == 255) start[NA] = ps[255];
}

__global__ void place_k(const int* __restrict__ idxt, int* __restrict__ wrk,
                        int* __restrict__ order)
{
    int i = blockIdx.x * 256 + threadIdx.x;
    if (i < EE) {
        int pos = atomicAdd(&wrk[idxt[i]], 1);
        order[pos] = i;
    }
}

// one wave per atom: h2[a] = sum_{e in bucket} x_b[e] * (rbf_h[e] @ W_ae_rbf)
__global__ __launch_bounds__(256) void segsum_k(
    const unsigned short* __restrict__ x_b, const float* __restrict__ rbf_h,
    const float* __restrict__ Wae, const int* __restrict__ start,
    const int* __restrict__ order, float* __restrict__ h2)
{
    const int tid = threadIdx.x;
    const int l = tid & 63, w = tid >> 6;
    const int a = blockIdx.x * 4 + w;
    if (a >= NA) return;

    float wc[32];
    #pragma unroll
    for (int j = 0; j < 16; ++j) {
        f32x2 v = *(const f32x2*)(Wae + j * 128 + 2 * l);
        wc[2 * j] = v[0]; wc[2 * j + 1] = v[1];
    }

    const int s = start[a], e_end = start[a + 1];
    float acc0 = 0.f, acc1 = 0.f;
    for (int i = s; i < e_end; ++i) {
        const int e = __builtin_amdgcn_readfirstlane(order[i]);
        const unsigned int xv = *(const unsigned int*)(x_b + (size_t)e * 128 + 2 * l);
        const float* rp = rbf_h + (size_t)e * 16;
        float c0 = 0.f, c1 = 0.f;
        #pragma unroll
        for (int j = 0; j < 16; ++j) {
            float r = rp[j];
            c0 += r * wc[2 * j];
            c1 += r * wc[2 * j + 1];
        }
        acc0 += bf2f((unsigned short)(xv & 0xffff)) * c0;
        acc1 += bf2f((unsigned short)(xv >> 16)) * c1;
    }
    f32x2 o; o[0] = acc0; o[1] = acc1;
    *(f32x2*)&h2[(size_t)a * 128 + 2 * l] = o;
}

// ---------------------------------------------------------------------------
// weight conversions
// ---------------------------------------------------------------------------
__global__ void wconv_k(const float* __restrict__ Wbil, unsigned short* __restrict__ WT)
{
    int t = blockIdx.x * 256 + threadIdx.x;
    int u = t >> 10, k = t & 1023, j = k >> 6, c = k & 63;
    WT[t] = f2bf(Wbil[(size_t)(c * 16 + j) * 64 + u]);
}

struct WDesc { const float* src; int K; int N; int off; };
struct WTab  { WDesc d[21]; };

__global__ void wconvall_k(WTab tab, unsigned short* __restrict__ dst)
{
    WDesc d = tab.d[blockIdx.x];
    const int tot = d.K * d.N;
    for (int i = threadIdx.x; i < tot; i += 256) {
        int n = i / d.K, k = i - n * d.K;
        dst[d.off + i] = f2bf(d.src[(size_t)k * d.N + n]);
    }
}

// ---------------------------------------------------------------------------
// bilinear (unchanged from round 3)
// ---------------------------------------------------------------------------
__device__ __forceinline__ float rlc(const f32x4& cv, int idx, int lbase)
{
    const int c = idx & 3;
    float comp = (c == 0) ? cv[0] : (c == 1) ? cv[1] : (c == 2) ? cv[2] : cv[3];
    return __uint_as_float(__builtin_amdgcn_readlane(__float_as_uint(comp),
                                                     lbase + (idx >> 2)));
}

__global__ __launch_bounds__(512) void bilinear3_k(
    const unsigned short* __restrict__ mkt,
    const float* __restrict__ rbfW1,
    const float* __restrict__ sph,
    const int*   __restrict__ id3kt,
    const unsigned short* __restrict__ WT,
    unsigned short* __restrict__ xb)
{
    __shared__ unsigned short aS[32 * 1024];
    float* pS = (float*)aS;

    const int tid = threadIdx.x;
    const int l   = tid & 63;
    const int w   = tid >> 6;
    const int e0  = blockIdx.x * 32;

    s16x8 bfrag[4][4];
    {
        const int u  = l & 15;
        const int kh = w * 128 + ((l >> 4) << 3);
        #pragma unroll
        for (int nt = 0; nt < 4; ++nt)
            #pragma unroll
            for (int kq = 0; kq < 4; ++kq)
                bfrag[nt][kq] = *(const s16x8*)&WT[(size_t)(nt * 16 + u) * 1024 + kh + kq * 32];
    }

    #pragma unroll
    for (int r = 0; r < 4; ++r) {
        const int eL = r * 8 + w;
        const int eG = e0 + eL;

        f32x4 cv = {0.f, 0.f, 0.f, 0.f};
        if (l < 14)       cv = *(const f32x4*)(sph   + (size_t)eG * 56  + l * 4);
        else if (l < 42)  cv = *(const f32x4*)(rbfW1 + (size_t)eG * 112 + (l - 14) * 4);

        float m2r[8];
        #pragma unroll
        for (int k = 0; k < 8; ++k)
            m2r[k] = bf2f(mkt[(size_t)id3kt[eG * 8 + k] * 64 + l]);

        float sk[7] = {0.f, 0.f, 0.f, 0.f, 0.f, 0.f, 0.f};
        #pragma unroll
        for (int k = 0; k < 8; ++k)
            #pragma unroll
            for (int s = 0; s < 7; ++s)
                sk[s] += rlc(cv, k * 7 + s, 0) * m2r[k];

        unsigned short* arow = aS + eL * 1024;
        const int lsw = l ^ ((eL & 7) << 3);
        #pragma unroll
        for (int j = 0; j < 16; ++j) {
            float av = 0.f;
            #pragma unroll
            for (int s = 0; s < 7; ++s)
                av += rlc(cv, j * 7 + s, 14) * sk[s];
            arow[j * 64 + lsw] = f2bf(av);
        }
    }
    __syncthreads();

    f32x4 acc[2][4];
    #pragma unroll
    for (int mt = 0; mt < 2; ++mt)
        #pragma unroll
        for (int nt = 0; nt < 4; ++nt)
            acc[mt][nt] = (f32x4){0.f, 0.f, 0.f, 0.f};

    const int kbase = w * 128 + ((l >> 4) << 3);
    #pragma unroll
    for (int kq = 0; kq < 4; ++kq) {
        s16x8 afr[2];
        #pragma unroll
        for (int mt = 0; mt < 2; ++mt) {
            const int row = mt * 16 + (l & 15);
            const int kk  = (kbase + kq * 32) ^ ((row & 7) << 3);
            afr[mt] = *(const s16x8*)&aS[row * 1024 + kk];
        }
        #pragma unroll
        for (int mt = 0; mt < 2; ++mt)
            #pragma unroll
            for (int nt = 0; nt < 4; ++nt)
                acc[mt][nt] = __builtin_amdgcn_mfma_f32_16x16x32_bf16(
                    afr[mt], bfrag[nt][kq], acc[mt][nt], 0, 0, 0);
    }
    __syncthreads();

    #pragma unroll
    for (int mt = 0; mt < 2; ++mt)
        #pragma unroll
        for (int nt = 0; nt < 4; ++nt)
            #pragma unroll
            for (int q = 0; q < 4; ++q) {
                const int e = mt * 16 + ((l >> 4) << 2) + q;
                const int u = nt * 16 + (l & 15);
                pS[(w * 32 + e) * 64 + u] = acc[mt][nt][q];
            }
    __syncthreads();

    {
        const int e  = tid >> 4;
        const int u0 = (tid & 15) << 2;
        f32x4 s = (f32x4){0.f, 0.f, 0.f, 0.f};
        #pragma unroll
        for (int ww = 0; ww < 8; ++ww)
            s += *(const f32x4*)&pS[(ww * 32 + e) * 64 + u0];
        s16x4 ov;
        #pragma unroll
        for (int i = 0; i < 4; ++i) ov[i] = (short)f2bf(s[i]);
        *(s16x4*)&xb[(size_t)(e0 + e) * 64 + u0] = ov;
    }
}

// ---------------------------------------------------------------------------
// launch
// ---------------------------------------------------------------------------
extern "C" void kernel_launch(void* const* d_in, const int* in_sizes, int n_in,
                              void* d_out, int out_size, void* d_ws, size_t ws_size,
                              hipStream_t stream)
{
    const float* m_st      = (const float*)d_in[1];
    const float* rbf_h     = (const float*)d_in[2];
    const float* rbf3      = (const float*)d_in[3];
    const float* cbf_rbfW1 = (const float*)d_in[4];
    const float* cbf_sph   = (const float*)d_in[5];
    const float* W_mlp_st  = (const float*)d_in[6];
    const float* W_m_kt    = (const float*)d_in[7];
    const float* W_t_rbf   = (const float*)d_in[8];
    const float* W_down    = (const float*)d_in[9];
    const float* W_bil     = (const float*)d_in[10];
    const float* W_st3     = (const float*)d_in[11];
    const float* W_ts3     = (const float*)d_in[12];
    const float* resb      = (const float*)d_in[13];
    const float* resa      = (const float*)d_in[14];
    const float* W_ae_rbf  = (const float*)d_in[15];
    const float* W_ae_in   = (const float*)d_in[16];
    const float* resat     = (const float*)d_in[17];
    const float* W_asi     = (const float*)d_in[18];
    const float* resm      = (const float*)d_in[19];
    const int*   idx_s     = (const int*)d_in[20];
    const int*   idx_t     = (const int*)d_in[21];
    const int*   idx_swap  = (const int*)d_in[22];
    const int*   id3_kt    = (const int*)d_in[23];

    // workspace layout
    float* B0 = (float*)d_ws;                               // E x 128 f32 : x
    float* h2 = B0 + (size_t)EE * 128;                      // NA x 128 f32
    unsigned short* scale_b = (unsigned short*)(h2 + (size_t)NA * 128); // E x 128
    unsigned short* yst_b   = scale_b;                      // alias (scale dead first)
    unsigned short* yts_b   = scale_b + (size_t)EE * 128;   // E x 128
    unsigned short* x_b     = yts_b + (size_t)EE * 128;     // E x 128
    unsigned short* mkt_b   = x_b + (size_t)EE * 128;       // E x 64
    unsigned short* xb_b    = mkt_b + (size_t)EE * 64;      // E x 64
    unsigned short* h_b     = xb_b + (size_t)EE * 64;       // NA x 128
    unsigned short* WTbil   = h_b + (size_t)NA * 128;       // 65536
    unsigned short* WTall   = WTbil + 65536;                // 352256
    int* cnt   = (int*)(WTall + 352256);
    int* start = cnt + NA;
    int* wrk   = start + NA + 1;
    int* order = wrk + NA;

    float* out_h = (float*)d_out;
    float* out_m = out_h + (size_t)NA * 128;

    const dim3 blk(256);
    const int gE = (EE + 127) / 128;   // 938
    const int gN = (NA + 127) / 128;   // 79
    constexpr size_t SQ = 128 * 128;

    // weight conversion table
    WTab tab; int off = 0; int oi = 0;
    auto put = [&](const float* s, int K, int N) {
        int o = off; tab.d[oi].src = s; tab.d[oi].K = K; tab.d[oi].N = N;
        tab.d[oi].off = o; ++oi; off += K * N; return o;
    };
    const int o_mlp  = put(W_mlp_st, 128, 128);
    const int o_mktw = put(W_m_kt, 128, 128);
    const int o_down = put(W_down, 128, 64);
    const int o_st3  = put(W_st3, 64, 128);
    const int o_ts3  = put(W_ts3, 64, 128);
    const int o_rb0  = put(resb, 128, 128);
    const int o_rb1  = put(resb + SQ, 128, 128);
    const int o_ra0  = put(resa, 128, 128);
    const int o_ra1  = put(resa + SQ, 128, 128);
    const int o_ra2  = put(resa + 2 * SQ, 128, 128);
    const int o_ra3  = put(resa + 3 * SQ, 128, 128);
    const int o_aein = put(W_ae_in, 128, 128);
    const int o_rat0 = put(resat, 128, 128);
    const int o_rat1 = put(resat + SQ, 128, 128);
    const int o_rat2 = put(resat + 2 * SQ, 128, 128);
    const int o_rat3 = put(resat + 3 * SQ, 128, 128);
    const int o_asi  = put(W_asi, 384, 128);
    const int o_rm0  = put(resm, 128, 128);
    const int o_rm1  = put(resm + SQ, 128, 128);
    const int o_rm2  = put(resm + 2 * SQ, 128, 128);
    const int o_rm3  = put(resm + 3 * SQ, 128, 128);

    // sort prep + weights
    hipMemsetAsync(cnt, 0, NA * sizeof(int), stream);
    wconv_k<<<65536 / 256, blk, 0, stream>>>(W_bil, WTbil);
    wconvall_k<<<21, blk, 0, stream>>>(tab, WTall);
    hist_k<<<(EE + 255) / 256, blk, 0, stream>>>(idx_t, cnt);
    scan_k<<<1, blk, 0, stream>>>(cnt, start, wrk);
    place_k<<<(EE + 255) / 256, blk, 0, stream>>>(idx_t, wrk, order);

    // scale = rbf3 @ W_t_rbf (bf16)
    rbf_scale_k<<<gE, blk, 0, stream>>>(rbf3, W_t_rbf, scale_b, EE);
    // front: mkt
    front_k<<<gE, blk, 0, stream>>>(m_st, scale_b, WTall + o_mktw, WTall + o_down, mkt_b);
    // bilinear
    bilinear3_k<<<EE / 32, dim3(512), 0, stream>>>(
        mkt_b, cbf_rbfW1, cbf_sph, id3_kt, WTbil, xb_b);
    // y_st / y_ts (yst_b aliases scale_b: scale consumed by front_k above)
    st3ts3_k<<<gE, blk, 0, stream>>>(xb_b, WTall + o_st3, WTall + o_ts3, yst_b, yts_b);
    // fused edge chain -> x (f32) + x_b (bf16)
    chain_k<<<gE, blk, 0, stream>>>(
        m_st, yst_b, yts_b, idx_swap,
        WTall + o_mlp, WTall + o_rb0, WTall + o_rb1,
        WTall + o_ra0, WTall + o_ra1, WTall + o_ra2, WTall + o_ra3,
        B0, x_b);
    // segment sum (sorted gather, fused coef)
    segsum_k<<<(NA + 3) / 4, blk, 0, stream>>>(x_b, rbf_h, W_ae_rbf, start, order, h2);
    // atom chain -> out_h + h_b
    atom_k<<<gN, blk, 0, stream>>>(
        h2, WTall + o_aein,
        WTall + o_rat0, WTall + o_rat1, WTall + o_rat2, WTall + o_rat3,
        out_h, h_b);
    // ASI + res_m -> out_m
    asi_k<<<gE, blk, 0, stream>>>(
        h_b, x_b, B0, idx_s, idx_t,
        WTall + o_asi,
        WTall + o_rm0, WTall + o_rm1, WTall + o_rm2, WTall + o_rm3,
        out_m);
}

// Round 5
// 936.598 us; speedup vs baseline: 3.6569x; 1.2151x over previous
//
#include <hip/hip_runtime.h>

// ---------------------------------------------------------------------------
// GemNet InteractionBlock forward, MI355X (gfx950).
// Round 5: all MLP kernels moved to 512 threads / 8 waves (2 feat x 4 row),
// __launch_bounds__(512,4) to hit 4 waves/SIMD (VGPR<=128, LDS 64KB x2/CU).
// ---------------------------------------------------------------------------

#define EE 120000
#define NA 10000

constexpr float C_INV = 0.70710678118654752440f;

using f32x4 = __attribute__((ext_vector_type(4))) float;
using f32x2 = __attribute__((ext_vector_type(2))) float;
using s16x8 = __attribute__((ext_vector_type(8))) short;
using s16x4 = __attribute__((ext_vector_type(4))) short;

__device__ __forceinline__ float act_silu(float x) { return x / (1.0f + __expf(-x)); }

__device__ __forceinline__ unsigned short f2bf(float f) {
    unsigned int u = __float_as_uint(f);
    u += 0x7fffu + ((u >> 16) & 1u);
    return (unsigned short)(u >> 16);
}
__device__ __forceinline__ float bf2f(unsigned short h) {
    return __uint_as_float(((unsigned int)h) << 16);
}

// ---------------------------------------------------------------------------
// Transposed GEMM tile: D[outF][row] += W[outF][k] * act[row][k]
// a-op = weights (global bf16 [outF][KW], pre-offset), b-op = LDS acts
// (row-major bf16, XOR swizzle, RS bytes/row).
// frag (mt,nf): outF = mt*16 + (l>>4)*4 + q, row = rowBase + nf*16 + (l&15).
// ---------------------------------------------------------------------------
template<int MT, int NF, int KQ>
__device__ __forceinline__ void gemmT(
    const char* ldsB, int RS,
    const unsigned short* W, int KW,
    int rowBase, int l, f32x4 (&acc)[MT][NF])
{
    const int fr = l & 15;
    const int k8 = (l >> 4) << 3;
    #pragma unroll
    for (int kq = 0; kq < KQ; ++kq) {
        s16x8 a[MT];
        #pragma unroll
        for (int mt = 0; mt < MT; ++mt)
            a[mt] = *(const s16x8*)&W[(size_t)(mt * 16 + fr) * KW + kq * 32 + k8];
        s16x8 b[NF];
        #pragma unroll
        for (int nf = 0; nf < NF; ++nf) {
            const int row = rowBase + nf * 16 + fr;
            const int kb  = ((kq * 32 + k8) * 2) ^ ((row & 7) << 4);
            b[nf] = *(const s16x8*)(ldsB + row * RS + kb);
        }
        #pragma unroll
        for (int mt = 0; mt < MT; ++mt)
            #pragma unroll
            for (int nf = 0; nf < NF; ++nf)
                acc[mt][nf] = __builtin_amdgcn_mfma_f32_16x16x32_bf16(
                    a[mt], b[nf], acc[mt][nf], 0, 0, 0);
    }
}

template<int MT, int NF>
__device__ __forceinline__ void zacc(f32x4 (&acc)[MT][NF])
{
    #pragma unroll
    for (int mt = 0; mt < MT; ++mt)
        #pragma unroll
        for (int nf = 0; nf < NF; ++nf)
            acc[mt][nf] = (f32x4){0.f, 0.f, 0.f, 0.f};
}

__device__ __forceinline__ void packA(char* lds, int RS, int row, int outF0, f32x4 v)
{
    s16x4 p;
    p[0] = (short)f2bf(v[0]); p[1] = (short)f2bf(v[1]);
    p[2] = (short)f2bf(v[2]); p[3] = (short)f2bf(v[3]);
    *(s16x4*)(lds + row * RS + ((outF0 * 2) ^ ((row & 7) << 4))) = p;
}

// stage 128 rows x 128 f32 -> swizzled bf16 LDS (RS=256), 512 threads
__device__ __forceinline__ void stage_f32(char* lds, const float* __restrict__ src,
                                          int row0, int M, int tid)
{
    #pragma unroll
    for (int u = 0; u < 4; ++u) {
        const int flat = tid + u * 512;
        const int row  = flat >> 4;
        const int k8   = (flat & 15) << 3;
        const int grow = row0 + row;
        s16x8 val = {0, 0, 0, 0, 0, 0, 0, 0};
        if (grow < M) {
            const float* p = src + (size_t)grow * 128 + k8;
            f32x4 lo = *(const f32x4*)p;
            f32x4 hi = *(const f32x4*)(p + 4);
            #pragma unroll
            for (int i = 0; i < 4; ++i) {
                val[i]     = (short)f2bf(lo[i]);
                val[i + 4] = (short)f2bf(hi[i]);
            }
        }
        *(s16x8*)(lds + row * 256 + ((k8 * 2) ^ ((row & 7) << 4))) = val;
    }
}

// ---------------------------------------------------------------------------
// one ResidualLayer (8-wave): inter = act(x@W0); y = act(inter@W1);
// x = (x+y)*C (+ optional (x+m_st)*C). x lives in regs + packed in A.
// ---------------------------------------------------------------------------
template<bool MSTM>
__device__ __forceinline__ void res_layer(
    char* A, char* B,
    const unsigned short* W0, const unsigned short* W1,
    int wm, int wn, int l, f32x4 (&x)[4][2],
    const float* __restrict__ mst, int row0, int M)
{
    const int fr = l & 15;
    const int fq = (l >> 4) << 2;
    f32x4 acc[4][2];
    zacc(acc);
    gemmT<4, 2, 4>(A, 256, W0 + (size_t)(wm * 64) * 128, 128, wn * 32, l, acc);
    #pragma unroll
    for (int mt = 0; mt < 4; ++mt)
        #pragma unroll
        for (int nf = 0; nf < 2; ++nf) {
            const int row = wn * 32 + nf * 16 + fr;
            const int of0 = wm * 64 + mt * 16 + fq;
            f32x4 v;
            #pragma unroll
            for (int q = 0; q < 4; ++q) v[q] = act_silu(acc[mt][nf][q]);
            packA(B, 256, row, of0, v);
        }
    __syncthreads();
    zacc(acc);
    gemmT<4, 2, 4>(B, 256, W1 + (size_t)(wm * 64) * 128, 128, wn * 32, l, acc);
    #pragma unroll
    for (int mt = 0; mt < 4; ++mt)
        #pragma unroll
        for (int nf = 0; nf < 2; ++nf) {
            const int row = wn * 32 + nf * 16 + fr;
            const int of0 = wm * 64 + mt * 16 + fq;
            #pragma unroll
            for (int q = 0; q < 4; ++q)
                x[mt][nf][q] = (x[mt][nf][q] + act_silu(acc[mt][nf][q])) * C_INV;
            if (MSTM) {
                const int grow = row0 + row;
                if (grow < M) {
                    f32x4 mv = *(const f32x4*)&mst[(size_t)grow * 128 + of0];
                    #pragma unroll
                    for (int q = 0; q < 4; ++q)
                        x[mt][nf][q] = (x[mt][nf][q] + mv[q]) * C_INV;
                }
            }
            packA(A, 256, row, of0, x[mt][nf]);
        }
    __syncthreads();
}

// ---------------------------------------------------------------------------
// front: tpre = act(m_st@W_m_kt)*scale ; mkt = act(tpre@W_down)
// ---------------------------------------------------------------------------
__global__ __launch_bounds__(512, 4) void front_k(
    const float* __restrict__ m_st, const unsigned short* __restrict__ scale_b,
    const unsigned short* __restrict__ Wmkt, const unsigned short* __restrict__ Wdown,
    unsigned short* __restrict__ mkt_b)
{
    __shared__ char A[128 * 256];
    const int tid = threadIdx.x;
    const int l = tid & 63, w = tid >> 6, wm = w & 1, wn = w >> 1;
    const int fr = l & 15, fq = (l >> 4) << 2;
    const int row0 = blockIdx.x * 128;

    stage_f32(A, m_st, row0, EE, tid);
    __syncthreads();

    f32x4 acc[4][2];
    zacc(acc);
    gemmT<4, 2, 4>(A, 256, Wmkt + (size_t)(wm * 64) * 128, 128, wn * 32, l, acc);
    __syncthreads();
    #pragma unroll
    for (int mt = 0; mt < 4; ++mt)
        #pragma unroll
        for (int nf = 0; nf < 2; ++nf) {
            const int row = wn * 32 + nf * 16 + fr;
            const int grow = row0 + row;
            const int of0 = wm * 64 + mt * 16 + fq;
            f32x4 v = {0.f, 0.f, 0.f, 0.f};
            if (grow < EE) {
                s16x4 sc = *(const s16x4*)&scale_b[(size_t)grow * 128 + of0];
                #pragma unroll
                for (int q = 0; q < 4; ++q)
                    v[q] = act_silu(acc[mt][nf][q]) * bf2f((unsigned short)sc[q]);
            }
            packA(A, 256, row, of0, v);
        }
    __syncthreads();

    f32x4 acc2[2][2];
    zacc(acc2);
    gemmT<2, 2, 4>(A, 256, Wdown + (size_t)(wm * 32) * 128, 128, wn * 32, l, acc2);
    #pragma unroll
    for (int mt = 0; mt < 2; ++mt)
        #pragma unroll
        for (int nf = 0; nf < 2; ++nf) {
            const int row = wn * 32 + nf * 16 + fr;
            const int grow = row0 + row;
            if (grow >= EE) continue;
            const int of0 = wm * 32 + mt * 16 + fq;
            s16x4 p;
            #pragma unroll
            for (int q = 0; q < 4; ++q) p[q] = (short)f2bf(act_silu(acc2[mt][nf][q]));
            *(s16x4*)&mkt_b[(size_t)grow * 64 + of0] = p;
        }
}

// ---------------------------------------------------------------------------
// st3/ts3: y_st = act(xb@W_st3), y_ts = act(xb@W_ts3)
// ---------------------------------------------------------------------------
__global__ __launch_bounds__(512, 4) void st3ts3_k(
    const unsigned short* __restrict__ xb_b,
    const unsigned short* __restrict__ Wst3, const unsigned short* __restrict__ Wts3,
    unsigned short* __restrict__ yst, unsigned short* __restrict__ yts)
{
    __shared__ char A[128 * 128];
    const int tid = threadIdx.x;
    const int l = tid & 63, w = tid >> 6, wm = w & 1, wn = w >> 1;
    const int fr = l & 15, fq = (l >> 4) << 2;
    const int row0 = blockIdx.x * 128;

    #pragma unroll
    for (int u = 0; u < 2; ++u) {
        const int flat = tid + u * 512;
        const int row = flat >> 3;
        const int k8 = (flat & 7) << 3;
        const int grow = row0 + row;
        s16x8 v = {0, 0, 0, 0, 0, 0, 0, 0};
        if (grow < EE) v = *(const s16x8*)&xb_b[(size_t)grow * 64 + k8];
        *(s16x8*)(A + row * 128 + ((k8 * 2) ^ ((row & 7) << 4))) = v;
    }
    __syncthreads();

    f32x4 aS[4][2], aT[4][2];
    zacc(aS); zacc(aT);
    gemmT<4, 2, 2>(A, 128, Wst3 + (size_t)(wm * 64) * 64, 64, wn * 32, l, aS);
    gemmT<4, 2, 2>(A, 128, Wts3 + (size_t)(wm * 64) * 64, 64, wn * 32, l, aT);

    #pragma unroll
    for (int mt = 0; mt < 4; ++mt)
        #pragma unroll
        for (int nf = 0; nf < 2; ++nf) {
            const int row = wn * 32 + nf * 16 + fr;
            const int grow = row0 + row;
            if (grow >= EE) continue;
            const int of0 = wm * 64 + mt * 16 + fq;
            s16x4 p, q4;
            #pragma unroll
            for (int q = 0; q < 4; ++q) {
                p[q]  = (short)f2bf(act_silu(aS[mt][nf][q]));
                q4[q] = (short)f2bf(act_silu(aT[mt][nf][q]));
            }
            *(s16x4*)&yst[(size_t)grow * 128 + of0] = p;
            *(s16x4*)&yts[(size_t)grow * 128 + of0] = q4;
        }
}

// ---------------------------------------------------------------------------
// chain: x_skip + (y_st + y_ts[swap]) merge + resb + m_st merge + resa x2
// ---------------------------------------------------------------------------
__global__ __launch_bounds__(512, 4) void chain_k(
    const float* __restrict__ m_st,
    const unsigned short* __restrict__ yst, const unsigned short* __restrict__ yts,
    const int* __restrict__ idx_swap,
    const unsigned short* __restrict__ Wmlp,
    const unsigned short* __restrict__ Wrb0, const unsigned short* __restrict__ Wrb1,
    const unsigned short* __restrict__ Wra0, const unsigned short* __restrict__ Wra1,
    const unsigned short* __restrict__ Wra2, const unsigned short* __restrict__ Wra3,
    float* __restrict__ x_out, unsigned short* __restrict__ xb_out)
{
    __shared__ char A[128 * 256];
    __shared__ char B[128 * 256];
    const int tid = threadIdx.x;
    const int l = tid & 63, w = tid >> 6, wm = w & 1, wn = w >> 1;
    const int fr = l & 15, fq = (l >> 4) << 2;
    const int row0 = blockIdx.x * 128;

    stage_f32(A, m_st, row0, EE, tid);
    __syncthreads();

    f32x4 acc[4][2];
    zacc(acc);
    gemmT<4, 2, 4>(A, 256, Wmlp + (size_t)(wm * 64) * 128, 128, wn * 32, l, acc);

    f32x4 x[4][2];
    #pragma unroll
    for (int mt = 0; mt < 4; ++mt)
        #pragma unroll
        for (int nf = 0; nf < 2; ++nf) {
            const int row = wn * 32 + nf * 16 + fr;
            const int grow = row0 + row;
            const int of0 = wm * 64 + mt * 16 + fq;
            if (grow < EE) {
                s16x4 a = *(const s16x4*)&yst[(size_t)grow * 128 + of0];
                const int sw = idx_swap[grow];
                s16x4 b = *(const s16x4*)&yts[(size_t)sw * 128 + of0];
                #pragma unroll
                for (int q = 0; q < 4; ++q)
                    x[mt][nf][q] = (acc[mt][nf][q] +
                        (bf2f((unsigned short)a[q]) + bf2f((unsigned short)b[q])) * C_INV) * C_INV;
            } else {
                x[mt][nf] = (f32x4){0.f, 0.f, 0.f, 0.f};
            }
        }
    __syncthreads();
    #pragma unroll
    for (int mt = 0; mt < 4; ++mt)
        #pragma unroll
        for (int nf = 0; nf < 2; ++nf)
            packA(A, 256, wn * 32 + nf * 16 + fr, wm * 64 + mt * 16 + fq, x[mt][nf]);
    __syncthreads();

    res_layer<true >(A, B, Wrb0, Wrb1, wm, wn, l, x, m_st, row0, EE);
    res_layer<false>(A, B, Wra0, Wra1, wm, wn, l, x, m_st, row0, EE);
    res_layer<false>(A, B, Wra2, Wra3, wm, wn, l, x, m_st, row0, EE);

    #pragma unroll
    for (int mt = 0; mt < 4; ++mt)
        #pragma unroll
        for (int nf = 0; nf < 2; ++nf) {
            const int row = wn * 32 + nf * 16 + fr;
            const int grow = row0 + row;
            if (grow >= EE) continue;
            const int of0 = wm * 64 + mt * 16 + fq;
            *(f32x4*)&x_out[(size_t)grow * 128 + of0] = x[mt][nf];
            s16x4 p;
            #pragma unroll
            for (int q = 0; q < 4; ++q) p[q] = (short)f2bf(x[mt][nf][q]);
            *(s16x4*)&xb_out[(size_t)grow * 128 + of0] = p;
        }
}

// ---------------------------------------------------------------------------
// atom chain
// ---------------------------------------------------------------------------
__global__ __launch_bounds__(512, 4) void atom_k(
    const float* __restrict__ h2,
    const unsigned short* __restrict__ Wae,
    const unsigned short* __restrict__ Wr0, const unsigned short* __restrict__ Wr1,
    const unsigned short* __restrict__ Wr2, const unsigned short* __restrict__ Wr3,
    float* __restrict__ out_h, unsigned short* __restrict__ h_b)
{
    __shared__ char A[128 * 256];
    __shared__ char B[128 * 256];
    const int tid = threadIdx.x;
    const int l = tid & 63, w = tid >> 6, wm = w & 1, wn = w >> 1;
    const int fr = l & 15, fq = (l >> 4) << 2;
    const int row0 = blockIdx.x * 128;

    stage_f32(A, h2, row0, NA, tid);
    __syncthreads();

    f32x4 acc[4][2];
    zacc(acc);
    gemmT<4, 2, 4>(A, 256, Wae + (size_t)(wm * 64) * 128, 128, wn * 32, l, acc);
    f32x4 x[4][2];
    #pragma unroll
    for (int mt = 0; mt < 4; ++mt)
        #pragma unroll
        for (int nf = 0; nf < 2; ++nf)
            #pragma unroll
            for (int q = 0; q < 4; ++q)
                x[mt][nf][q] = act_silu(acc[mt][nf][q]);
    __syncthreads();
    #pragma unroll
    for (int mt = 0; mt < 4; ++mt)
        #pragma unroll
        for (int nf = 0; nf < 2; ++nf)
            packA(A, 256, wn * 32 + nf * 16 + fr, wm * 64 + mt * 16 + fq, x[mt][nf]);
    __syncthreads();

    res_layer<false>(A, B, Wr0, Wr1, wm, wn, l, x, nullptr, row0, NA);
    res_layer<false>(A, B, Wr2, Wr3, wm, wn, l, x, nullptr, row0, NA);

    #pragma unroll
    for (int mt = 0; mt < 4; ++mt)
        #pragma unroll
        for (int nf = 0; nf < 2; ++nf) {
            const int row = wn * 32 + nf * 16 + fr;
            const int grow = row0 + row;
            if (grow >= NA) continue;
            const int of0 = wm * 64 + mt * 16 + fq;
            *(f32x4*)&out_h[(size_t)grow * 128 + of0] = x[mt][nf];
            s16x4 p;
            #pragma unroll
            for (int q = 0; q < 4; ++q) p[q] = (short)f2bf(x[mt][nf][q]);
            *(s16x4*)&h_b[(size_t)grow * 128 + of0] = p;
        }
}

// ---------------------------------------------------------------------------
// ASI + res_m
// ---------------------------------------------------------------------------
__global__ __launch_bounds__(512, 4) void asi_k(
    const unsigned short* __restrict__ h_b, const unsigned short* __restrict__ x_b,
    const float* __restrict__ x_f32,
    const int* __restrict__ idx_s, const int* __restrict__ idx_t,
    const unsigned short* __restrict__ Wasi,
    const unsigned short* __restrict__ Wm0, const unsigned short* __restrict__ Wm1,
    const unsigned short* __restrict__ Wm2, const unsigned short* __restrict__ Wm3,
    float* __restrict__ out_m)
{
    __shared__ char A[128 * 256];
    __shared__ char B[128 * 256];
    const int tid = threadIdx.x;
    const int l = tid & 63, w = tid >> 6, wm = w & 1, wn = w >> 1;
    const int fr = l & 15, fq = (l >> 4) << 2;
    const int row0 = blockIdx.x * 128;

    f32x4 acc[4][2];
    zacc(acc);

    for (int c = 0; c < 3; ++c) {
        #pragma unroll
        for (int u = 0; u < 4; ++u) {
            const int flat = tid + u * 512;
            const int row = flat >> 4;
            const int k8 = (flat & 15) << 3;
            const int grow = row0 + row;
            s16x8 v = {0, 0, 0, 0, 0, 0, 0, 0};
            if (grow < EE) {
                const unsigned short* src =
                    (c == 0) ? h_b + (size_t)idx_s[grow] * 128
                  : (c == 1) ? h_b + (size_t)idx_t[grow] * 128
                             : x_b + (size_t)grow * 128;
                v = *(const s16x8*)&src[k8];
            }
            *(s16x8*)(A + row * 256 + ((k8 * 2) ^ ((row & 7) << 4))) = v;
        }
        __syncthreads();
        gemmT<4, 2, 4>(A, 256, Wasi + (size_t)(wm * 64) * 384 + c * 128, 384, wn * 32, l, acc);
        __syncthreads();
    }

    f32x4 x[4][2];
    #pragma unroll
    for (int mt = 0; mt < 4; ++mt)
        #pragma unroll
        for (int nf = 0; nf < 2; ++nf)
            #pragma unroll
            for (int q = 0; q < 4; ++q)
                x[mt][nf][q] = act_silu(acc[mt][nf][q]);
    #pragma unroll
    for (int mt = 0; mt < 4; ++mt)
        #pragma unroll
        for (int nf = 0; nf < 2; ++nf)
            packA(A, 256, wn * 32 + nf * 16 + fr, wm * 64 + mt * 16 + fq, x[mt][nf]);
    __syncthreads();

    res_layer<false>(A, B, Wm0, Wm1, wm, wn, l, x, nullptr, row0, EE);
    res_layer<false>(A, B, Wm2, Wm3, wm, wn, l, x, nullptr, row0, EE);

    #pragma unroll
    for (int mt = 0; mt < 4; ++mt)
        #pragma unroll
        for (int nf = 0; nf < 2; ++nf) {
            const int row = wn * 32 + nf * 16 + fr;
            const int grow = row0 + row;
            if (grow >= EE) continue;
            const int of0 = wm * 64 + mt * 16 + fq;
            f32x4 xv = *(const f32x4*)&x_f32[(size_t)grow * 128 + of0];
            f32x4 o;
            #pragma unroll
            for (int q = 0; q < 4; ++q) o[q] = (x[mt][nf][q] + xv[q]) * C_INV;
            *(f32x4*)&out_m[(size_t)grow * 128 + of0] = o;
        }
}

// ---------------------------------------------------------------------------
// rbf scale: scale = rbf3 @ W_t_rbf -> bf16
// ---------------------------------------------------------------------------
__global__ __launch_bounds__(256) void rbf_scale_k(
    const float* __restrict__ A, const float* __restrict__ W,
    unsigned short* __restrict__ out, int M)
{
    __shared__ float Ws[16][128];
    const int tid = threadIdx.x;
    #pragma unroll
    for (int t = tid; t < 512; t += 256) {
        int kk = t >> 5, c4 = (t & 31) << 2;
        *(float4*)&Ws[kk][c4] = *(const float4*)(W + kk * 128 + c4);
    }
    __syncthreads();
    const int tx = tid & 31, ty = tid >> 5;
    const int row0 = blockIdx.x * 128;
    #pragma unroll
    for (int i = 0; i < 16; ++i) {
        const int row = row0 + ty + i * 8;
        if (row >= M) continue;
        float av[16];
        #pragma unroll
        for (int j = 0; j < 4; ++j) {
            float4 a = *(const float4*)(A + (size_t)row * 16 + j * 4);
            av[j * 4] = a.x; av[j * 4 + 1] = a.y; av[j * 4 + 2] = a.z; av[j * 4 + 3] = a.w;
        }
        float4 s = make_float4(0.f, 0.f, 0.f, 0.f);
        #pragma unroll
        for (int k = 0; k < 16; ++k) {
            float4 wv = *(const float4*)&Ws[k][tx * 4];
            s.x += av[k] * wv.x; s.y += av[k] * wv.y;
            s.z += av[k] * wv.z; s.w += av[k] * wv.w;
        }
        s16x4 p;
        p[0] = (short)f2bf(s.x); p[1] = (short)f2bf(s.y);
        p[2] = (short)f2bf(s.z); p[3] = (short)f2bf(s.w);
        *(s16x4*)&out[(size_t)row * 128 + tx * 4] = p;
    }
}

// ---------------------------------------------------------------------------
// counting sort of idx_t + gather segment-sum with fused coef
// ---------------------------------------------------------------------------
__global__ void hist_k(const int* __restrict__ idxt, int* __restrict__ cnt)
{
    int i = blockIdx.x * 256 + threadIdx.x;
    if (i < EE) atomicAdd(&cnt[idxt[i]], 1);
}

__global__ __launch_bounds__(256) void scan_k(const int* __restrict__ cnt,
                                              int* __restrict__ start, int* __restrict__ wrk)
{
    __shared__ int ps[256];
    const int t = threadIdx.x;
    int s = 0;
    for (int j = 0; j < 40; ++j) {
        int idx = t * 40 + j;
        if (idx < NA) s += cnt[idx];
    }
    ps[t] = s;
    __syncthreads();
    for (int off = 1; off < 256; off <<= 1) {
        int v = (t >= off) ? ps[t - off] : 0;
        __syncthreads();
        ps[t] += v;
        __syncthreads();
    }
    int run = ps[t] - s;
    for (int j = 0; j < 40; ++j) {
        int idx = t * 40 + j;
        if (idx < NA) {
            start[idx] = run;
            wrk[idx] = run;
            run += cnt[idx];
        }
    }
    if (t == 255) start[NA] = ps[255];
}

__global__ void place_k(const int* __restrict__ idxt, int* __restrict__ wrk,
                        int* __restrict__ order)
{
    int i = blockIdx.x * 256 + threadIdx.x;
    if (i < EE) {
        int pos = atomicAdd(&wrk[idxt[i]], 1);
        order[pos] = i;
    }
}

// one wave per atom: h2[a] = sum_{e in bucket} x_b[e] * (rbf_h[e] @ W_ae_rbf)
__global__ __launch_bounds__(256) void segsum_k(
    const unsigned short* __restrict__ x_b, const float* __restrict__ rbf_h,
    const float* __restrict__ Wae, const int* __restrict__ start,
    const int* __restrict__ order, float* __restrict__ h2)
{
    const int tid = threadIdx.x;
    const int l = tid & 63, w = tid >> 6;
    const int a = blockIdx.x * 4 + w;
    if (a >= NA) return;

    float wc[32];
    #pragma unroll
    for (int j = 0; j < 16; ++j) {
        f32x2 v = *(const f32x2*)(Wae + j * 128 + 2 * l);
        wc[2 * j] = v[0]; wc[2 * j + 1] = v[1];
    }

    const int s = start[a], e_end = start[a + 1];
    float acc0 = 0.f, acc1 = 0.f;
    for (int i = s; i < e_end; ++i) {
        const int e = __builtin_amdgcn_readfirstlane(order[i]);
        const unsigned int xv = *(const unsigned int*)(x_b + (size_t)e * 128 + 2 * l);
        const float* rp = rbf_h + (size_t)e * 16;
        float c0 = 0.f, c1 = 0.f;
        #pragma unroll
        for (int j = 0; j < 16; ++j) {
            float r = rp[j];
            c0 += r * wc[2 * j];
            c1 += r * wc[2 * j + 1];
        }
        acc0 += bf2f((unsigned short)(xv & 0xffff)) * c0;
        acc1 += bf2f((unsigned short)(xv >> 16)) * c1;
    }
    f32x2 o; o[0] = acc0; o[1] = acc1;
    *(f32x2*)&h2[(size_t)a * 128 + 2 * l] = o;
}

// ---------------------------------------------------------------------------
// weight conversions
// ---------------------------------------------------------------------------
__global__ void wconv_k(const float* __restrict__ Wbil, unsigned short* __restrict__ WT)
{
    int t = blockIdx.x * 256 + threadIdx.x;
    int u = t >> 10, k = t & 1023, j = k >> 6, c = k & 63;
    WT[t] = f2bf(Wbil[(size_t)(c * 16 + j) * 64 + u]);
}

struct WDesc { const float* src; int K; int N; int off; };
struct WTab  { WDesc d[21]; };

__global__ void wconvall_k(WTab tab, unsigned short* __restrict__ dst)
{
    WDesc d = tab.d[blockIdx.x];
    const int tot = d.K * d.N;
    for (int i = threadIdx.x; i < tot; i += 256) {
        int n = i / d.K, k = i - n * d.K;
        dst[d.off + i] = f2bf(d.src[(size_t)k * d.N + n]);
    }
}

// ---------------------------------------------------------------------------
// bilinear (readlane coefficients, bf16 in/out)
// ---------------------------------------------------------------------------
__device__ __forceinline__ float rlc(const f32x4& cv, int idx, int lbase)
{
    const int c = idx & 3;
    float comp = (c == 0) ? cv[0] : (c == 1) ? cv[1] : (c == 2) ? cv[2] : cv[3];
    return __uint_as_float(__builtin_amdgcn_readlane(__float_as_uint(comp),
                                                     lbase + (idx >> 2)));
}

__global__ __launch_bounds__(512) void bilinear3_k(
    const unsigned short* __restrict__ mkt,
    const float* __restrict__ rbfW1,
    const float* __restrict__ sph,
    const int*   __restrict__ id3kt,
    const unsigned short* __restrict__ WT,
    unsigned short* __restrict__ xb)
{
    __shared__ unsigned short aS[32 * 1024];
    float* pS = (float*)aS;

    const int tid = threadIdx.x;
    const int l   = tid & 63;
    const int w   = tid >> 6;
    const int e0  = blockIdx.x * 32;

    s16x8 bfrag[4][4];
    {
        const int u  = l & 15;
        const int kh = w * 128 + ((l >> 4) << 3);
        #pragma unroll
        for (int nt = 0; nt < 4; ++nt)
            #pragma unroll
            for (int kq = 0; kq < 4; ++kq)
                bfrag[nt][kq] = *(const s16x8*)&WT[(size_t)(nt * 16 + u) * 1024 + kh + kq * 32];
    }

    #pragma unroll
    for (int r = 0; r < 4; ++r) {
        const int eL = r * 8 + w;
        const int eG = e0 + eL;

        f32x4 cv = {0.f, 0.f, 0.f, 0.f};
        if (l < 14)       cv = *(const f32x4*)(sph   + (size_t)eG * 56  + l * 4);
        else if (l < 42)  cv = *(const f32x4*)(rbfW1 + (size_t)eG * 112 + (l - 14) * 4);

        float m2r[8];
        #pragma unroll
        for (int k = 0; k < 8; ++k)
            m2r[k] = bf2f(mkt[(size_t)id3kt[eG * 8 + k] * 64 + l]);

        float sk[7] = {0.f, 0.f, 0.f, 0.f, 0.f, 0.f, 0.f};
        #pragma unroll
        for (int k = 0; k < 8; ++k)
            #pragma unroll
            for (int s = 0; s < 7; ++s)
                sk[s] += rlc(cv, k * 7 + s, 0) * m2r[k];

        unsigned short* arow = aS + eL * 1024;
        const int lsw = l ^ ((eL & 7) << 3);
        #pragma unroll
        for (int j = 0; j < 16; ++j) {
            float av = 0.f;
            #pragma unroll
            for (int s = 0; s < 7; ++s)
                av += rlc(cv, j * 7 + s, 14) * sk[s];
            arow[j * 64 + lsw] = f2bf(av);
        }
    }
    __syncthreads();

    f32x4 acc[2][4];
    #pragma unroll
    for (int mt = 0; mt < 2; ++mt)
        #pragma unroll
        for (int nt = 0; nt < 4; ++nt)
            acc[mt][nt] = (f32x4){0.f, 0.f, 0.f, 0.f};

    const int kbase = w * 128 + ((l >> 4) << 3);
    #pragma unroll
    for (int kq = 0; kq < 4; ++kq) {
        s16x8 afr[2];
        #pragma unroll
        for (int mt = 0; mt < 2; ++mt) {
            const int row = mt * 16 + (l & 15);
            const int kk  = (kbase + kq * 32) ^ ((row & 7) << 3);
            afr[mt] = *(const s16x8*)&aS[row * 1024 + kk];
        }
        #pragma unroll
        for (int mt = 0; mt < 2; ++mt)
            #pragma unroll
            for (int nt = 0; nt < 4; ++nt)
                acc[mt][nt] = __builtin_amdgcn_mfma_f32_16x16x32_bf16(
                    afr[mt], bfrag[nt][kq], acc[mt][nt], 0, 0, 0);
    }
    __syncthreads();

    #pragma unroll
    for (int mt = 0; mt < 2; ++mt)
        #pragma unroll
        for (int nt = 0; nt < 4; ++nt)
            #pragma unroll
            for (int q = 0; q < 4; ++q) {
                const int e = mt * 16 + ((l >> 4) << 2) + q;
                const int u = nt * 16 + (l & 15);
                pS[(w * 32 + e) * 64 + u] = acc[mt][nt][q];
            }
    __syncthreads();

    {
        const int e  = tid >> 4;
        const int u0 = (tid & 15) << 2;
        f32x4 s = (f32x4){0.f, 0.f, 0.f, 0.f};
        #pragma unroll
        for (int ww = 0; ww < 8; ++ww)
            s += *(const f32x4*)&pS[(ww * 32 + e) * 64 + u0];
        s16x4 ov;
        #pragma unroll
        for (int i = 0; i < 4; ++i) ov[i] = (short)f2bf(s[i]);
        *(s16x4*)&xb[(size_t)(e0 + e) * 64 + u0] = ov;
    }
}

// ---------------------------------------------------------------------------
// launch
// ---------------------------------------------------------------------------
extern "C" void kernel_launch(void* const* d_in, const int* in_sizes, int n_in,
                              void* d_out, int out_size, void* d_ws, size_t ws_size,
                              hipStream_t stream)
{
    const float* m_st      = (const float*)d_in[1];
    const float* rbf_h     = (const float*)d_in[2];
    const float* rbf3      = (const float*)d_in[3];
    const float* cbf_rbfW1 = (const float*)d_in[4];
    const float* cbf_sph   = (const float*)d_in[5];
    const float* W_mlp_st  = (const float*)d_in[6];
    const float* W_m_kt    = (const float*)d_in[7];
    const float* W_t_rbf   = (const float*)d_in[8];
    const float* W_down    = (const float*)d_in[9];
    const float* W_bil     = (const float*)d_in[10];
    const float* W_st3     = (const float*)d_in[11];
    const float* W_ts3     = (const float*)d_in[12];
    const float* resb      = (const float*)d_in[13];
    const float* resa      = (const float*)d_in[14];
    const float* W_ae_rbf  = (const float*)d_in[15];
    const float* W_ae_in   = (const float*)d_in[16];
    const float* resat     = (const float*)d_in[17];
    const float* W_asi     = (const float*)d_in[18];
    const float* resm      = (const float*)d_in[19];
    const int*   idx_s     = (const int*)d_in[20];
    const int*   idx_t     = (const int*)d_in[21];
    const int*   idx_swap  = (const int*)d_in[22];
    const int*   id3_kt    = (const int*)d_in[23];

    float* B0 = (float*)d_ws;                               // E x 128 f32 : x
    float* h2 = B0 + (size_t)EE * 128;                      // NA x 128 f32
    unsigned short* scale_b = (unsigned short*)(h2 + (size_t)NA * 128);
    unsigned short* yst_b   = scale_b;                      // alias (scale dead first)
    unsigned short* yts_b   = scale_b + (size_t)EE * 128;
    unsigned short* x_b     = yts_b + (size_t)EE * 128;
    unsigned short* mkt_b   = x_b + (size_t)EE * 128;
    unsigned short* xb_b    = mkt_b + (size_t)EE * 64;
    unsigned short* h_b     = xb_b + (size_t)EE * 64;
    unsigned short* WTbil   = h_b + (size_t)NA * 128;
    unsigned short* WTall   = WTbil + 65536;
    int* cnt   = (int*)(WTall + 352256);
    int* start = cnt + NA;
    int* wrk   = start + NA + 1;
    int* order = wrk + NA;

    float* out_h = (float*)d_out;
    float* out_m = out_h + (size_t)NA * 128;

    const dim3 blk(256);
    const dim3 blk5(512);
    const int gE = (EE + 127) / 128;   // 938
    const int gN = (NA + 127) / 128;   // 79
    constexpr size_t SQ = 128 * 128;

    WTab tab; int off = 0; int oi = 0;
    auto put = [&](const float* s, int K, int N) {
        int o = off; tab.d[oi].src = s; tab.d[oi].K = K; tab.d[oi].N = N;
        tab.d[oi].off = o; ++oi; off += K * N; return o;
    };
    const int o_mlp  = put(W_mlp_st, 128, 128);
    const int o_mktw = put(W_m_kt, 128, 128);
    const int o_down = put(W_down, 128, 64);
    const int o_st3  = put(W_st3, 64, 128);
    const int o_ts3  = put(W_ts3, 64, 128);
    const int o_rb0  = put(resb, 128, 128);
    const int o_rb1  = put(resb + SQ, 128, 128);
    const int o_ra0  = put(resa, 128, 128);
    const int o_ra1  = put(resa + SQ, 128, 128);
    const int o_ra2  = put(resa + 2 * SQ, 128, 128);
    const int o_ra3  = put(resa + 3 * SQ, 128, 128);
    const int o_aein = put(W_ae_in, 128, 128);
    const int o_rat0 = put(resat, 128, 128);
    const int o_rat1 = put(resat + SQ, 128, 128);
    const int o_rat2 = put(resat + 2 * SQ, 128, 128);
    const int o_rat3 = put(resat + 3 * SQ, 128, 128);
    const int o_asi  = put(W_asi, 384, 128);
    const int o_rm0  = put(resm, 128, 128);
    const int o_rm1  = put(resm + SQ, 128, 128);
    const int o_rm2  = put(resm + 2 * SQ, 128, 128);
    const int o_rm3  = put(resm + 3 * SQ, 128, 128);

    hipMemsetAsync(cnt, 0, NA * sizeof(int), stream);
    wconv_k<<<65536 / 256, blk, 0, stream>>>(W_bil, WTbil);
    wconvall_k<<<21, blk, 0, stream>>>(tab, WTall);
    hist_k<<<(EE + 255) / 256, blk, 0, stream>>>(idx_t, cnt);
    scan_k<<<1, blk, 0, stream>>>(cnt, start, wrk);
    place_k<<<(EE + 255) / 256, blk, 0, stream>>>(idx_t, wrk, order);

    rbf_scale_k<<<gE, blk, 0, stream>>>(rbf3, W_t_rbf, scale_b, EE);
    front_k<<<gE, blk5, 0, stream>>>(m_st, scale_b, WTall + o_mktw, WTall + o_down, mkt_b);
    bilinear3_k<<<EE / 32, blk5, 0, stream>>>(
        mkt_b, cbf_rbfW1, cbf_sph, id3_kt, WTbil, xb_b);
    st3ts3_k<<<gE, blk5, 0, stream>>>(xb_b, WTall + o_st3, WTall + o_ts3, yst_b, yts_b);
    chain_k<<<gE, blk5, 0, stream>>>(
        m_st, yst_b, yts_b, idx_swap,
        WTall + o_mlp, WTall + o_rb0, WTall + o_rb1,
        WTall + o_ra0, WTall + o_ra1, WTall + o_ra2, WTall + o_ra3,
        B0, x_b);
    segsum_k<<<(NA + 3) / 4, blk, 0, stream>>>(x_b, rbf_h, W_ae_rbf, start, order, h2);
    atom_k<<<gN, blk5, 0, stream>>>(
        h2, WTall + o_aein,
        WTall + o_rat0, WTall + o_rat1, WTall + o_rat2, WTall + o_rat3,
        out_h, h_b);
    asi_k<<<gE, blk5, 0, stream>>>(
        h_b, x_b, B0, idx_s, idx_t,
        WTall + o_asi,
        WTall + o_rm0, WTall + o_rm1, WTall + o_rm2, WTall + o_rm3,
        out_m);
}

// Round 6
// 830.630 us; speedup vs baseline: 4.1235x; 1.1276x over previous
//
#include <hip/hip_runtime.h>

// ---------------------------------------------------------------------------
// GemNet InteractionBlock forward, MI355X (gfx950).
// Round 6: v_cvt_pk_bf16_f32 packing everywhere (epilogue-VALU cut),
// x kept bf16-only (no f32 round-trip), atom chain on 64-row tiles.
// ---------------------------------------------------------------------------

#define EE 120000
#define NA 10000

constexpr float C_INV = 0.70710678118654752440f;

using f32x4 = __attribute__((ext_vector_type(4))) float;
using f32x2 = __attribute__((ext_vector_type(2))) float;
using s16x8 = __attribute__((ext_vector_type(8))) short;
using s16x4 = __attribute__((ext_vector_type(4))) short;

__device__ __forceinline__ float act_silu(float x) { return x / (1.0f + __expf(-x)); }

__device__ __forceinline__ unsigned short f2bf(float f) {
    unsigned int u = __float_as_uint(f);
    u += 0x7fffu + ((u >> 16) & 1u);
    return (unsigned short)(u >> 16);
}
__device__ __forceinline__ float bf2f(unsigned short h) {
    return __uint_as_float(((unsigned int)h) << 16);
}
// packed RNE f32x2 -> 2xbf16 in one VALU op
__device__ __forceinline__ unsigned int cvtpk(float a, float b) {
    unsigned int r;
    asm("v_cvt_pk_bf16_f32 %0, %1, %2" : "=v"(r) : "v"(a), "v"(b));
    return r;
}

// ---------------------------------------------------------------------------
// Transposed GEMM tile: D[outF][row] += W[outF][k] * act[row][k]
// a-op = weights (global bf16 [outF][KW]), b-op = LDS acts (XOR swizzle).
// frag (mt,nf): outF = mt*16 + (l>>4)*4 + q, row = rowBase + nf*16 + (l&15).
// ---------------------------------------------------------------------------
template<int MT, int NF, int KQ>
__device__ __forceinline__ void gemmT(
    const char* ldsB, int RS,
    const unsigned short* W, int KW,
    int rowBase, int l, f32x4 (&acc)[MT][NF])
{
    const int fr = l & 15;
    const int k8 = (l >> 4) << 3;
    #pragma unroll
    for (int kq = 0; kq < KQ; ++kq) {
        s16x8 a[MT];
        #pragma unroll
        for (int mt = 0; mt < MT; ++mt)
            a[mt] = *(const s16x8*)&W[(size_t)(mt * 16 + fr) * KW + kq * 32 + k8];
        s16x8 b[NF];
        #pragma unroll
        for (int nf = 0; nf < NF; ++nf) {
            const int row = rowBase + nf * 16 + fr;
            const int kb  = ((kq * 32 + k8) * 2) ^ ((row & 7) << 4);
            b[nf] = *(const s16x8*)(ldsB + row * RS + kb);
        }
        #pragma unroll
        for (int mt = 0; mt < MT; ++mt)
            #pragma unroll
            for (int nf = 0; nf < NF; ++nf)
                acc[mt][nf] = __builtin_amdgcn_mfma_f32_16x16x32_bf16(
                    a[mt], b[nf], acc[mt][nf], 0, 0, 0);
    }
}

template<int MT, int NF>
__device__ __forceinline__ void zacc(f32x4 (&acc)[MT][NF])
{
    #pragma unroll
    for (int mt = 0; mt < MT; ++mt)
        #pragma unroll
        for (int nf = 0; nf < NF; ++nf)
            acc[mt][nf] = (f32x4){0.f, 0.f, 0.f, 0.f};
}

__device__ __forceinline__ void packA(char* lds, int RS, int row, int outF0, f32x4 v)
{
    uint2 p;
    p.x = cvtpk(v[0], v[1]);
    p.y = cvtpk(v[2], v[3]);
    *(uint2*)(lds + row * RS + ((outF0 * 2) ^ ((row & 7) << 4))) = p;
}

__device__ __forceinline__ void store_bf4(unsigned short* dst, f32x4 v)
{
    uint2 p;
    p.x = cvtpk(v[0], v[1]);
    p.y = cvtpk(v[2], v[3]);
    *(uint2*)dst = p;
}

// stage ROWS x 128 f32 -> swizzled bf16 LDS (RS=256), 512 threads
template<int ROWS>
__device__ __forceinline__ void stage_f32(char* lds, const float* __restrict__ src,
                                          int row0, int M, int tid)
{
    #pragma unroll
    for (int u = 0; u < ROWS * 16 / 512; ++u) {
        const int flat = tid + u * 512;
        const int row  = flat >> 4;
        const int k8   = (flat & 15) << 3;
        const int grow = row0 + row;
        uint4 val = {0u, 0u, 0u, 0u};
        if (grow < M) {
            const float* p = src + (size_t)grow * 128 + k8;
            f32x4 lo = *(const f32x4*)p;
            f32x4 hi = *(const f32x4*)(p + 4);
            val.x = cvtpk(lo[0], lo[1]);
            val.y = cvtpk(lo[2], lo[3]);
            val.z = cvtpk(hi[0], hi[1]);
            val.w = cvtpk(hi[2], hi[3]);
        }
        *(uint4*)(lds + row * 256 + ((k8 * 2) ^ ((row & 7) << 4))) = val;
    }
}

// ---------------------------------------------------------------------------
// one ResidualLayer (8-wave, NF row-groups): inter = act(x@W0);
// y = act(inter@W1); x = (x+y)*C (+ optional (x+m_st)*C).
// ---------------------------------------------------------------------------
template<bool MSTM, int NF>
__device__ __forceinline__ void res_layer(
    char* A, char* B,
    const unsigned short* W0, const unsigned short* W1,
    int wm, int wn, int l, f32x4 (&x)[4][NF],
    const float* __restrict__ mst, int row0, int M)
{
    const int fr = l & 15;
    const int fq = (l >> 4) << 2;
    f32x4 acc[4][NF];
    zacc(acc);
    gemmT<4, NF, 4>(A, 256, W0 + (size_t)(wm * 64) * 128, 128, wn * NF * 16, l, acc);
    #pragma unroll
    for (int mt = 0; mt < 4; ++mt)
        #pragma unroll
        for (int nf = 0; nf < NF; ++nf) {
            const int row = wn * NF * 16 + nf * 16 + fr;
            const int of0 = wm * 64 + mt * 16 + fq;
            f32x4 v;
            #pragma unroll
            for (int q = 0; q < 4; ++q) v[q] = act_silu(acc[mt][nf][q]);
            packA(B, 256, row, of0, v);
        }
    __syncthreads();
    zacc(acc);
    gemmT<4, NF, 4>(B, 256, W1 + (size_t)(wm * 64) * 128, 128, wn * NF * 16, l, acc);
    #pragma unroll
    for (int mt = 0; mt < 4; ++mt)
        #pragma unroll
        for (int nf = 0; nf < NF; ++nf) {
            const int row = wn * NF * 16 + nf * 16 + fr;
            const int of0 = wm * 64 + mt * 16 + fq;
            #pragma unroll
            for (int q = 0; q < 4; ++q)
                x[mt][nf][q] = (x[mt][nf][q] + act_silu(acc[mt][nf][q])) * C_INV;
            if (MSTM) {
                const int grow = row0 + row;
                if (grow < M) {
                    f32x4 mv = *(const f32x4*)&mst[(size_t)grow * 128 + of0];
                    #pragma unroll
                    for (int q = 0; q < 4; ++q)
                        x[mt][nf][q] = (x[mt][nf][q] + mv[q]) * C_INV;
                }
            }
            packA(A, 256, row, of0, x[mt][nf]);
        }
    __syncthreads();
}

// ---------------------------------------------------------------------------
// front: tpre = act(m_st@W_m_kt)*scale ; mkt = act(tpre@W_down)
// ---------------------------------------------------------------------------
__global__ __launch_bounds__(512, 4) void front_k(
    const float* __restrict__ m_st, const unsigned short* __restrict__ scale_b,
    const unsigned short* __restrict__ Wmkt, const unsigned short* __restrict__ Wdown,
    unsigned short* __restrict__ mkt_b)
{
    __shared__ char A[128 * 256];
    const int tid = threadIdx.x;
    const int l = tid & 63, w = tid >> 6, wm = w & 1, wn = w >> 1;
    const int fr = l & 15, fq = (l >> 4) << 2;
    const int row0 = blockIdx.x * 128;

    stage_f32<128>(A, m_st, row0, EE, tid);
    __syncthreads();

    f32x4 acc[4][2];
    zacc(acc);
    gemmT<4, 2, 4>(A, 256, Wmkt + (size_t)(wm * 64) * 128, 128, wn * 32, l, acc);
    __syncthreads();
    #pragma unroll
    for (int mt = 0; mt < 4; ++mt)
        #pragma unroll
        for (int nf = 0; nf < 2; ++nf) {
            const int row = wn * 32 + nf * 16 + fr;
            const int grow = row0 + row;
            const int of0 = wm * 64 + mt * 16 + fq;
            f32x4 v = {0.f, 0.f, 0.f, 0.f};
            if (grow < EE) {
                s16x4 sc = *(const s16x4*)&scale_b[(size_t)grow * 128 + of0];
                #pragma unroll
                for (int q = 0; q < 4; ++q)
                    v[q] = act_silu(acc[mt][nf][q]) * bf2f((unsigned short)sc[q]);
            }
            packA(A, 256, row, of0, v);
        }
    __syncthreads();

    f32x4 acc2[2][2];
    zacc(acc2);
    gemmT<2, 2, 4>(A, 256, Wdown + (size_t)(wm * 32) * 128, 128, wn * 32, l, acc2);
    #pragma unroll
    for (int mt = 0; mt < 2; ++mt)
        #pragma unroll
        for (int nf = 0; nf < 2; ++nf) {
            const int row = wn * 32 + nf * 16 + fr;
            const int grow = row0 + row;
            if (grow >= EE) continue;
            const int of0 = wm * 32 + mt * 16 + fq;
            f32x4 v;
            #pragma unroll
            for (int q = 0; q < 4; ++q) v[q] = act_silu(acc2[mt][nf][q]);
            store_bf4(&mkt_b[(size_t)grow * 64 + of0], v);
        }
}

// ---------------------------------------------------------------------------
// st3/ts3: y_st = act(xb@W_st3), y_ts = act(xb@W_ts3)
// ---------------------------------------------------------------------------
__global__ __launch_bounds__(512, 4) void st3ts3_k(
    const unsigned short* __restrict__ xb_b,
    const unsigned short* __restrict__ Wst3, const unsigned short* __restrict__ Wts3,
    unsigned short* __restrict__ yst, unsigned short* __restrict__ yts)
{
    __shared__ char A[128 * 128];
    const int tid = threadIdx.x;
    const int l = tid & 63, w = tid >> 6, wm = w & 1, wn = w >> 1;
    const int fr = l & 15, fq = (l >> 4) << 2;
    const int row0 = blockIdx.x * 128;

    #pragma unroll
    for (int u = 0; u < 2; ++u) {
        const int flat = tid + u * 512;
        const int row = flat >> 3;
        const int k8 = (flat & 7) << 3;
        const int grow = row0 + row;
        s16x8 v = {0, 0, 0, 0, 0, 0, 0, 0};
        if (grow < EE) v = *(const s16x8*)&xb_b[(size_t)grow * 64 + k8];
        *(s16x8*)(A + row * 128 + ((k8 * 2) ^ ((row & 7) << 4))) = v;
    }
    __syncthreads();

    f32x4 aS[4][2], aT[4][2];
    zacc(aS); zacc(aT);
    gemmT<4, 2, 2>(A, 128, Wst3 + (size_t)(wm * 64) * 64, 64, wn * 32, l, aS);
    gemmT<4, 2, 2>(A, 128, Wts3 + (size_t)(wm * 64) * 64, 64, wn * 32, l, aT);

    #pragma unroll
    for (int mt = 0; mt < 4; ++mt)
        #pragma unroll
        for (int nf = 0; nf < 2; ++nf) {
            const int row = wn * 32 + nf * 16 + fr;
            const int grow = row0 + row;
            if (grow >= EE) continue;
            const int of0 = wm * 64 + mt * 16 + fq;
            f32x4 vs, vt;
            #pragma unroll
            for (int q = 0; q < 4; ++q) {
                vs[q] = act_silu(aS[mt][nf][q]);
                vt[q] = act_silu(aT[mt][nf][q]);
            }
            store_bf4(&yst[(size_t)grow * 128 + of0], vs);
            store_bf4(&yts[(size_t)grow * 128 + of0], vt);
        }
}

// ---------------------------------------------------------------------------
// chain: x_skip + (y_st + y_ts[swap]) merge + resb + m_st merge + resa x2
// output: x_b (bf16 only)
// ---------------------------------------------------------------------------
__global__ __launch_bounds__(512, 4) void chain_k(
    const float* __restrict__ m_st,
    const unsigned short* __restrict__ yst, const unsigned short* __restrict__ yts,
    const int* __restrict__ idx_swap,
    const unsigned short* __restrict__ Wmlp,
    const unsigned short* __restrict__ Wrb0, const unsigned short* __restrict__ Wrb1,
    const unsigned short* __restrict__ Wra0, const unsigned short* __restrict__ Wra1,
    const unsigned short* __restrict__ Wra2, const unsigned short* __restrict__ Wra3,
    unsigned short* __restrict__ xb_out)
{
    __shared__ char A[128 * 256];
    __shared__ char B[128 * 256];
    const int tid = threadIdx.x;
    const int l = tid & 63, w = tid >> 6, wm = w & 1, wn = w >> 1;
    const int fr = l & 15, fq = (l >> 4) << 2;
    const int row0 = blockIdx.x * 128;

    stage_f32<128>(A, m_st, row0, EE, tid);
    __syncthreads();

    f32x4 acc[4][2];
    zacc(acc);
    gemmT<4, 2, 4>(A, 256, Wmlp + (size_t)(wm * 64) * 128, 128, wn * 32, l, acc);

    f32x4 x[4][2];
    #pragma unroll
    for (int mt = 0; mt < 4; ++mt)
        #pragma unroll
        for (int nf = 0; nf < 2; ++nf) {
            const int row = wn * 32 + nf * 16 + fr;
            const int grow = row0 + row;
            const int of0 = wm * 64 + mt * 16 + fq;
            if (grow < EE) {
                s16x4 a = *(const s16x4*)&yst[(size_t)grow * 128 + of0];
                const int sw = idx_swap[grow];
                s16x4 b = *(const s16x4*)&yts[(size_t)sw * 128 + of0];
                #pragma unroll
                for (int q = 0; q < 4; ++q)
                    x[mt][nf][q] = (acc[mt][nf][q] +
                        (bf2f((unsigned short)a[q]) + bf2f((unsigned short)b[q])) * C_INV) * C_INV;
            } else {
                x[mt][nf] = (f32x4){0.f, 0.f, 0.f, 0.f};
            }
        }
    __syncthreads();
    #pragma unroll
    for (int mt = 0; mt < 4; ++mt)
        #pragma unroll
        for (int nf = 0; nf < 2; ++nf)
            packA(A, 256, wn * 32 + nf * 16 + fr, wm * 64 + mt * 16 + fq, x[mt][nf]);
    __syncthreads();

    res_layer<true , 2>(A, B, Wrb0, Wrb1, wm, wn, l, x, m_st, row0, EE);
    res_layer<false, 2>(A, B, Wra0, Wra1, wm, wn, l, x, m_st, row0, EE);
    res_layer<false, 2>(A, B, Wra2, Wra3, wm, wn, l, x, m_st, row0, EE);

    #pragma unroll
    for (int mt = 0; mt < 4; ++mt)
        #pragma unroll
        for (int nf = 0; nf < 2; ++nf) {
            const int row = wn * 32 + nf * 16 + fr;
            const int grow = row0 + row;
            if (grow >= EE) continue;
            const int of0 = wm * 64 + mt * 16 + fq;
            store_bf4(&xb_out[(size_t)grow * 128 + of0], x[mt][nf]);
        }
}

// ---------------------------------------------------------------------------
// atom chain (64-row tiles, NF=1)
// ---------------------------------------------------------------------------
__global__ __launch_bounds__(512, 4) void atom_k(
    const float* __restrict__ h2,
    const unsigned short* __restrict__ Wae,
    const unsigned short* __restrict__ Wr0, const unsigned short* __restrict__ Wr1,
    const unsigned short* __restrict__ Wr2, const unsigned short* __restrict__ Wr3,
    float* __restrict__ out_h, unsigned short* __restrict__ h_b)
{
    __shared__ char A[64 * 256];
    __shared__ char B[64 * 256];
    const int tid = threadIdx.x;
    const int l = tid & 63, w = tid >> 6, wm = w & 1, wn = w >> 1;
    const int fr = l & 15, fq = (l >> 4) << 2;
    const int row0 = blockIdx.x * 64;

    stage_f32<64>(A, h2, row0, NA, tid);
    __syncthreads();

    f32x4 acc[4][1];
    zacc(acc);
    gemmT<4, 1, 4>(A, 256, Wae + (size_t)(wm * 64) * 128, 128, wn * 16, l, acc);
    f32x4 x[4][1];
    #pragma unroll
    for (int mt = 0; mt < 4; ++mt)
        #pragma unroll
        for (int q = 0; q < 4; ++q)
            x[mt][0][q] = act_silu(acc[mt][0][q]);
    __syncthreads();
    #pragma unroll
    for (int mt = 0; mt < 4; ++mt)
        packA(A, 256, wn * 16 + fr, wm * 64 + mt * 16 + fq, x[mt][0]);
    __syncthreads();

    res_layer<false, 1>(A, B, Wr0, Wr1, wm, wn, l, x, nullptr, row0, NA);
    res_layer<false, 1>(A, B, Wr2, Wr3, wm, wn, l, x, nullptr, row0, NA);

    #pragma unroll
    for (int mt = 0; mt < 4; ++mt) {
        const int row = wn * 16 + fr;
        const int grow = row0 + row;
        if (grow >= NA) continue;
        const int of0 = wm * 64 + mt * 16 + fq;
        *(f32x4*)&out_h[(size_t)grow * 128 + of0] = x[mt][0];
        store_bf4(&h_b[(size_t)grow * 128 + of0], x[mt][0]);
    }
}

// ---------------------------------------------------------------------------
// ASI + res_m: m = act([h[s]|h[t]|x]@W_asi); res_m x2; out_m = (m + x)*C
// ---------------------------------------------------------------------------
__global__ __launch_bounds__(512, 4) void asi_k(
    const unsigned short* __restrict__ h_b, const unsigned short* __restrict__ x_b,
    const int* __restrict__ idx_s, const int* __restrict__ idx_t,
    const unsigned short* __restrict__ Wasi,
    const unsigned short* __restrict__ Wm0, const unsigned short* __restrict__ Wm1,
    const unsigned short* __restrict__ Wm2, const unsigned short* __restrict__ Wm3,
    float* __restrict__ out_m)
{
    __shared__ char A[128 * 256];
    __shared__ char B[128 * 256];
    const int tid = threadIdx.x;
    const int l = tid & 63, w = tid >> 6, wm = w & 1, wn = w >> 1;
    const int fr = l & 15, fq = (l >> 4) << 2;
    const int row0 = blockIdx.x * 128;

    f32x4 acc[4][2];
    zacc(acc);

    for (int c = 0; c < 3; ++c) {
        #pragma unroll
        for (int u = 0; u < 4; ++u) {
            const int flat = tid + u * 512;
            const int row = flat >> 4;
            const int k8 = (flat & 15) << 3;
            const int grow = row0 + row;
            s16x8 v = {0, 0, 0, 0, 0, 0, 0, 0};
            if (grow < EE) {
                const unsigned short* src =
                    (c == 0) ? h_b + (size_t)idx_s[grow] * 128
                  : (c == 1) ? h_b + (size_t)idx_t[grow] * 128
                             : x_b + (size_t)grow * 128;
                v = *(const s16x8*)&src[k8];
            }
            *(s16x8*)(A + row * 256 + ((k8 * 2) ^ ((row & 7) << 4))) = v;
        }
        __syncthreads();
        gemmT<4, 2, 4>(A, 256, Wasi + (size_t)(wm * 64) * 384 + c * 128, 384, wn * 32, l, acc);
        __syncthreads();
    }

    f32x4 x[4][2];
    #pragma unroll
    for (int mt = 0; mt < 4; ++mt)
        #pragma unroll
        for (int nf = 0; nf < 2; ++nf)
            #pragma unroll
            for (int q = 0; q < 4; ++q)
                x[mt][nf][q] = act_silu(acc[mt][nf][q]);
    #pragma unroll
    for (int mt = 0; mt < 4; ++mt)
        #pragma unroll
        for (int nf = 0; nf < 2; ++nf)
            packA(A, 256, wn * 32 + nf * 16 + fr, wm * 64 + mt * 16 + fq, x[mt][nf]);
    __syncthreads();

    res_layer<false, 2>(A, B, Wm0, Wm1, wm, wn, l, x, nullptr, row0, EE);
    res_layer<false, 2>(A, B, Wm2, Wm3, wm, wn, l, x, nullptr, row0, EE);

    #pragma unroll
    for (int mt = 0; mt < 4; ++mt)
        #pragma unroll
        for (int nf = 0; nf < 2; ++nf) {
            const int row = wn * 32 + nf * 16 + fr;
            const int grow = row0 + row;
            if (grow >= EE) continue;
            const int of0 = wm * 64 + mt * 16 + fq;
            s16x4 xv = *(const s16x4*)&x_b[(size_t)grow * 128 + of0];
            f32x4 o;
            #pragma unroll
            for (int q = 0; q < 4; ++q)
                o[q] = (x[mt][nf][q] + bf2f((unsigned short)xv[q])) * C_INV;
            *(f32x4*)&out_m[(size_t)grow * 128 + of0] = o;
        }
}

// ---------------------------------------------------------------------------
// rbf scale: scale = rbf3 @ W_t_rbf -> bf16
// ---------------------------------------------------------------------------
__global__ __launch_bounds__(256) void rbf_scale_k(
    const float* __restrict__ A, const float* __restrict__ W,
    unsigned short* __restrict__ out, int M)
{
    __shared__ float Ws[16][128];
    const int tid = threadIdx.x;
    #pragma unroll
    for (int t = tid; t < 512; t += 256) {
        int kk = t >> 5, c4 = (t & 31) << 2;
        *(float4*)&Ws[kk][c4] = *(const float4*)(W + kk * 128 + c4);
    }
    __syncthreads();
    const int tx = tid & 31, ty = tid >> 5;
    const int row0 = blockIdx.x * 128;
    #pragma unroll
    for (int i = 0; i < 16; ++i) {
        const int row = row0 + ty + i * 8;
        if (row >= M) continue;
        float av[16];
        #pragma unroll
        for (int j = 0; j < 4; ++j) {
            float4 a = *(const float4*)(A + (size_t)row * 16 + j * 4);
            av[j * 4] = a.x; av[j * 4 + 1] = a.y; av[j * 4 + 2] = a.z; av[j * 4 + 3] = a.w;
        }
        f32x4 s = {0.f, 0.f, 0.f, 0.f};
        #pragma unroll
        for (int k = 0; k < 16; ++k) {
            float4 wv = *(const float4*)&Ws[k][tx * 4];
            s[0] += av[k] * wv.x; s[1] += av[k] * wv.y;
            s[2] += av[k] * wv.z; s[3] += av[k] * wv.w;
        }
        store_bf4(&out[(size_t)row * 128 + tx * 4], s);
    }
}

// ---------------------------------------------------------------------------
// counting sort of idx_t + gather segment-sum with fused coef
// ---------------------------------------------------------------------------
__global__ void hist_k(const int* __restrict__ idxt, int* __restrict__ cnt)
{
    int i = blockIdx.x * 256 + threadIdx.x;
    if (i < EE) atomicAdd(&cnt[idxt[i]], 1);
}

__global__ __launch_bounds__(256) void scan_k(const int* __restrict__ cnt,
                                              int* __restrict__ start, int* __restrict__ wrk)
{
    __shared__ int ps[256];
    const int t = threadIdx.x;
    int s = 0;
    for (int j = 0; j < 40; ++j) {
        int idx = t * 40 + j;
        if (idx < NA) s += cnt[idx];
    }
    ps[t] = s;
    __syncthreads();
    for (int off = 1; off < 256; off <<= 1) {
        int v = (t >= off) ? ps[t - off] : 0;
        __syncthreads();
        ps[t] += v;
        __syncthreads();
    }
    int run = ps[t] - s;
    for (int j = 0; j < 40; ++j) {
        int idx = t * 40 + j;
        if (idx < NA) {
            start[idx] = run;
            wrk[idx] = run;
            run += cnt[idx];
        }
    }
    if (t == 255) start[NA] = ps[255];
}

__global__ void place_k(const int* __restrict__ idxt, int* __restrict__ wrk,
                        int* __restrict__ order)
{
    int i = blockIdx.x * 256 + threadIdx.x;
    if (i < EE) {
        int pos = atomicAdd(&wrk[idxt[i]], 1);
        order[pos] = i;
    }
}

// one wave per atom: h2[a] = sum_{e in bucket} x_b[e] * (rbf_h[e] @ W_ae_rbf)
__global__ __launch_bounds__(256) void segsum_k(
    const unsigned short* __restrict__ x_b, const float* __restrict__ rbf_h,
    const float* __restrict__ Wae, const int* __restrict__ start,
    const int* __restrict__ order, float* __restrict__ h2)
{
    const int tid = threadIdx.x;
    const int l = tid & 63, w = tid >> 6;
    const int a = blockIdx.x * 4 + w;
    if (a >= NA) return;

    float wc[32];
    #pragma unroll
    for (int j = 0; j < 16; ++j) {
        f32x2 v = *(const f32x2*)(Wae + j * 128 + 2 * l);
        wc[2 * j] = v[0]; wc[2 * j + 1] = v[1];
    }

    const int s = start[a], e_end = start[a + 1];
    float acc0 = 0.f, acc1 = 0.f;
    for (int i = s; i < e_end; ++i) {
        const int e = __builtin_amdgcn_readfirstlane(order[i]);
        const unsigned int xv = *(const unsigned int*)(x_b + (size_t)e * 128 + 2 * l);
        const float* rp = rbf_h + (size_t)e * 16;
        float c0 = 0.f, c1 = 0.f;
        #pragma unroll
        for (int j = 0; j < 16; ++j) {
            float r = rp[j];
            c0 += r * wc[2 * j];
            c1 += r * wc[2 * j + 1];
        }
        acc0 += bf2f((unsigned short)(xv & 0xffff)) * c0;
        acc1 += bf2f((unsigned short)(xv >> 16)) * c1;
    }
    f32x2 o; o[0] = acc0; o[1] = acc1;
    *(f32x2*)&h2[(size_t)a * 128 + 2 * l] = o;
}

// ---------------------------------------------------------------------------
// weight conversions
// ---------------------------------------------------------------------------
__global__ void wconv_k(const float* __restrict__ Wbil, unsigned short* __restrict__ WT)
{
    int t = blockIdx.x * 256 + threadIdx.x;
    int u = t >> 10, k = t & 1023, j = k >> 6, c = k & 63;
    WT[t] = f2bf(Wbil[(size_t)(c * 16 + j) * 64 + u]);
}

struct WDesc { const float* src; int K; int N; int off; };
struct WTab  { WDesc d[21]; };

__global__ void wconvall_k(WTab tab, unsigned short* __restrict__ dst)
{
    WDesc d = tab.d[blockIdx.x];
    const int tot = d.K * d.N;
    for (int i = threadIdx.x; i < tot; i += 256) {
        int n = i / d.K, k = i - n * d.K;
        dst[d.off + i] = f2bf(d.src[(size_t)k * d.N + n]);
    }
}

// ---------------------------------------------------------------------------
// bilinear (readlane coefficients, bf16 in/out)
// ---------------------------------------------------------------------------
__device__ __forceinline__ float rlc(const f32x4& cv, int idx, int lbase)
{
    const int c = idx & 3;
    float comp = (c == 0) ? cv[0] : (c == 1) ? cv[1] : (c == 2) ? cv[2] : cv[3];
    return __uint_as_float(__builtin_amdgcn_readlane(__float_as_uint(comp),
                                                     lbase + (idx >> 2)));
}

__global__ __launch_bounds__(512) void bilinear3_k(
    const unsigned short* __restrict__ mkt,
    const float* __restrict__ rbfW1,
    const float* __restrict__ sph,
    const int*   __restrict__ id3kt,
    const unsigned short* __restrict__ WT,
    unsigned short* __restrict__ xb)
{
    __shared__ unsigned short aS[32 * 1024];
    float* pS = (float*)aS;

    const int tid = threadIdx.x;
    const int l   = tid & 63;
    const int w   = tid >> 6;
    const int e0  = blockIdx.x * 32;

    s16x8 bfrag[4][4];
    {
        const int u  = l & 15;
        const int kh = w * 128 + ((l >> 4) << 3);
        #pragma unroll
        for (int nt = 0; nt < 4; ++nt)
            #pragma unroll
            for (int kq = 0; kq < 4; ++kq)
                bfrag[nt][kq] = *(const s16x8*)&WT[(size_t)(nt * 16 + u) * 1024 + kh + kq * 32];
    }

    #pragma unroll
    for (int r = 0; r < 4; ++r) {
        const int eL = r * 8 + w;
        const int eG = e0 + eL;

        f32x4 cv = {0.f, 0.f, 0.f, 0.f};
        if (l < 14)       cv = *(const f32x4*)(sph   + (size_t)eG * 56  + l * 4);
        else if (l < 42)  cv = *(const f32x4*)(rbfW1 + (size_t)eG * 112 + (l - 14) * 4);

        float m2r[8];
        #pragma unroll
        for (int k = 0; k < 8; ++k)
            m2r[k] = bf2f(mkt[(size_t)id3kt[eG * 8 + k] * 64 + l]);

        float sk[7] = {0.f, 0.f, 0.f, 0.f, 0.f, 0.f, 0.f};
        #pragma unroll
        for (int k = 0; k < 8; ++k)
            #pragma unroll
            for (int s = 0; s < 7; ++s)
                sk[s] += rlc(cv, k * 7 + s, 0) * m2r[k];

        unsigned short* arow = aS + eL * 1024;
        const int lsw = l ^ ((eL & 7) << 3);
        #pragma unroll
        for (int j = 0; j < 16; ++j) {
            float av = 0.f;
            #pragma unroll
            for (int s = 0; s < 7; ++s)
                av += rlc(cv, j * 7 + s, 14) * sk[s];
            arow[j * 64 + lsw] = f2bf(av);
        }
    }
    __syncthreads();

    f32x4 acc[2][4];
    #pragma unroll
    for (int mt = 0; mt < 2; ++mt)
        #pragma unroll
        for (int nt = 0; nt < 4; ++nt)
            acc[mt][nt] = (f32x4){0.f, 0.f, 0.f, 0.f};

    const int kbase = w * 128 + ((l >> 4) << 3);
    #pragma unroll
    for (int kq = 0; kq < 4; ++kq) {
        s16x8 afr[2];
        #pragma unroll
        for (int mt = 0; mt < 2; ++mt) {
            const int row = mt * 16 + (l & 15);
            const int kk  = (kbase + kq * 32) ^ ((row & 7) << 3);
            afr[mt] = *(const s16x8*)&aS[row * 1024 + kk];
        }
        #pragma unroll
        for (int mt = 0; mt < 2; ++mt)
            #pragma unroll
            for (int nt = 0; nt < 4; ++nt)
                acc[mt][nt] = __builtin_amdgcn_mfma_f32_16x16x32_bf16(
                    afr[mt], bfrag[nt][kq], acc[mt][nt], 0, 0, 0);
    }
    __syncthreads();

    #pragma unroll
    for (int mt = 0; mt < 2; ++mt)
        #pragma unroll
        for (int nt = 0; nt < 4; ++nt)
            #pragma unroll
            for (int q = 0; q < 4; ++q) {
                const int e = mt * 16 + ((l >> 4) << 2) + q;
                const int u = nt * 16 + (l & 15);
                pS[(w * 32 + e) * 64 + u] = acc[mt][nt][q];
            }
    __syncthreads();

    {
        const int e  = tid >> 4;
        const int u0 = (tid & 15) << 2;
        f32x4 s = (f32x4){0.f, 0.f, 0.f, 0.f};
        #pragma unroll
        for (int ww = 0; ww < 8; ++ww)
            s += *(const f32x4*)&pS[(ww * 32 + e) * 64 + u0];
        store_bf4(&xb[(size_t)(e0 + e) * 64 + u0], s);
    }
}

// ---------------------------------------------------------------------------
// launch
// ---------------------------------------------------------------------------
extern "C" void kernel_launch(void* const* d_in, const int* in_sizes, int n_in,
                              void* d_out, int out_size, void* d_ws, size_t ws_size,
                              hipStream_t stream)
{
    const float* m_st      = (const float*)d_in[1];
    const float* rbf_h     = (const float*)d_in[2];
    const float* rbf3      = (const float*)d_in[3];
    const float* cbf_rbfW1 = (const float*)d_in[4];
    const float* cbf_sph   = (const float*)d_in[5];
    const float* W_mlp_st  = (const float*)d_in[6];
    const float* W_m_kt    = (const float*)d_in[7];
    const float* W_t_rbf   = (const float*)d_in[8];
    const float* W_down    = (const float*)d_in[9];
    const float* W_bil     = (const float*)d_in[10];
    const float* W_st3     = (const float*)d_in[11];
    const float* W_ts3     = (const float*)d_in[12];
    const float* resb      = (const float*)d_in[13];
    const float* resa      = (const float*)d_in[14];
    const float* W_ae_rbf  = (const float*)d_in[15];
    const float* W_ae_in   = (const float*)d_in[16];
    const float* resat     = (const float*)d_in[17];
    const float* W_asi     = (const float*)d_in[18];
    const float* resm      = (const float*)d_in[19];
    const int*   idx_s     = (const int*)d_in[20];
    const int*   idx_t     = (const int*)d_in[21];
    const int*   idx_swap  = (const int*)d_in[22];
    const int*   id3_kt    = (const int*)d_in[23];

    float* h2 = (float*)d_ws;                               // NA x 128 f32
    unsigned short* scale_b = (unsigned short*)(h2 + (size_t)NA * 128);
    unsigned short* yst_b   = scale_b;                      // alias (scale dead first)
    unsigned short* yts_b   = scale_b + (size_t)EE * 128;
    unsigned short* x_b     = yts_b + (size_t)EE * 128;
    unsigned short* mkt_b   = x_b + (size_t)EE * 128;
    unsigned short* xb_b    = mkt_b + (size_t)EE * 64;
    unsigned short* h_b     = xb_b + (size_t)EE * 64;
    unsigned short* WTbil   = h_b + (size_t)NA * 128;
    unsigned short* WTall   = WTbil + 65536;
    int* cnt   = (int*)(WTall + 352256);
    int* start = cnt + NA;
    int* wrk   = start + NA + 1;
    int* order = wrk + NA;

    float* out_h = (float*)d_out;
    float* out_m = out_h + (size_t)NA * 128;

    const dim3 blk(256);
    const dim3 blk5(512);
    const int gE  = (EE + 127) / 128;   // 938
    const int gN64 = (NA + 63) / 64;    // 157
    constexpr size_t SQ = 128 * 128;

    WTab tab; int off = 0; int oi = 0;
    auto put = [&](const float* s, int K, int N) {
        int o = off; tab.d[oi].src = s; tab.d[oi].K = K; tab.d[oi].N = N;
        tab.d[oi].off = o; ++oi; off += K * N; return o;
    };
    const int o_mlp  = put(W_mlp_st, 128, 128);
    const int o_mktw = put(W_m_kt, 128, 128);
    const int o_down = put(W_down, 128, 64);
    const int o_st3  = put(W_st3, 64, 128);
    const int o_ts3  = put(W_ts3, 64, 128);
    const int o_rb0  = put(resb, 128, 128);
    const int o_rb1  = put(resb + SQ, 128, 128);
    const int o_ra0  = put(resa, 128, 128);
    const int o_ra1  = put(resa + SQ, 128, 128);
    const int o_ra2  = put(resa + 2 * SQ, 128, 128);
    const int o_ra3  = put(resa + 3 * SQ, 128, 128);
    const int o_aein = put(W_ae_in, 128, 128);
    const int o_rat0 = put(resat, 128, 128);
    const int o_rat1 = put(resat + SQ, 128, 128);
    const int o_rat2 = put(resat + 2 * SQ, 128, 128);
    const int o_rat3 = put(resat + 3 * SQ, 128, 128);
    const int o_asi  = put(W_asi, 384, 128);
    const int o_rm0  = put(resm, 128, 128);
    const int o_rm1  = put(resm + SQ, 128, 128);
    const int o_rm2  = put(resm + 2 * SQ, 128, 128);
    const int o_rm3  = put(resm + 3 * SQ, 128, 128);

    hipMemsetAsync(cnt, 0, NA * sizeof(int), stream);
    wconv_k<<<65536 / 256, blk, 0, stream>>>(W_bil, WTbil);
    wconvall_k<<<21, blk, 0, stream>>>(tab, WTall);
    hist_k<<<(EE + 255) / 256, blk, 0, stream>>>(idx_t, cnt);
    scan_k<<<1, blk, 0, stream>>>(cnt, start, wrk);
    place_k<<<(EE + 255) / 256, blk, 0, stream>>>(idx_t, wrk, order);

    rbf_scale_k<<<gE, blk, 0, stream>>>(rbf3, W_t_rbf, scale_b, EE);
    front_k<<<gE, blk5, 0, stream>>>(m_st, scale_b, WTall + o_mktw, WTall + o_down, mkt_b);
    bilinear3_k<<<EE / 32, blk5, 0, stream>>>(
        mkt_b, cbf_rbfW1, cbf_sph, id3_kt, WTbil, xb_b);
    st3ts3_k<<<gE, blk5, 0, stream>>>(xb_b, WTall + o_st3, WTall + o_ts3, yst_b, yts_b);
    chain_k<<<gE, blk5, 0, stream>>>(
        m_st, yst_b, yts_b, idx_swap,
        WTall + o_mlp, WTall + o_rb0, WTall + o_rb1,
        WTall + o_ra0, WTall + o_ra1, WTall + o_ra2, WTall + o_ra3,
        x_b);
    segsum_k<<<(NA + 3) / 4, blk, 0, stream>>>(x_b, rbf_h, W_ae_rbf, start, order, h2);
    atom_k<<<gN64, blk5, 0, stream>>>(
        h2, WTall + o_aein,
        WTall + o_rat0, WTall + o_rat1, WTall + o_rat2, WTall + o_rat3,
        out_h, h_b);
    asi_k<<<gE, blk5, 0, stream>>>(
        h_b, x_b, idx_s, idx_t,
        WTall + o_asi,
        WTall + o_rm0, WTall + o_rm1, WTall + o_rm2, WTall + o_rm3,
        out_m);
}

// Round 7
// 701.744 us; speedup vs baseline: 4.8808x; 1.1837x over previous
//
#include <hip/hip_runtime.h>

// ---------------------------------------------------------------------------
// GemNet InteractionBlock forward, MI355X (gfx950).
// Round 7: software-pipelined weight loads (load_w array + gemm_pre),
// 4-feat x 2-row wave geometry (MT=2,NF=4), m_st merge from LDS not HBM.
// ---------------------------------------------------------------------------

#define EE 120000
#define NA 10000

constexpr float C_INV = 0.70710678118654752440f;

using f32x4 = __attribute__((ext_vector_type(4))) float;
using f32x2 = __attribute__((ext_vector_type(2))) float;
using s16x8 = __attribute__((ext_vector_type(8))) short;
using s16x4 = __attribute__((ext_vector_type(4))) short;

__device__ __forceinline__ float act_silu(float x) { return x / (1.0f + __expf(-x)); }

__device__ __forceinline__ unsigned short f2bf(float f) {
    unsigned int u = __float_as_uint(f);
    u += 0x7fffu + ((u >> 16) & 1u);
    return (unsigned short)(u >> 16);
}
__device__ __forceinline__ float bf2f(unsigned short h) {
    return __uint_as_float(((unsigned int)h) << 16);
}
__device__ __forceinline__ unsigned int cvtpk(float a, float b) {
    unsigned int r;
    asm("v_cvt_pk_bf16_f32 %0, %1, %2" : "=v"(r) : "v"(a), "v"(b));
    return r;
}

// ---------------------------------------------------------------------------
// weight fragment preload: a[mt][kq] = W[(mt*16+fr)][kq*32+k8 .. +8]
// ---------------------------------------------------------------------------
template<int MT, int KQ>
__device__ __forceinline__ void load_w(const unsigned short* __restrict__ W, int KW,
                                       int l, s16x8 (&a)[MT][KQ])
{
    const int fr = l & 15;
    const int k8 = (l >> 4) << 3;
    #pragma unroll
    for (int mt = 0; mt < MT; ++mt)
        #pragma unroll
        for (int kq = 0; kq < KQ; ++kq)
            a[mt][kq] = *(const s16x8*)&W[(size_t)(mt * 16 + fr) * KW + kq * 32 + k8];
}

// MFMA with preloaded weights; b from swizzled LDS
template<int MT, int NF, int KQ>
__device__ __forceinline__ void gemm_pre(
    const s16x8 (&a)[MT][KQ], const char* ldsB, int RS,
    int rowBase, int l, f32x4 (&acc)[MT][NF])
{
    const int fr = l & 15;
    const int k8 = (l >> 4) << 3;
    #pragma unroll
    for (int kq = 0; kq < KQ; ++kq) {
        s16x8 b[NF];
        #pragma unroll
        for (int nf = 0; nf < NF; ++nf) {
            const int row = rowBase + nf * 16 + fr;
            const int kb  = ((kq * 32 + k8) * 2) ^ ((row & 7) << 4);
            b[nf] = *(const s16x8*)(ldsB + row * RS + kb);
        }
        #pragma unroll
        for (int mt = 0; mt < MT; ++mt)
            #pragma unroll
            for (int nf = 0; nf < NF; ++nf)
                acc[mt][nf] = __builtin_amdgcn_mfma_f32_16x16x32_bf16(
                    a[mt][kq], b[nf], acc[mt][nf], 0, 0, 0);
    }
}

template<int MT, int NF>
__device__ __forceinline__ void zacc(f32x4 (&acc)[MT][NF])
{
    #pragma unroll
    for (int mt = 0; mt < MT; ++mt)
        #pragma unroll
        for (int nf = 0; nf < NF; ++nf)
            acc[mt][nf] = (f32x4){0.f, 0.f, 0.f, 0.f};
}

__device__ __forceinline__ void packA(char* lds, int RS, int row, int outF0, f32x4 v)
{
    uint2 p;
    p.x = cvtpk(v[0], v[1]);
    p.y = cvtpk(v[2], v[3]);
    *(uint2*)(lds + row * RS + ((outF0 * 2) ^ ((row & 7) << 4))) = p;
}

__device__ __forceinline__ void store_bf4(unsigned short* dst, f32x4 v)
{
    uint2 p;
    p.x = cvtpk(v[0], v[1]);
    p.y = cvtpk(v[2], v[3]);
    *(uint2*)dst = p;
}

// stage ROWS x 128 f32 -> swizzled bf16 LDS (RS=256), 512 threads
template<int ROWS>
__device__ __forceinline__ void stage_f32(char* lds, const float* __restrict__ src,
                                          int row0, int M, int tid)
{
    #pragma unroll
    for (int u = 0; u < ROWS * 16 / 512; ++u) {
        const int flat = tid + u * 512;
        const int row  = flat >> 4;
        const int k8   = (flat & 15) << 3;
        const int grow = row0 + row;
        uint4 val = {0u, 0u, 0u, 0u};
        if (grow < M) {
            const float* p = src + (size_t)grow * 128 + k8;
            f32x4 lo = *(const f32x4*)p;
            f32x4 hi = *(const f32x4*)(p + 4);
            val.x = cvtpk(lo[0], lo[1]);
            val.y = cvtpk(lo[2], lo[3]);
            val.z = cvtpk(hi[0], hi[1]);
            val.w = cvtpk(hi[2], hi[3]);
        }
        *(uint4*)(lds + row * 256 + ((k8 * 2) ^ ((row & 7) << 4))) = val;
    }
}

// ---------------------------------------------------------------------------
// one ResidualLayer (8 waves: wm in 0..3 feat-quarters, wn in 0..1 row-halves)
// inter = act(x@W0); y = act(inter@W1); x = (x+y)*C (+ optional bf16 m_st merge)
// ---------------------------------------------------------------------------
template<bool MSTM, int NF>
__device__ __forceinline__ void res_layer(
    char* A, char* B,
    const unsigned short* W0, const unsigned short* W1,
    int wm, int wn, int l, f32x4 (&x)[2][NF],
    const s16x4 (*ms)[NF])          // bf16 m_st frags (MSTM only)
{
    const int fr = l & 15;
    const int fq = (l >> 4) << 2;

    s16x8 aw[2][4];
    load_w<2, 4>(W0 + (size_t)(wm * 32) * 128, 128, l, aw);
    f32x4 acc[2][NF];
    zacc(acc);
    gemm_pre<2, NF, 4>(aw, A, 256, wn * NF * 16, l, acc);

    s16x8 aw1[2][4];
    load_w<2, 4>(W1 + (size_t)(wm * 32) * 128, 128, l, aw1);   // issue before barrier

    #pragma unroll
    for (int mt = 0; mt < 2; ++mt)
        #pragma unroll
        for (int nf = 0; nf < NF; ++nf) {
            const int row = wn * NF * 16 + nf * 16 + fr;
            const int of0 = wm * 32 + mt * 16 + fq;
            f32x4 v;
            #pragma unroll
            for (int q = 0; q < 4; ++q) v[q] = act_silu(acc[mt][nf][q]);
            packA(B, 256, row, of0, v);
        }
    __syncthreads();

    zacc(acc);
    gemm_pre<2, NF, 4>(aw1, B, 256, wn * NF * 16, l, acc);
    #pragma unroll
    for (int mt = 0; mt < 2; ++mt)
        #pragma unroll
        for (int nf = 0; nf < NF; ++nf) {
            const int row = wn * NF * 16 + nf * 16 + fr;
            const int of0 = wm * 32 + mt * 16 + fq;
            #pragma unroll
            for (int q = 0; q < 4; ++q)
                x[mt][nf][q] = (x[mt][nf][q] + act_silu(acc[mt][nf][q])) * C_INV;
            if (MSTM) {
                #pragma unroll
                for (int q = 0; q < 4; ++q)
                    x[mt][nf][q] = (x[mt][nf][q] +
                                    bf2f((unsigned short)ms[mt][nf][q])) * C_INV;
            }
            packA(A, 256, row, of0, x[mt][nf]);
        }
    __syncthreads();
}

// read a bf16 fragment (4 feats) back from swizzled LDS
__device__ __forceinline__ s16x4 read_frag(const char* lds, int row, int of0)
{
    return *(const s16x4*)(lds + row * 256 + ((of0 * 2) ^ ((row & 7) << 4)));
}

// ---------------------------------------------------------------------------
// front: tpre = act(m_st@W_m_kt)*scale ; mkt = act(tpre@W_down)
// ---------------------------------------------------------------------------
__global__ __launch_bounds__(512, 4) void front_k(
    const float* __restrict__ m_st, const unsigned short* __restrict__ scale_b,
    const unsigned short* __restrict__ Wmkt, const unsigned short* __restrict__ Wdown,
    unsigned short* __restrict__ mkt_b)
{
    __shared__ char A[128 * 256];
    const int tid = threadIdx.x;
    const int l = tid & 63, w = tid >> 6, wm = w & 3, wn = w >> 2;
    const int fr = l & 15, fq = (l >> 4) << 2;
    const int row0 = blockIdx.x * 128;

    s16x8 aw[2][4];
    load_w<2, 4>(Wmkt + (size_t)(wm * 32) * 128, 128, l, aw);

    stage_f32<128>(A, m_st, row0, EE, tid);
    __syncthreads();

    f32x4 acc[2][4];
    zacc(acc);
    gemm_pre<2, 4, 4>(aw, A, 256, wn * 64, l, acc);

    s16x8 aw2[1][4];
    load_w<1, 4>(Wdown + (size_t)(wm * 16) * 128, 128, l, aw2);

    __syncthreads();
    #pragma unroll
    for (int mt = 0; mt < 2; ++mt)
        #pragma unroll
        for (int nf = 0; nf < 4; ++nf) {
            const int row = wn * 64 + nf * 16 + fr;
            const int grow = row0 + row;
            const int of0 = wm * 32 + mt * 16 + fq;
            f32x4 v = {0.f, 0.f, 0.f, 0.f};
            if (grow < EE) {
                s16x4 sc = *(const s16x4*)&scale_b[(size_t)grow * 128 + of0];
                #pragma unroll
                for (int q = 0; q < 4; ++q)
                    v[q] = act_silu(acc[mt][nf][q]) * bf2f((unsigned short)sc[q]);
            }
            packA(A, 256, row, of0, v);
        }
    __syncthreads();

    f32x4 acc2[1][4];
    zacc(acc2);
    gemm_pre<1, 4, 4>(aw2, A, 256, wn * 64, l, acc2);
    #pragma unroll
    for (int nf = 0; nf < 4; ++nf) {
        const int row = wn * 64 + nf * 16 + fr;
        const int grow = row0 + row;
        if (grow >= EE) continue;
        const int of0 = wm * 16 + fq;
        f32x4 v;
        #pragma unroll
        for (int q = 0; q < 4; ++q) v[q] = act_silu(acc2[0][nf][q]);
        store_bf4(&mkt_b[(size_t)grow * 64 + of0], v);
    }
}

// ---------------------------------------------------------------------------
// st3/ts3: y_st = act(xb@W_st3), y_ts = act(xb@W_ts3)
// ---------------------------------------------------------------------------
__global__ __launch_bounds__(512, 4) void st3ts3_k(
    const unsigned short* __restrict__ xb_b,
    const unsigned short* __restrict__ Wst3, const unsigned short* __restrict__ Wts3,
    unsigned short* __restrict__ yst, unsigned short* __restrict__ yts)
{
    __shared__ char A[128 * 128];
    const int tid = threadIdx.x;
    const int l = tid & 63, w = tid >> 6, wm = w & 3, wn = w >> 2;
    const int fr = l & 15, fq = (l >> 4) << 2;
    const int row0 = blockIdx.x * 128;

    s16x8 awS[2][2], awT[2][2];
    load_w<2, 2>(Wst3 + (size_t)(wm * 32) * 64, 64, l, awS);
    load_w<2, 2>(Wts3 + (size_t)(wm * 32) * 64, 64, l, awT);

    #pragma unroll
    for (int u = 0; u < 2; ++u) {
        const int flat = tid + u * 512;
        const int row = flat >> 3;
        const int k8 = (flat & 7) << 3;
        const int grow = row0 + row;
        s16x8 v = {0, 0, 0, 0, 0, 0, 0, 0};
        if (grow < EE) v = *(const s16x8*)&xb_b[(size_t)grow * 64 + k8];
        *(s16x8*)(A + row * 128 + ((k8 * 2) ^ ((row & 7) << 4))) = v;
    }
    __syncthreads();

    f32x4 aS[2][4], aT[2][4];
    zacc(aS); zacc(aT);
    {
        const int k8 = (l >> 4) << 3;
        #pragma unroll
        for (int kq = 0; kq < 2; ++kq) {
            s16x8 b[4];
            #pragma unroll
            for (int nf = 0; nf < 4; ++nf) {
                const int row = wn * 64 + nf * 16 + fr;
                const int kb  = ((kq * 32 + k8) * 2) ^ ((row & 7) << 4);
                b[nf] = *(const s16x8*)(A + row * 128 + kb);
            }
            #pragma unroll
            for (int mt = 0; mt < 2; ++mt)
                #pragma unroll
                for (int nf = 0; nf < 4; ++nf) {
                    aS[mt][nf] = __builtin_amdgcn_mfma_f32_16x16x32_bf16(
                        awS[mt][kq], b[nf], aS[mt][nf], 0, 0, 0);
                    aT[mt][nf] = __builtin_amdgcn_mfma_f32_16x16x32_bf16(
                        awT[mt][kq], b[nf], aT[mt][nf], 0, 0, 0);
                }
        }
    }

    #pragma unroll
    for (int mt = 0; mt < 2; ++mt)
        #pragma unroll
        for (int nf = 0; nf < 4; ++nf) {
            const int row = wn * 64 + nf * 16 + fr;
            const int grow = row0 + row;
            if (grow >= EE) continue;
            const int of0 = wm * 32 + mt * 16 + fq;
            f32x4 vs, vt;
            #pragma unroll
            for (int q = 0; q < 4; ++q) {
                vs[q] = act_silu(aS[mt][nf][q]);
                vt[q] = act_silu(aT[mt][nf][q]);
            }
            store_bf4(&yst[(size_t)grow * 128 + of0], vs);
            store_bf4(&yts[(size_t)grow * 128 + of0], vt);
        }
}

// ---------------------------------------------------------------------------
// chain: x_skip + (y_st + y_ts[swap]) merge + resb + m_st merge + resa x2
// ---------------------------------------------------------------------------
__global__ __launch_bounds__(512, 4) void chain_k(
    const float* __restrict__ m_st,
    const unsigned short* __restrict__ yst, const unsigned short* __restrict__ yts,
    const int* __restrict__ idx_swap,
    const unsigned short* __restrict__ Wmlp,
    const unsigned short* __restrict__ Wrb0, const unsigned short* __restrict__ Wrb1,
    const unsigned short* __restrict__ Wra0, const unsigned short* __restrict__ Wra1,
    const unsigned short* __restrict__ Wra2, const unsigned short* __restrict__ Wra3,
    unsigned short* __restrict__ xb_out)
{
    __shared__ char A[128 * 256];
    __shared__ char B[128 * 256];
    const int tid = threadIdx.x;
    const int l = tid & 63, w = tid >> 6, wm = w & 3, wn = w >> 2;
    const int fr = l & 15, fq = (l >> 4) << 2;
    const int row0 = blockIdx.x * 128;

    s16x8 aw[2][4];
    load_w<2, 4>(Wmlp + (size_t)(wm * 32) * 128, 128, l, aw);

    stage_f32<128>(A, m_st, row0, EE, tid);
    __syncthreads();

    f32x4 acc[2][4];
    zacc(acc);
    gemm_pre<2, 4, 4>(aw, A, 256, wn * 64, l, acc);

    // keep bf16 m_st frags for the post-resb merge (avoids 61MB HBM re-read)
    s16x4 ms[2][4];
    #pragma unroll
    for (int mt = 0; mt < 2; ++mt)
        #pragma unroll
        for (int nf = 0; nf < 4; ++nf)
            ms[mt][nf] = read_frag(A, wn * 64 + nf * 16 + fr, wm * 32 + mt * 16 + fq);

    f32x4 x[2][4];
    #pragma unroll
    for (int mt = 0; mt < 2; ++mt)
        #pragma unroll
        for (int nf = 0; nf < 4; ++nf) {
            const int row = wn * 64 + nf * 16 + fr;
            const int grow = row0 + row;
            const int of0 = wm * 32 + mt * 16 + fq;
            if (grow < EE) {
                s16x4 a = *(const s16x4*)&yst[(size_t)grow * 128 + of0];
                const int sw = idx_swap[grow];
                s16x4 b = *(const s16x4*)&yts[(size_t)sw * 128 + of0];
                #pragma unroll
                for (int q = 0; q < 4; ++q)
                    x[mt][nf][q] = (acc[mt][nf][q] +
                        (bf2f((unsigned short)a[q]) + bf2f((unsigned short)b[q])) * C_INV) * C_INV;
            } else {
                x[mt][nf] = (f32x4){0.f, 0.f, 0.f, 0.f};
            }
        }
    __syncthreads();
    #pragma unroll
    for (int mt = 0; mt < 2; ++mt)
        #pragma unroll
        for (int nf = 0; nf < 4; ++nf)
            packA(A, 256, wn * 64 + nf * 16 + fr, wm * 32 + mt * 16 + fq, x[mt][nf]);
    __syncthreads();

    res_layer<true , 4>(A, B, Wrb0, Wrb1, wm, wn, l, x, ms);
    res_layer<false, 4>(A, B, Wra0, Wra1, wm, wn, l, x, nullptr);
    res_layer<false, 4>(A, B, Wra2, Wra3, wm, wn, l, x, nullptr);

    #pragma unroll
    for (int mt = 0; mt < 2; ++mt)
        #pragma unroll
        for (int nf = 0; nf < 4; ++nf) {
            const int row = wn * 64 + nf * 16 + fr;
            const int grow = row0 + row;
            if (grow >= EE) continue;
            const int of0 = wm * 32 + mt * 16 + fq;
            store_bf4(&xb_out[(size_t)grow * 128 + of0], x[mt][nf]);
        }
}

// ---------------------------------------------------------------------------
// atom chain (64-row tiles, NF=2)
// ---------------------------------------------------------------------------
__global__ __launch_bounds__(512, 4) void atom_k(
    const float* __restrict__ h2,
    const unsigned short* __restrict__ Wae,
    const unsigned short* __restrict__ Wr0, const unsigned short* __restrict__ Wr1,
    const unsigned short* __restrict__ Wr2, const unsigned short* __restrict__ Wr3,
    float* __restrict__ out_h, unsigned short* __restrict__ h_b)
{
    __shared__ char A[64 * 256];
    __shared__ char B[64 * 256];
    const int tid = threadIdx.x;
    const int l = tid & 63, w = tid >> 6, wm = w & 3, wn = w >> 2;
    const int fr = l & 15, fq = (l >> 4) << 2;
    const int row0 = blockIdx.x * 64;

    s16x8 aw[2][4];
    load_w<2, 4>(Wae + (size_t)(wm * 32) * 128, 128, l, aw);

    stage_f32<64>(A, h2, row0, NA, tid);
    __syncthreads();

    f32x4 acc[2][2];
    zacc(acc);
    gemm_pre<2, 2, 4>(aw, A, 256, wn * 32, l, acc);
    f32x4 x[2][2];
    #pragma unroll
    for (int mt = 0; mt < 2; ++mt)
        #pragma unroll
        for (int nf = 0; nf < 2; ++nf)
            #pragma unroll
            for (int q = 0; q < 4; ++q)
                x[mt][nf][q] = act_silu(acc[mt][nf][q]);
    __syncthreads();
    #pragma unroll
    for (int mt = 0; mt < 2; ++mt)
        #pragma unroll
        for (int nf = 0; nf < 2; ++nf)
            packA(A, 256, wn * 32 + nf * 16 + fr, wm * 32 + mt * 16 + fq, x[mt][nf]);
    __syncthreads();

    res_layer<false, 2>(A, B, Wr0, Wr1, wm, wn, l, x, nullptr);
    res_layer<false, 2>(A, B, Wr2, Wr3, wm, wn, l, x, nullptr);

    #pragma unroll
    for (int mt = 0; mt < 2; ++mt)
        #pragma unroll
        for (int nf = 0; nf < 2; ++nf) {
            const int row = wn * 32 + nf * 16 + fr;
            const int grow = row0 + row;
            if (grow >= NA) continue;
            const int of0 = wm * 32 + mt * 16 + fq;
            *(f32x4*)&out_h[(size_t)grow * 128 + of0] = x[mt][nf];
            store_bf4(&h_b[(size_t)grow * 128 + of0], x[mt][nf]);
        }
}

// ---------------------------------------------------------------------------
// ASI + res_m: m = act([h[s]|h[t]|x]@W_asi); res_m x2; out_m = (m + x)*C
// ---------------------------------------------------------------------------
__global__ __launch_bounds__(512, 4) void asi_k(
    const unsigned short* __restrict__ h_b, const unsigned short* __restrict__ x_b,
    const int* __restrict__ idx_s, const int* __restrict__ idx_t,
    const unsigned short* __restrict__ Wasi,
    const unsigned short* __restrict__ Wm0, const unsigned short* __restrict__ Wm1,
    const unsigned short* __restrict__ Wm2, const unsigned short* __restrict__ Wm3,
    float* __restrict__ out_m)
{
    __shared__ char A[128 * 256];
    __shared__ char B[128 * 256];
    const int tid = threadIdx.x;
    const int l = tid & 63, w = tid >> 6, wm = w & 3, wn = w >> 2;
    const int fr = l & 15, fq = (l >> 4) << 2;
    const int row0 = blockIdx.x * 128;

    f32x4 acc[2][4];
    zacc(acc);

    for (int c = 0; c < 3; ++c) {
        s16x8 aw[2][4];
        load_w<2, 4>(Wasi + (size_t)(wm * 32) * 384 + c * 128, 384, l, aw);
        #pragma unroll
        for (int u = 0; u < 4; ++u) {
            const int flat = tid + u * 512;
            const int row = flat >> 4;
            const int k8 = (flat & 15) << 3;
            const int grow = row0 + row;
            s16x8 v = {0, 0, 0, 0, 0, 0, 0, 0};
            if (grow < EE) {
                const unsigned short* src =
                    (c == 0) ? h_b + (size_t)idx_s[grow] * 128
                  : (c == 1) ? h_b + (size_t)idx_t[grow] * 128
                             : x_b + (size_t)grow * 128;
                v = *(const s16x8*)&src[k8];
            }
            *(s16x8*)(A + row * 256 + ((k8 * 2) ^ ((row & 7) << 4))) = v;
        }
        __syncthreads();
        gemm_pre<2, 4, 4>(aw, A, 256, wn * 64, l, acc);
        __syncthreads();
    }

    f32x4 x[2][4];
    #pragma unroll
    for (int mt = 0; mt < 2; ++mt)
        #pragma unroll
        for (int nf = 0; nf < 4; ++nf)
            #pragma unroll
            for (int q = 0; q < 4; ++q)
                x[mt][nf][q] = act_silu(acc[mt][nf][q]);
    #pragma unroll
    for (int mt = 0; mt < 2; ++mt)
        #pragma unroll
        for (int nf = 0; nf < 4; ++nf)
            packA(A, 256, wn * 64 + nf * 16 + fr, wm * 32 + mt * 16 + fq, x[mt][nf]);
    __syncthreads();

    res_layer<false, 4>(A, B, Wm0, Wm1, wm, wn, l, x, nullptr);
    res_layer<false, 4>(A, B, Wm2, Wm3, wm, wn, l, x, nullptr);

    #pragma unroll
    for (int mt = 0; mt < 2; ++mt)
        #pragma unroll
        for (int nf = 0; nf < 4; ++nf) {
            const int row = wn * 64 + nf * 16 + fr;
            const int grow = row0 + row;
            if (grow >= EE) continue;
            const int of0 = wm * 32 + mt * 16 + fq;
            s16x4 xv = *(const s16x4*)&x_b[(size_t)grow * 128 + of0];
            f32x4 o;
            #pragma unroll
            for (int q = 0; q < 4; ++q)
                o[q] = (x[mt][nf][q] + bf2f((unsigned short)xv[q])) * C_INV;
            *(f32x4*)&out_m[(size_t)grow * 128 + of0] = o;
        }
}

// ---------------------------------------------------------------------------
// rbf scale: scale = rbf3 @ W_t_rbf -> bf16
// ---------------------------------------------------------------------------
__global__ __launch_bounds__(256) void rbf_scale_k(
    const float* __restrict__ A, const float* __restrict__ W,
    unsigned short* __restrict__ out, int M)
{
    __shared__ float Ws[16][128];
    const int tid = threadIdx.x;
    #pragma unroll
    for (int t = tid; t < 512; t += 256) {
        int kk = t >> 5, c4 = (t & 31) << 2;
        *(float4*)&Ws[kk][c4] = *(const float4*)(W + kk * 128 + c4);
    }
    __syncthreads();
    const int tx = tid & 31, ty = tid >> 5;
    const int row0 = blockIdx.x * 128;
    #pragma unroll
    for (int i = 0; i < 16; ++i) {
        const int row = row0 + ty + i * 8;
        if (row >= M) continue;
        float av[16];
        #pragma unroll
        for (int j = 0; j < 4; ++j) {
            float4 a = *(const float4*)(A + (size_t)row * 16 + j * 4);
            av[j * 4] = a.x; av[j * 4 + 1] = a.y; av[j * 4 + 2] = a.z; av[j * 4 + 3] = a.w;
        }
        f32x4 s = {0.f, 0.f, 0.f, 0.f};
        #pragma unroll
        for (int k = 0; k < 16; ++k) {
            float4 wv = *(const float4*)&Ws[k][tx * 4];
            s[0] += av[k] * wv.x; s[1] += av[k] * wv.y;
            s[2] += av[k] * wv.z; s[3] += av[k] * wv.w;
        }
        store_bf4(&out[(size_t)row * 128 + tx * 4], s);
    }
}

// ---------------------------------------------------------------------------
// counting sort of idx_t + gather segment-sum with fused coef
// ---------------------------------------------------------------------------
__global__ void hist_k(const int* __restrict__ idxt, int* __restrict__ cnt)
{
    int i = blockIdx.x * 256 + threadIdx.x;
    if (i < EE) atomicAdd(&cnt[idxt[i]], 1);
}

__global__ __launch_bounds__(256) void scan_k(const int* __restrict__ cnt,
                                              int* __restrict__ start, int* __restrict__ wrk)
{
    __shared__ int ps[256];
    const int t = threadIdx.x;
    int s = 0;
    for (int j = 0; j < 40; ++j) {
        int idx = t * 40 + j;
        if (idx < NA) s += cnt[idx];
    }
    ps[t] = s;
    __syncthreads();
    for (int off = 1; off < 256; off <<= 1) {
        int v = (t >= off) ? ps[t - off] : 0;
        __syncthreads();
        ps[t] += v;
        __syncthreads();
    }
    int run = ps[t] - s;
    for (int j = 0; j < 40; ++j) {
        int idx = t * 40 + j;
        if (idx < NA) {
            start[idx] = run;
            wrk[idx] = run;
            run += cnt[idx];
        }
    }
    if (t == 255) start[NA] = ps[255];
}

__global__ void place_k(const int* __restrict__ idxt, int* __restrict__ wrk,
                        int* __restrict__ order)
{
    int i = blockIdx.x * 256 + threadIdx.x;
    if (i < EE) {
        int pos = atomicAdd(&wrk[idxt[i]], 1);
        order[pos] = i;
    }
}

// one wave per atom: h2[a] = sum_{e in bucket} x_b[e] * (rbf_h[e] @ W_ae_rbf)
__global__ __launch_bounds__(256) void segsum_k(
    const unsigned short* __restrict__ x_b, const float* __restrict__ rbf_h,
    const float* __restrict__ Wae, const int* __restrict__ start,
    const int* __restrict__ order, float* __restrict__ h2)
{
    const int tid = threadIdx.x;
    const int l = tid & 63, w = tid >> 6;
    const int a = blockIdx.x * 4 + w;
    if (a >= NA) return;

    float wc[32];
    #pragma unroll
    for (int j = 0; j < 16; ++j) {
        f32x2 v = *(const f32x2*)(Wae + j * 128 + 2 * l);
        wc[2 * j] = v[0]; wc[2 * j + 1] = v[1];
    }

    const int s = start[a], e_end = start[a + 1];
    float acc0 = 0.f, acc1 = 0.f;
    for (int i = s; i < e_end; ++i) {
        const int e = __builtin_amdgcn_readfirstlane(order[i]);
        const unsigned int xv = *(const unsigned int*)(x_b + (size_t)e * 128 + 2 * l);
        const float* rp = rbf_h + (size_t)e * 16;
        float c0 = 0.f, c1 = 0.f;
        #pragma unroll
        for (int j = 0; j < 16; ++j) {
            float r = rp[j];
            c0 += r * wc[2 * j];
            c1 += r * wc[2 * j + 1];
        }
        acc0 += bf2f((unsigned short)(xv & 0xffff)) * c0;
        acc1 += bf2f((unsigned short)(xv >> 16)) * c1;
    }
    f32x2 o; o[0] = acc0; o[1] = acc1;
    *(f32x2*)&h2[(size_t)a * 128 + 2 * l] = o;
}

// ---------------------------------------------------------------------------
// weight conversions
// ---------------------------------------------------------------------------
__global__ void wconv_k(const float* __restrict__ Wbil, unsigned short* __restrict__ WT)
{
    int t = blockIdx.x * 256 + threadIdx.x;
    int u = t >> 10, k = t & 1023, j = k >> 6, c = k & 63;
    WT[t] = f2bf(Wbil[(size_t)(c * 16 + j) * 64 + u]);
}

struct WDesc { const float* src; int K; int N; int off; };
struct WTab  { WDesc d[21]; };

__global__ void wconvall_k(WTab tab, unsigned short* __restrict__ dst)
{
    WDesc d = tab.d[blockIdx.x];
    const int tot = d.K * d.N;
    for (int i = threadIdx.x; i < tot; i += 256) {
        int n = i / d.K, k = i - n * d.K;
        dst[d.off + i] = f2bf(d.src[(size_t)k * d.N + n]);
    }
}

// ---------------------------------------------------------------------------
// bilinear (readlane coefficients, bf16 in/out)
// ---------------------------------------------------------------------------
__device__ __forceinline__ float rlc(const f32x4& cv, int idx, int lbase)
{
    const int c = idx & 3;
    float comp = (c == 0) ? cv[0] : (c == 1) ? cv[1] : (c == 2) ? cv[2] : cv[3];
    return __uint_as_float(__builtin_amdgcn_readlane(__float_as_uint(comp),
                                                     lbase + (idx >> 2)));
}

__global__ __launch_bounds__(512) void bilinear3_k(
    const unsigned short* __restrict__ mkt,
    const float* __restrict__ rbfW1,
    const float* __restrict__ sph,
    const int*   __restrict__ id3kt,
    const unsigned short* __restrict__ WT,
    unsigned short* __restrict__ xb)
{
    __shared__ unsigned short aS[32 * 1024];
    float* pS = (float*)aS;

    const int tid = threadIdx.x;
    const int l   = tid & 63;
    const int w   = tid >> 6;
    const int e0  = blockIdx.x * 32;

    s16x8 bfrag[4][4];
    {
        const int u  = l & 15;
        const int kh = w * 128 + ((l >> 4) << 3);
        #pragma unroll
        for (int nt = 0; nt < 4; ++nt)
            #pragma unroll
            for (int kq = 0; kq < 4; ++kq)
                bfrag[nt][kq] = *(const s16x8*)&WT[(size_t)(nt * 16 + u) * 1024 + kh + kq * 32];
    }

    #pragma unroll
    for (int r = 0; r < 4; ++r) {
        const int eL = r * 8 + w;
        const int eG = e0 + eL;

        f32x4 cv = {0.f, 0.f, 0.f, 0.f};
        if (l < 14)       cv = *(const f32x4*)(sph   + (size_t)eG * 56  + l * 4);
        else if (l < 42)  cv = *(const f32x4*)(rbfW1 + (size_t)eG * 112 + (l - 14) * 4);

        float m2r[8];
        #pragma unroll
        for (int k = 0; k < 8; ++k)
            m2r[k] = bf2f(mkt[(size_t)id3kt[eG * 8 + k] * 64 + l]);

        float sk[7] = {0.f, 0.f, 0.f, 0.f, 0.f, 0.f, 0.f};
        #pragma unroll
        for (int k = 0; k < 8; ++k)
            #pragma unroll
            for (int s = 0; s < 7; ++s)
                sk[s] += rlc(cv, k * 7 + s, 0) * m2r[k];

        unsigned short* arow = aS + eL * 1024;
        const int lsw = l ^ ((eL & 7) << 3);
        #pragma unroll
        for (int j = 0; j < 16; ++j) {
            float av = 0.f;
            #pragma unroll
            for (int s = 0; s < 7; ++s)
                av += rlc(cv, j * 7 + s, 14) * sk[s];
            arow[j * 64 + lsw] = f2bf(av);
        }
    }
    __syncthreads();

    f32x4 acc[2][4];
    #pragma unroll
    for (int mt = 0; mt < 2; ++mt)
        #pragma unroll
        for (int nt = 0; nt < 4; ++nt)
            acc[mt][nt] = (f32x4){0.f, 0.f, 0.f, 0.f};

    const int kbase = w * 128 + ((l >> 4) << 3);
    #pragma unroll
    for (int kq = 0; kq < 4; ++kq) {
        s16x8 afr[2];
        #pragma unroll
        for (int mt = 0; mt < 2; ++mt) {
            const int row = mt * 16 + (l & 15);
            const int kk  = (kbase + kq * 32) ^ ((row & 7) << 3);
            afr[mt] = *(const s16x8*)&aS[row * 1024 + kk];
        }
        #pragma unroll
        for (int mt = 0; mt < 2; ++mt)
            #pragma unroll
            for (int nt = 0; nt < 4; ++nt)
                acc[mt][nt] = __builtin_amdgcn_mfma_f32_16x16x32_bf16(
                    afr[mt], bfrag[nt][kq], acc[mt][nt], 0, 0, 0);
    }
    __syncthreads();

    #pragma unroll
    for (int mt = 0; mt < 2; ++mt)
        #pragma unroll
        for (int nt = 0; nt < 4; ++nt)
            #pragma unroll
            for (int q = 0; q < 4; ++q) {
                const int e = mt * 16 + ((l >> 4) << 2) + q;
                const int u = nt * 16 + (l & 15);
                pS[(w * 32 + e) * 64 + u] = acc[mt][nt][q];
            }
    __syncthreads();

    {
        const int e  = tid >> 4;
        const int u0 = (tid & 15) << 2;
        f32x4 s = (f32x4){0.f, 0.f, 0.f, 0.f};
        #pragma unroll
        for (int ww = 0; ww < 8; ++ww)
            s += *(const f32x4*)&pS[(ww * 32 + e) * 64 + u0];
        store_bf4(&xb[(size_t)(e0 + e) * 64 + u0], s);
    }
}

// ---------------------------------------------------------------------------
// launch
// ---------------------------------------------------------------------------
extern "C" void kernel_launch(void* const* d_in, const int* in_sizes, int n_in,
                              void* d_out, int out_size, void* d_ws, size_t ws_size,
                              hipStream_t stream)
{
    const float* m_st      = (const float*)d_in[1];
    const float* rbf_h     = (const float*)d_in[2];
    const float* rbf3      = (const float*)d_in[3];
    const float* cbf_rbfW1 = (const float*)d_in[4];
    const float* cbf_sph   = (const float*)d_in[5];
    const float* W_mlp_st  = (const float*)d_in[6];
    const float* W_m_kt    = (const float*)d_in[7];
    const float* W_t_rbf   = (const float*)d_in[8];
    const float* W_down    = (const float*)d_in[9];
    const float* W_bil     = (const float*)d_in[10];
    const float* W_st3     = (const float*)d_in[11];
    const float* W_ts3     = (const float*)d_in[12];
    const float* resb      = (const float*)d_in[13];
    const float* resa      = (const float*)d_in[14];
    const float* W_ae_rbf  = (const float*)d_in[15];
    const float* W_ae_in   = (const float*)d_in[16];
    const float* resat     = (const float*)d_in[17];
    const float* W_asi     = (const float*)d_in[18];
    const float* resm      = (const float*)d_in[19];
    const int*   idx_s     = (const int*)d_in[20];
    const int*   idx_t     = (const int*)d_in[21];
    const int*   idx_swap  = (const int*)d_in[22];
    const int*   id3_kt    = (const int*)d_in[23];

    float* h2 = (float*)d_ws;                               // NA x 128 f32
    unsigned short* scale_b = (unsigned short*)(h2 + (size_t)NA * 128);
    unsigned short* yst_b   = scale_b;                      // alias (scale dead first)
    unsigned short* yts_b   = scale_b + (size_t)EE * 128;
    unsigned short* x_b     = yts_b + (size_t)EE * 128;
    unsigned short* mkt_b   = x_b + (size_t)EE * 128;
    unsigned short* xb_b    = mkt_b + (size_t)EE * 64;
    unsigned short* h_b     = xb_b + (size_t)EE * 64;
    unsigned short* WTbil   = h_b + (size_t)NA * 128;
    unsigned short* WTall   = WTbil + 65536;
    int* cnt   = (int*)(WTall + 352256);
    int* start = cnt + NA;
    int* wrk   = start + NA + 1;
    int* order = wrk + NA;

    float* out_h = (float*)d_out;
    float* out_m = out_h + (size_t)NA * 128;

    const dim3 blk(256);
    const dim3 blk5(512);
    const int gE  = (EE + 127) / 128;   // 938
    const int gN64 = (NA + 63) / 64;    // 157
    constexpr size_t SQ = 128 * 128;

    WTab tab; int off = 0; int oi = 0;
    auto put = [&](const float* s, int K, int N) {
        int o = off; tab.d[oi].src = s; tab.d[oi].K = K; tab.d[oi].N = N;
        tab.d[oi].off = o; ++oi; off += K * N; return o;
    };
    const int o_mlp  = put(W_mlp_st, 128, 128);
    const int o_mktw = put(W_m_kt, 128, 128);
    const int o_down = put(W_down, 128, 64);
    const int o_st3  = put(W_st3, 64, 128);
    const int o_ts3  = put(W_ts3, 64, 128);
    const int o_rb0  = put(resb, 128, 128);
    const int o_rb1  = put(resb + SQ, 128, 128);
    const int o_ra0  = put(resa, 128, 128);
    const int o_ra1  = put(resa + SQ, 128, 128);
    const int o_ra2  = put(resa + 2 * SQ, 128, 128);
    const int o_ra3  = put(resa + 3 * SQ, 128, 128);
    const int o_aein = put(W_ae_in, 128, 128);
    const int o_rat0 = put(resat, 128, 128);
    const int o_rat1 = put(resat + SQ, 128, 128);
    const int o_rat2 = put(resat + 2 * SQ, 128, 128);
    const int o_rat3 = put(resat + 3 * SQ, 128, 128);
    const int o_asi  = put(W_asi, 384, 128);
    const int o_rm0  = put(resm, 128, 128);
    const int o_rm1  = put(resm + SQ, 128, 128);
    const int o_rm2  = put(resm + 2 * SQ, 128, 128);
    const int o_rm3  = put(resm + 3 * SQ, 128, 128);

    hipMemsetAsync(cnt, 0, NA * sizeof(int), stream);
    wconv_k<<<65536 / 256, blk, 0, stream>>>(W_bil, WTbil);
    wconvall_k<<<21, blk, 0, stream>>>(tab, WTall);
    hist_k<<<(EE + 255) / 256, blk, 0, stream>>>(idx_t, cnt);
    scan_k<<<1, blk, 0, stream>>>(cnt, start, wrk);
    place_k<<<(EE + 255) / 256, blk, 0, stream>>>(idx_t, wrk, order);

    rbf_scale_k<<<gE, blk, 0, stream>>>(rbf3, W_t_rbf, scale_b, EE);
    front_k<<<gE, blk5, 0, stream>>>(m_st, scale_b, WTall + o_mktw, WTall + o_down, mkt_b);
    bilinear3_k<<<EE / 32, blk5, 0, stream>>>(
        mkt_b, cbf_rbfW1, cbf_sph, id3_kt, WTbil, xb_b);
    st3ts3_k<<<gE, blk5, 0, stream>>>(xb_b, WTall + o_st3, WTall + o_ts3, yst_b, yts_b);
    chain_k<<<gE, blk5, 0, stream>>>(
        m_st, yst_b, yts_b, idx_swap,
        WTall + o_mlp, WTall + o_rb0, WTall + o_rb1,
        WTall + o_ra0, WTall + o_ra1, WTall + o_ra2, WTall + o_ra3,
        x_b);
    segsum_k<<<(NA + 3) / 4, blk, 0, stream>>>(x_b, rbf_h, W_ae_rbf, start, order, h2);
    atom_k<<<gN64, blk5, 0, stream>>>(
        h2, WTall + o_aein,
        WTall + o_rat0, WTall + o_rat1, WTall + o_rat2, WTall + o_rat3,
        out_h, h_b);
    asi_k<<<gE, blk5, 0, stream>>>(
        h_b, x_b, idx_s, idx_t,
        WTall + o_asi,
        WTall + o_rm0, WTall + o_rm1, WTall + o_rm2, WTall + o_rm3,
        out_m);
}